// Round 9
// baseline (4379.982 us; speedup 1.0000x reference)
//
#include <hip/hip_runtime.h>

typedef _Float16 f16;
typedef _Float16 f16x2 __attribute__((ext_vector_type(2)));
typedef _Float16 f16x4 __attribute__((ext_vector_type(4)));
typedef _Float16 f16x8 __attribute__((ext_vector_type(8)));
typedef float f32x4 __attribute__((ext_vector_type(4)));
typedef int iv4 __attribute__((ext_vector_type(4)));

#define S_LEN 1024
#define BATCH 32
#define HID 256
#define L2E 1.4426950408889634f
#define L2E2 2.8853900817779268f

#if __has_builtin(__builtin_amdgcn_fdot2)
#define FDOT2(a, b, c) __builtin_amdgcn_fdot2((a), (b), (c), false)
#else
static __device__ __forceinline__ float FDOT2(f16x2 a, f16x2 b, float c) {
  return c + (float)a[0] * (float)b[0] + (float)a[1] * (float)b[1];
}
#endif

__device__ __forceinline__ float EXP2(float x) {
#if __has_builtin(__builtin_amdgcn_exp2f)
  return __builtin_amdgcn_exp2f(x);
#else
  return exp2f(x);
#endif
}
__device__ __forceinline__ float RCP(float x) {
#if __has_builtin(__builtin_amdgcn_rcpf)
  return __builtin_amdgcn_rcpf(x);
#else
  return 1.0f / x;
#endif
}

__device__ __forceinline__ iv4 cvt8(float4 a, float4 b) {
#if __has_builtin(__builtin_amdgcn_cvt_pkrtz)
  auto p0 = __builtin_amdgcn_cvt_pkrtz(a.x, a.y);
  auto p1 = __builtin_amdgcn_cvt_pkrtz(a.z, a.w);
  auto p2 = __builtin_amdgcn_cvt_pkrtz(b.x, b.y);
  auto p3 = __builtin_amdgcn_cvt_pkrtz(b.z, b.w);
  iv4 o;
  o[0] = __builtin_bit_cast(int, p0);
  o[1] = __builtin_bit_cast(int, p1);
  o[2] = __builtin_bit_cast(int, p2);
  o[3] = __builtin_bit_cast(int, p3);
  return o;
#else
  f16x8 h;
  h[0] = (f16)a.x; h[1] = (f16)a.y; h[2] = (f16)a.z; h[3] = (f16)a.w;
  h[4] = (f16)b.x; h[5] = (f16)b.y; h[6] = (f16)b.z; h[7] = (f16)b.w;
  return __builtin_bit_cast(iv4, h);
#endif
}

#if __has_builtin(__builtin_amdgcn_global_load_lds)
__device__ __forceinline__ void gload16(const void* g, void* l) {
  __builtin_amdgcn_global_load_lds((const __attribute__((address_space(1))) void*)g,
                                   (__attribute__((address_space(3))) void*)l, 16, 0, 0);
}
#else
__device__ __forceinline__ void gload16(const void* g, void* l) {
  *(f16x8*)l = *(const f16x8*)g;  // reg round-trip fallback
}
#endif

// barrier that waits LDS only (no vmcnt drain)
#define WG_BARRIER()                                                  \
  do {                                                                \
    __builtin_amdgcn_sched_barrier(0);                                \
    asm volatile("s_waitcnt lgkmcnt(0)\n\ts_barrier" ::: "memory");   \
    __builtin_amdgcn_sched_barrier(0);                                \
  } while (0)

__device__ __forceinline__ float dot8(f16x8 w, f16x8 h, float acc) {
  f16x2 a, b;
  a[0] = w[0]; a[1] = w[1]; b[0] = h[0]; b[1] = h[1]; acc = FDOT2(a, b, acc);
  a[0] = w[2]; a[1] = w[3]; b[0] = h[2]; b[1] = h[3]; acc = FDOT2(a, b, acc);
  a[0] = w[4]; a[1] = w[5]; b[0] = h[4]; b[1] = h[5]; acc = FDOT2(a, b, acc);
  a[0] = w[6]; a[1] = w[7]; b[0] = h[6]; b[1] = h[7]; acc = FDOT2(a, b, acc);
  return acc;
}

// ---------------- f32 -> f16 convert (plain) ----------------
__global__ void cvt_f32_f16(const float* __restrict__ src, f16* __restrict__ dst, int n4) {
  int i = blockIdx.x * 256 + threadIdx.x;
  if (i < n4) {
    float4 v = ((const float4*)src)[i];
    f16x4 h;
    h[0] = (f16)v.x; h[1] = (f16)v.y; h[2] = (f16)v.z; h[3] = (f16)v.w;
    ((f16x4*)dst)[i] = h;
  }
}

// ---------------- w_ih f32 -> f16, log2e row-scaled ----------------
__global__ void cvt_wih(const float* __restrict__ src, f16* __restrict__ dst, int K, int total8) {
  int i = blockIdx.x * 256 + threadIdx.x;
  if (i < total8) {
    int row = (int)(((long long)i * 8) / K);
    float sc = (row >= 512 && row < 768) ? L2E2 : L2E;
    const float* s = src + (size_t)i * 8;
    float4 a = *(const float4*)s;
    float4 b = *(const float4*)(s + 4);
    f16x8 h;
    h[0] = (f16)(a.x * sc); h[1] = (f16)(a.y * sc); h[2] = (f16)(a.z * sc); h[3] = (f16)(a.w * sc);
    h[4] = (f16)(b.x * sc); h[5] = (f16)(b.y * sc); h[6] = (f16)(b.z * sc); h[7] = (f16)(b.w * sc);
    *(f16x8*)(dst + (size_t)i * 8) = h;
  }
}

// ---------------- bias pack: bsum[u][n] = (bih+bhh)*sc ----------------
__global__ void bias_pack(const float* __restrict__ a0, const float* __restrict__ h0,
                          const float* __restrict__ a1, const float* __restrict__ h1,
                          const float* __restrict__ a2, const float* __restrict__ h2,
                          const float* __restrict__ a3, const float* __restrict__ h3,
                          float* __restrict__ bsum) {
  int i = blockIdx.x * 256 + threadIdx.x;
  if (i < 4096) {
    int u = i >> 10, n = i & 1023;
    float sc = (n >= 512 && n < 768) ? L2E2 : L2E;
    const float* pa = u == 0 ? a0 : u == 1 ? a1 : u == 2 ? a2 : a3;
    const float* ph = u == 0 ? h0 : u == 1 ? h1 : u == 2 ? h2 : h3;
    bsum[i] = (pa[n] + ph[n]) * sc;
  }
}

// ---------------- whh f32 -> i8 per-row symmetric quant, log2e pre-scaled ----------------
__global__ __launch_bounds__(256) void quant_whh(const float* __restrict__ src,
                                                 char* __restrict__ dstq,
                                                 float* __restrict__ fsc) {
  const int row = blockIdx.x * 4 + (threadIdx.x >> 6);
  const int lane = threadIdx.x & 63;
  const float sc = (row >= 512 && row < 768) ? L2E2 : L2E;
  float4 v = *(const float4*)(src + (size_t)row * 256 + lane * 4);
  float w0 = v.x * sc, w1 = v.y * sc, w2 = v.z * sc, w3 = v.w * sc;
  float mx = fmaxf(fmaxf(fabsf(w0), fabsf(w1)), fmaxf(fabsf(w2), fabsf(w3)));
#pragma unroll
  for (int off = 1; off < 64; off <<= 1) mx = fmaxf(mx, __shfl_xor(mx, off));
  mx = fmaxf(mx, 1e-20f);
  float inv = 127.0f / mx;
  int q0 = (int)rintf(w0 * inv), q1 = (int)rintf(w1 * inv);
  int q2 = (int)rintf(w2 * inv), q3 = (int)rintf(w3 * inv);
  int pk = (q0 & 0xff) | ((q1 & 0xff) << 8) | ((q2 & 0xff) << 16) | ((q3 & 0xff) << 24);
  ((int*)(dstq + (size_t)row * 256))[lane] = pk;
  if (lane == 0) fsc[row] = mx / 16129.0f;
}

// ---------------- fused input-projection GEMM -> P4 planes ----------------
// grid (16, 256): unit = bx>>2, v = bx&3. Tile: 4 batches x 32 t x 256 cols, K-step 64.
// B staged via global_load_lds (pre-swizzled source); A reg-staged with next-step prefetch;
// counted vmcnt(8) so A prefetch stays in flight across the barrier; XOR-swizzled LDS tiles.
__global__ __attribute__((amdgpu_flat_work_group_size(256, 256), amdgpu_waves_per_eu(2, 2)))
void proj_gemm(const float* __restrict__ x,
               const float* __restrict__ xbin,
               const f16* __restrict__ w16all,
               const float* __restrict__ bsum,
               char* __restrict__ P4) {
  __shared__ __align__(16) char smem[65536];  // As [0,16K) ; Bs [16K,48K) ; epilogue uses all
  const int unit = blockIdx.x >> 2;
  const int v = blockIdx.x & 3;
  const int bm = blockIdx.y;
  const int K = (unit < 2) ? 512 : 1536;
  const float* Aptr = (unit < 2) ? x : xbin;
  const size_t woff = (unit == 0) ? 0u : (unit == 1) ? 524288u : (unit == 2) ? 1048576u : 2621440u;
  const f16* W16 = w16all + woff;
  const int bgrp = bm >> 5, t0 = (bm & 31) * 32;
  const int b0 = bgrp * 4, c = bgrp >> 1, lkb = bgrp & 1;
  const int tid = threadIdx.x;
  const int lane = tid & 63, wid = tid >> 6;
  const int wm = wid >> 1, wn = wid & 1;
  const int lr = lane & 15, lk = lane >> 4;

  f32x4 acc[4][8];
#pragma unroll
  for (int i = 0; i < 4; ++i)
#pragma unroll
    for (int n = 0; n < 8; ++n) acc[i][n] = (f32x4){0.f, 0.f, 0.f, 0.f};

  float4 A0a[4], A0b[4], A1a[4], A1b[4];

#define ISSUE_A(KK_, R0, R1)                                                  \
  _Pragma("unroll") for (int s = 0; s < 4; ++s) {                             \
    int slot = s * 256 + tid;                                                 \
    int row = slot >> 3, seg = slot & 7;                                      \
    size_t arow = (size_t)(b0 + (row >> 5)) * 1024 + t0 + (row & 31);         \
    const float* ga = Aptr + arow * K + (KK_) + seg * 8;                      \
    R0[s] = *(const float4*)ga;                                               \
    R1[s] = *(const float4*)(ga + 4);                                         \
  }

#define PROJ_STEP(KC_, KP_, AC0, AC1, AN0, AN1)                                             \
  {                                                                                         \
    asm volatile("s_waitcnt vmcnt(0)" ::: "memory");                                        \
    __builtin_amdgcn_sched_barrier(0);                                                      \
    _Pragma("unroll") for (int s = 0; s < 4; ++s) {                                         \
      int slot = s * 256 + tid;                                                             \
      int row = slot >> 3, seg = slot & 7;                                                  \
      int wa = row * 128 + ((seg ^ (row & 7)) << 4);                                        \
      *(iv4*)(smem + wa) = cvt8(AC0[s], AC1[s]);                                            \
    }                                                                                       \
    __builtin_amdgcn_sched_barrier(0);                                                      \
    _Pragma("unroll") for (int i = 0; i < 8; ++i) {                                         \
      int g = (wid * 8 + i) * 64 + lane;                                                    \
      int brow = g >> 3, cg = g & 7;                                                        \
      const f16* bsrc = W16 + (size_t)(v * 256 + brow) * K + (KC_) + ((cg ^ (brow & 7)) << 3); \
      gload16(bsrc, smem + 16384 + (wid * 8 + i) * 1024);                                   \
    }                                                                                       \
    __builtin_amdgcn_sched_barrier(0);                                                      \
    if ((KP_) < K) {                                                                        \
      ISSUE_A(KP_, AN0, AN1);                                                               \
      __builtin_amdgcn_sched_barrier(0);                                                    \
      asm volatile("s_waitcnt vmcnt(8)" ::: "memory");                                      \
    } else {                                                                                \
      asm volatile("s_waitcnt vmcnt(0)" ::: "memory");                                      \
    }                                                                                       \
    WG_BARRIER();                                                                           \
    _Pragma("unroll") for (int kk = 0; kk < 2; ++kk) {                                      \
      f16x8 af[4], bf[8];                                                                   \
      _Pragma("unroll") for (int mi = 0; mi < 4; ++mi) {                                    \
        int ba = (wm * 64 + mi * 16 + lr) * 128 + kk * 64 + lk * 16;                        \
        af[mi] = *(const f16x8*)(smem + (ba ^ ((lr & 7) << 4)));                            \
      }                                                                                     \
      _Pragma("unroll") for (int ni = 0; ni < 8; ++ni) {                                    \
        int bb = (wn * 128 + ni * 16 + lr) * 128 + kk * 64 + lk * 16;                       \
        bf[ni] = *(const f16x8*)(smem + 16384 + (bb ^ ((lr & 7) << 4)));                    \
      }                                                                                     \
      _Pragma("unroll") for (int mi = 0; mi < 4; ++mi)                                      \
        _Pragma("unroll") for (int ni = 0; ni < 8; ++ni)                                    \
          acc[mi][ni] = __builtin_amdgcn_mfma_f32_16x16x32_f16(af[mi], bf[ni], acc[mi][ni], 0, 0, 0); \
    }                                                                                       \
    WG_BARRIER();                                                                           \
  }

  ISSUE_A(0, A0a, A0b);
  for (int k0 = 0; k0 < K; k0 += 128) {
    PROJ_STEP(k0, k0 + 64, A0a, A0b, A1a, A1b);
    PROJ_STEP(k0 + 64, k0 + 128, A1a, A1b, A0a, A0b);
  }
#undef PROJ_STEP
#undef ISSUE_A
  __syncthreads();

  // epilogue: acc -> LDS (swizzled) -> coalesced 8B stores (round-5/6 proven)
  float biasv[8];
#pragma unroll
  for (int ni = 0; ni < 8; ++ni)
    biasv[ni] = bsum[unit * 1024 + v * 256 + wn * 128 + ni * 16 + lr];
#pragma unroll
  for (int mi = 0; mi < 4; ++mi) {
#pragma unroll
    for (int ni = 0; ni < 8; ++ni) {
      int col = wn * 128 + ni * 16 + lr;
      int wc = col >> 5, jc = (col >> 4) & 1, lc = col & 15;
#pragma unroll
      for (int rr = 0; rr < 4; ++rr) {
        int row = wm * 64 + mi * 16 + lk * 4 + rr;
        int bsub = row >> 5, t_loc = row & 31;
        int unit2 = t_loc * 256 + wc * 32 + jc * 16 + lc;
        int off = (unit2 * 8 + bsub * 2) ^ ((t_loc & 7) << 4);
        *(f16*)(smem + off) = (f16)(acc[mi][ni][rr] + biasv[ni]);
      }
    }
  }
  __syncthreads();
  char* Pv = P4 + ((size_t)unit << 26) + ((size_t)v << 24);
#pragma unroll
  for (int k = 0; k < 32; ++k) {
    int uid = k * 256 + tid;
    int t_loc = uid >> 8, sub = uid & 255;
    int off = (uid * 8) ^ ((t_loc & 7) << 4);
    unsigned long long val = *(const unsigned long long*)(smem + off);
    int wq = sub >> 5, jq = (sub >> 4) & 1, lq = sub & 15;
    size_t didx = (((size_t)((t0 + t_loc) * 4 + c) * 512) + wq * 64 + jq * 32 + lkb * 16 + lq) << 3;
    *(unsigned long long*)(Pv + didx) = val;
  }
}

// ---------------- LSTM recurrence: 64 WGs = (unit, batch-pair), i8 MFMA, 1 cell/lane ----------------
__global__ __attribute__((amdgpu_flat_work_group_size(512, 512), amdgpu_waves_per_eu(2, 2)))
void lstm_rec5(const char* __restrict__ Wq4,
               const float* __restrict__ fsc4,
               const char* __restrict__ P4,
               const float* __restrict__ h0m,
               const float* __restrict__ c0m,
               const float* __restrict__ h0b,
               const float* __restrict__ c0b,
               f16* __restrict__ hid4) {
  const int wg = blockIdx.x;
  const int u = wg >> 4, c16 = wg & 15;
  const int dir = u & 1;
  const int tid = threadIdx.x;
  const int l = tid & 63, w = tid >> 6;
  const int lr = l & 15, lk = l >> 4;
  const int jj = lk >> 1, selb = lk & 1;
  const int r2 = lr & 1;
  const int swzA = r2 ? 80 : 0;
  const int swzW = selb ? 80 : 0;
  const int j = w * 32 + jj * 16 + lr;  // hidden unit owned by this lane

  __shared__ __align__(16) char hbuf[2][512];  // [2 batch rows][256 k] i8, swizzled

  // ---- weights: 32 x iv4 = 128 regs; n = v*256 + w*32 + (nt&1)*16 + lr ----
  iv4 Bf[4][8];
  const char* wb = Wq4 + ((size_t)u << 18);
#pragma unroll
  for (int nt = 0; nt < 8; ++nt) {
    int n = (nt >> 1) * 256 + w * 32 + ((nt & 1) << 4) + lr;
#pragma unroll
    for (int ks = 0; ks < 4; ++ks)
      Bf[ks][nt] = *(const iv4*)(wb + (size_t)n * 256 + ks * 64 + lk * 16);
  }
  float fv[4], fv4[4];
#pragma unroll
  for (int v = 0; v < 4; ++v) {
    fv[v] = fsc4[u * 1024 + v * 256 + j];
    fv4[v] = fv[v] * 4.f;
  }

  // ---- init c / h0 (h0 quantized at scale 127/4, step-0 uses fv4) ----
  const int b = c16 * 2 + selb;
  const float* h0 = (u < 2 ? h0m : h0b) + (size_t)dir * BATCH * HID;
  const float* c0 = (u < 2 ? c0m : c0b) + (size_t)dir * BATCH * HID;
  float cst = c0[b * HID + j];
  {
    float hv = h0[b * HID + j] * 31.75f;
    int hq = (int)rintf(hv);
    hq = hq > 127 ? 127 : (hq < -127 ? -127 : hq);
    hbuf[0][selb * 256 + (j ^ swzW)] = (char)hq;
  }

  // ---- P preload for s=0 ----
  const char* Pc = P4 + ((size_t)u << 26);
  const size_t soff =
      (size_t)((w * 64 + jj * 32 + (((c16 >> 1) & 1) << 4) + lr) * 8 + (c16 & 1) * 4);
  const int cq = c16 >> 2;
  f16x2 Pa[4], Pb[4];
  {
    int t0 = dir ? (S_LEN - 1) : 0;
    size_t tb = ((size_t)((t0 << 2) + cq) << 12) + soff;
#pragma unroll
    for (int v = 0; v < 4; ++v) Pa[v] = *(const f16x2*)(Pc + ((size_t)v << 24) + tb);
  }
  WG_BARRIER();

#define LSTM_STEP(S_, SP_, PC_, PN_, FV_)                                                   \
  {                                                                                         \
    const int t = dir ? (S_LEN - 1 - (S_)) : (S_);                                          \
    {                                                                                       \
      int s2 = ((S_) + 1 < S_LEN) ? (S_) + 1 : (S_);                                        \
      int t2 = dir ? (S_LEN - 1 - s2) : s2;                                                 \
      size_t tb = ((size_t)((t2 << 2) + cq) << 12) + soff;                                  \
      _Pragma("unroll") for (int v = 0; v < 4; ++v)                                         \
          PN_[v] = *(const f16x2*)(Pc + ((size_t)v << 24) + tb);                            \
    }                                                                                       \
    iv4 ia[8];                                                                              \
    _Pragma("unroll") for (int nt = 0; nt < 8; ++nt) ia[nt] = (iv4){0, 0, 0, 0};            \
    const char* hb = hbuf[SP_];                                                             \
    _Pragma("unroll") for (int ks = 0; ks < 4; ++ks) {                                      \
      iv4 Af = *(const iv4*)(hb + r2 * 256 + ((ks * 64 + lk * 16) ^ swzA));                 \
      _Pragma("unroll") for (int nt = 0; nt < 8; ++nt)                                      \
          ia[nt] = __builtin_amdgcn_mfma_i32_16x16x64_i8(Af, Bf[ks][nt], ia[nt], 0, 0, 0);  \
    }                                                                                       \
    float z[4];                                                                             \
    _Pragma("unroll") for (int v = 0; v < 4; ++v) {                                         \
      int e0 = selb ? ia[v * 2][1] : ia[v * 2][0];                                          \
      int e1 = selb ? ia[v * 2 + 1][1] : ia[v * 2 + 1][0];                                  \
      int iz = jj ? e1 : e0;                                                                \
      float pv = selb ? (float)PC_[v][1] : (float)PC_[v][0];                                \
      z[v] = pv + FV_[v] * (float)iz;                                                       \
    }                                                                                       \
    float zi = z[0], zf = z[1], zg = z[2], zo = z[3];                                       \
    float ei = EXP2(-zi), ef = EXP2(-zf), eg = EXP2(-zg), eo = EXP2(-zo);                   \
    float di = 1.f + ei, df = 1.f + ef, dg = 1.f + eg, dof = 1.f + eo;                      \
    float r1 = RCP(di * df);                                                                \
    float si = r1 * df, sf = r1 * di;                                                       \
    float r2x = RCP(dg * dof);                                                              \
    float tg = 2.f * (r2x * dof) - 1.f, so = r2x * dg;                                      \
    float cc = sf * cst + si * tg;                                                          \
    cst = cc;                                                                               \
    float ec = EXP2(-L2E2 * cc);                                                            \
    float th = 2.f * RCP(1.f + ec) - 1.f;                                                   \
    float hh = so * th;                                                                     \
    int hq = (int)rintf(hh * 127.f);                                                        \
    hbuf[SP_ ^ 1][selb * 256 + (j ^ swzW)] = (char)hq;                                      \
    hid4[((size_t)b << 20) + ((size_t)t << 10) + (u << 8) + j] = (f16)hh;                   \
    WG_BARRIER();                                                                           \
  }

  LSTM_STEP(0, 0, Pa, Pb, fv4);
  for (int s = 1; s <= 1021; s += 2) {
    LSTM_STEP(s, 1, Pb, Pa, fv);
    LSTM_STEP(s + 1, 0, Pa, Pb, fv);
  }
  LSTM_STEP(1023, 1, Pb, Pa, fv);
#undef LSTM_STEP
}

// ---------------- emissions ----------------
__global__ __launch_bounds__(256) void emis_kernel(const f16* __restrict__ hid4,
                                                   const f16* __restrict__ wtag,
                                                   const float* __restrict__ btag,
                                                   const f16* __restrict__ wbin,
                                                   const float* __restrict__ bbin,
                                                   float* __restrict__ emis,
                                                   float* __restrict__ emisb) {
  const int tid = threadIdx.x;
  const int rl = tid >> 4, n = tid & 15;
  const size_t row = (size_t)blockIdx.x * 16 + rl;
  const f16x8* hv = (const f16x8*)(hid4 + row * 1024);
  const f16x8* wv = (const f16x8*)(wtag + n * 1024);
  float acc = btag[n];
#pragma unroll 8
  for (int kc = 0; kc < 128; ++kc) acc = dot8(wv[kc], hv[kc], acc);
  emis[row * 16 + n] = acc;
  if (n < 5) {
    const f16x8* hv2 = (const f16x8*)(hid4 + row * 1024 + 512);
    const f16x8* wv2 = (const f16x8*)(wbin + (size_t)n * 512);
    float a2 = bbin[n];
#pragma unroll 8
    for (int kc = 0; kc < 64; ++kc) a2 = dot8(wv2[kc], hv2[kc], a2);
    emisb[row * 5 + n] = a2;
  }
}

// ---------------- CRF forward (logZ): proven round-6 version ----------------
__global__ __launch_bounds__(64) void crf_logz(const float* __restrict__ emis,
                                               const float* __restrict__ trans,
                                               const float* __restrict__ emisb,
                                               const float* __restrict__ transb,
                                               const float* __restrict__ mask,
                                               float* __restrict__ outLogZ) {
  const int crf = blockIdx.x >> 5, b = blockIdx.x & 31;
  const int NTc = crf ? 5 : 16;
  const float* __restrict__ E = crf ? emisb : emis;
  const float* __restrict__ T = crf ? transb : trans;
  const int lane = threadIdx.x;
  const int jn = lane >> 2, p = lane & 3;
  const bool jv = (jn < NTc);
  const int jc = jv ? jn : 0;
  float Tc[4];
#pragma unroll
  for (int ii = 0; ii < 4; ++ii) {
    int i = p * 4 + ii;
    Tc[ii] = (jv && i < NTc) ? T[i * NTc + jn] : -1e30f;
  }
  __shared__ float as_[2][16];
  if (lane < 16) { as_[0][lane] = -1e30f; as_[1][lane] = -1e30f; }
  __syncthreads();
  float alpha = 0.f;
  if (jv && p == 0) {
    alpha = T[1 * NTc + jn] + E[(size_t)(b << 10) * NTc + jn];  // SOS=1, t=0
    as_[0][jn] = alpha;
  }
  __syncthreads();
  int cur = 0;
  const size_t ebase = (size_t)(b << 10) * NTc + jc;
  const int mbase = b << 10;
#define LDE(tt) E[ebase + (size_t)(tt)*NTc]
#define LDM(tt) mask[mbase + (tt)]

  auto step = [&](float e_tj, float m_t) {
    float v0 = (jv && (p * 4 + 0) < NTc) ? (as_[cur][p * 4 + 0] + Tc[0]) : -1e30f;
    float v1 = (jv && (p * 4 + 1) < NTc) ? (as_[cur][p * 4 + 1] + Tc[1]) : -1e30f;
    float v2 = (jv && (p * 4 + 2) < NTc) ? (as_[cur][p * 4 + 2] + Tc[2]) : -1e30f;
    float v3 = (jv && (p * 4 + 3) < NTc) ? (as_[cur][p * 4 + 3] + Tc[3]) : -1e30f;
    float mx = fmaxf(fmaxf(v0, v1), fmaxf(v2, v3));
    mx = fmaxf(mx, __shfl_xor(mx, 1, 4));
    mx = fmaxf(mx, __shfl_xor(mx, 2, 4));
    float ss = __expf(v0 - mx) + __expf(v1 - mx) + __expf(v2 - mx) + __expf(v3 - mx);
    ss += __shfl_xor(ss, 1, 4);
    ss += __shfl_xor(ss, 2, 4);
    if (jv && p == 0) {
      float newv = e_tj + mx + __logf(ss);
      alpha = (m_t > 0.5f) ? newv : alpha;
      as_[cur ^ 1][jn] = alpha;
    }
    __syncthreads();
    cur ^= 1;
  };

  float eb[4], mb[4];
#pragma unroll
  for (int k = 0; k < 4; ++k) { eb[k] = LDE(1 + k); mb[k] = LDM(1 + k); }
  for (int t = 1; t <= 1017; t += 4) {
    float en[4], mn[4];
#pragma unroll
    for (int k = 0; k < 4; ++k) {
      int ix = t + 4 + k;
      ix = ix > 1023 ? 1023 : ix;
      en[k] = LDE(ix);
      mn[k] = LDM(ix);
    }
    step(eb[0], mb[0]); step(eb[1], mb[1]); step(eb[2], mb[2]); step(eb[3], mb[3]);
#pragma unroll
    for (int k = 0; k < 4; ++k) { eb[k] = en[k]; mb[k] = mn[k]; }
  }
  step(eb[0], mb[0]); step(eb[1], mb[1]); step(eb[2], mb[2]);
#undef LDE
#undef LDM

  if (lane == 0) {
    float mx = -1e30f;
    for (int jjx = 0; jjx < NTc; ++jjx) mx = fmaxf(mx, as_[cur][jjx] + T[jjx * NTc + 2]);
    float ss = 0.f;
    for (int jjx = 0; jjx < NTc; ++jjx) ss += __expf(as_[cur][jjx] + T[jjx * NTc + 2] - mx);
    outLogZ[crf * 32 + b] = mx + __logf(ss);
  }
}

// ---------------- CRF gold score ----------------
__global__ __launch_bounds__(64) void crf_score(const float* __restrict__ emis,
                                                const float* __restrict__ trans,
                                                const float* __restrict__ emisb,
                                                const float* __restrict__ transb,
                                                const float* __restrict__ mask,
                                                const int* __restrict__ tags,
                                                const int* __restrict__ tagsb,
                                                float* __restrict__ outScore) {
  const int crf = blockIdx.x >> 5, b = blockIdx.x & 31;
  const int NTc = crf ? 5 : 16;
  const float* __restrict__ E = crf ? emisb : emis;
  const float* __restrict__ T = crf ? transb : trans;
  const int* __restrict__ tg = (crf ? tagsb : tags) + (b << 10);
  const float* __restrict__ mk = mask + (b << 10);
  const int lane = threadIdx.x;
  float s = 0.f, cnt = 0.f;
  for (int t = lane; t < S_LEN; t += 64) {
    float m = mk[t];
    cnt += m;
    if (t >= 1 && m > 0.5f)
      s += E[((size_t)(b << 10) + t) * NTc + tg[t]] + T[tg[t - 1] * NTc + tg[t]];
  }
#pragma unroll
  for (int off = 32; off >= 1; off >>= 1) {
    s += __shfl_down(s, off);
    cnt += __shfl_down(cnt, off);
  }
  if (lane == 0) {
    int L = (int)(cnt + 0.5f);
    int t0 = tg[0];
    float tot = T[1 * NTc + t0] + E[(size_t)(b << 10) * NTc + t0] + s + T[tg[L - 1] * NTc + 2];
    outScore[crf * 32 + b] = tot;
  }
}

__global__ void finalk(const float* __restrict__ logZ, const float* __restrict__ score,
                       float* __restrict__ out) {
  int j = threadIdx.x;
  if (j < 2) {
    float a = 0.f;
    for (int b = 0; b < 32; ++b) a += logZ[j * 32 + b] - score[j * 32 + b];
    out[j] = a;
  }
}

extern "C" void kernel_launch(void* const* d_in, const int* in_sizes, int n_in,
                              void* d_out, int out_size, void* d_ws, size_t ws_size,
                              hipStream_t stream) {
  const float* x       = (const float*)d_in[0];
  const float* xbin    = (const float*)d_in[1];
  const float* mask    = (const float*)d_in[2];
  const int*   tags    = (const int*)d_in[3];
  const int*   tagsb   = (const int*)d_in[4];
  const float* trans   = (const float*)d_in[5];
  const float* transb  = (const float*)d_in[6];
  const float* w2f_ih  = (const float*)d_in[7];
  const float* w2f_hh  = (const float*)d_in[8];
  const float* b2f_ih  = (const float*)d_in[9];
  const float* b2f_hh  = (const float*)d_in[10];
  const float* w2b_ih  = (const float*)d_in[11];
  const float* w2b_hh  = (const float*)d_in[12];
  const float* b2b_ih  = (const float*)d_in[13];
  const float* b2b_hh  = (const float*)d_in[14];
  const float* w_bin   = (const float*)d_in[15];
  const float* bb_bin  = (const float*)d_in[16];
  const float* w1f_ih  = (const float*)d_in[17];
  const float* w1f_hh  = (const float*)d_in[18];
  const float* b1f_ih  = (const float*)d_in[19];
  const float* b1f_hh  = (const float*)d_in[20];
  const float* w1b_ih  = (const float*)d_in[21];
  const float* w1b_hh  = (const float*)d_in[22];
  const float* b1b_ih  = (const float*)d_in[23];
  const float* b1b_hh  = (const float*)d_in[24];
  const float* w_tag   = (const float*)d_in[25];
  const float* b_tag   = (const float*)d_in[26];
  const float* h0_bin  = (const float*)d_in[27];
  const float* c0_bin  = (const float*)d_in[28];
  const float* h0_main = (const float*)d_in[29];
  const float* c0_main = (const float*)d_in[30];

  char* ws = (char*)d_ws;
  char* P4    = ws;                                   // 4u x 64MiB = 256MiB
  f16* hid4   = (f16*)(ws + 268435456);               // 64MiB
  char* Wq4   = ws + 335544320;                       // 1MiB
  float* fsc4 = (float*)(ws + 336592896);             // 16KB
  f16* wtag   = (f16*)(ws + 336609280);
  f16* wbin   = (f16*)(ws + 336642048);
  float* emis  = (float*)(ws + 336647168);            // 2MiB
  float* emisb = (float*)(ws + 338744320);
  float* logZ  = (float*)(ws + 339399680);
  float* score = (float*)(ws + 339399936);
  float* bsum  = (float*)(ws + 339400704);            // 16KB
  f16* w16all  = (f16*)(ws + 340000768);              // 8MiB, ends 348389376

  // weight preps
  quant_whh<<<256, 256, 0, stream>>>(w1f_hh, Wq4 + 0 * 262144, fsc4 + 0 * 1024);
  quant_whh<<<256, 256, 0, stream>>>(w1b_hh, Wq4 + 1 * 262144, fsc4 + 1 * 1024);
  quant_whh<<<256, 256, 0, stream>>>(w2f_hh, Wq4 + 2 * 262144, fsc4 + 2 * 1024);
  quant_whh<<<256, 256, 0, stream>>>(w2b_hh, Wq4 + 3 * 262144, fsc4 + 3 * 1024);
  cvt_f32_f16<<<16, 256, 0, stream>>>(w_tag, wtag, 4096);
  cvt_f32_f16<<<3, 256, 0, stream>>>(w_bin, wbin, 640);
  cvt_wih<<<256, 256, 0, stream>>>(w1f_ih, w16all + 0, 512, 65536);
  cvt_wih<<<256, 256, 0, stream>>>(w1b_ih, w16all + 524288, 512, 65536);
  cvt_wih<<<768, 256, 0, stream>>>(w2f_ih, w16all + 1048576, 1536, 196608);
  cvt_wih<<<768, 256, 0, stream>>>(w2b_ih, w16all + 2621440, 1536, 196608);
  bias_pack<<<16, 256, 0, stream>>>(b1f_ih, b1f_hh, b1b_ih, b1b_hh,
                                    b2f_ih, b2f_hh, b2b_ih, b2b_hh, bsum);

  // fused input projections: blockIdx.x = unit*4 + v
  dim3 gg(16, 256);
  proj_gemm<<<gg, 256, 0, stream>>>(x, xbin, w16all, bsum, P4);

  lstm_rec5<<<64, 512, 0, stream>>>(Wq4, fsc4, P4, h0_main, c0_main, h0_bin, c0_bin, hid4);
  emis_kernel<<<2048, 256, 0, stream>>>(hid4, wtag, b_tag, wbin, bb_bin, emis, emisb);
  crf_logz<<<64, 64, 0, stream>>>(emis, trans, emisb, transb, mask, logZ);
  crf_score<<<64, 64, 0, stream>>>(emis, trans, emisb, transb, mask, tags, tagsb, score);
  finalk<<<1, 64, 0, stream>>>(logZ, score, (float*)d_out);
}

// Round 10
// 2323.027 us; speedup vs baseline: 1.8855x; 1.8855x over previous
//
#include <hip/hip_runtime.h>

typedef _Float16 f16;
typedef _Float16 f16x2 __attribute__((ext_vector_type(2)));
typedef _Float16 f16x4 __attribute__((ext_vector_type(4)));
typedef _Float16 f16x8 __attribute__((ext_vector_type(8)));
typedef float f32x4 __attribute__((ext_vector_type(4)));
typedef int iv4 __attribute__((ext_vector_type(4)));

#define S_LEN 1024
#define BATCH 32
#define HID 256
#define L2E 1.4426950408889634f
#define L2E2 2.8853900817779268f

#if __has_builtin(__builtin_amdgcn_fdot2)
#define FDOT2(a, b, c) __builtin_amdgcn_fdot2((a), (b), (c), false)
#else
static __device__ __forceinline__ float FDOT2(f16x2 a, f16x2 b, float c) {
  return c + (float)a[0] * (float)b[0] + (float)a[1] * (float)b[1];
}
#endif

__device__ __forceinline__ float EXP2(float x) {
#if __has_builtin(__builtin_amdgcn_exp2f)
  return __builtin_amdgcn_exp2f(x);
#else
  return exp2f(x);
#endif
}
__device__ __forceinline__ float RCP(float x) {
#if __has_builtin(__builtin_amdgcn_rcpf)
  return __builtin_amdgcn_rcpf(x);
#else
  return 1.0f / x;
#endif
}

__device__ __forceinline__ iv4 cvt8(float4 a, float4 b) {
#if __has_builtin(__builtin_amdgcn_cvt_pkrtz)
  auto p0 = __builtin_amdgcn_cvt_pkrtz(a.x, a.y);
  auto p1 = __builtin_amdgcn_cvt_pkrtz(a.z, a.w);
  auto p2 = __builtin_amdgcn_cvt_pkrtz(b.x, b.y);
  auto p3 = __builtin_amdgcn_cvt_pkrtz(b.z, b.w);
  iv4 o;
  o[0] = __builtin_bit_cast(int, p0);
  o[1] = __builtin_bit_cast(int, p1);
  o[2] = __builtin_bit_cast(int, p2);
  o[3] = __builtin_bit_cast(int, p3);
  return o;
#else
  f16x8 h;
  h[0] = (f16)a.x; h[1] = (f16)a.y; h[2] = (f16)a.z; h[3] = (f16)a.w;
  h[4] = (f16)b.x; h[5] = (f16)b.y; h[6] = (f16)b.z; h[7] = (f16)b.w;
  return __builtin_bit_cast(iv4, h);
#endif
}

#if __has_builtin(__builtin_amdgcn_global_load_lds)
__device__ __forceinline__ void gload16(const void* g, void* l) {
  __builtin_amdgcn_global_load_lds((const __attribute__((address_space(1))) void*)g,
                                   (__attribute__((address_space(3))) void*)l, 16, 0, 0);
}
#else
__device__ __forceinline__ void gload16(const void* g, void* l) {
  int lane = __builtin_amdgcn_mbcnt_hi(~0u, __builtin_amdgcn_mbcnt_lo(~0u, 0));
  ((f16x8*)l)[lane] = *(const f16x8*)g;  // emulate base + lane*16
}
#endif

// barrier that waits LDS only (no vmcnt drain)
#define WG_BARRIER()                                                  \
  do {                                                                \
    __builtin_amdgcn_sched_barrier(0);                                \
    asm volatile("s_waitcnt lgkmcnt(0)\n\ts_barrier" ::: "memory");   \
    __builtin_amdgcn_sched_barrier(0);                                \
  } while (0)

__device__ __forceinline__ float dot8(f16x8 w, f16x8 h, float acc) {
  f16x2 a, b;
  a[0] = w[0]; a[1] = w[1]; b[0] = h[0]; b[1] = h[1]; acc = FDOT2(a, b, acc);
  a[0] = w[2]; a[1] = w[3]; b[0] = h[2]; b[1] = h[3]; acc = FDOT2(a, b, acc);
  a[0] = w[4]; a[1] = w[5]; b[0] = h[4]; b[1] = h[5]; acc = FDOT2(a, b, acc);
  a[0] = w[6]; a[1] = w[7]; b[0] = h[6]; b[1] = h[7]; acc = FDOT2(a, b, acc);
  return acc;
}

// ---------------- f32 -> f16 convert (plain) ----------------
__global__ void cvt_f32_f16(const float* __restrict__ src, f16* __restrict__ dst, int n4) {
  int i = blockIdx.x * 256 + threadIdx.x;
  if (i < n4) {
    float4 v = ((const float4*)src)[i];
    f16x4 h;
    h[0] = (f16)v.x; h[1] = (f16)v.y; h[2] = (f16)v.z; h[3] = (f16)v.w;
    ((f16x4*)dst)[i] = h;
  }
}

// ---------------- w_ih f32 -> f16, log2e row-scaled ----------------
__global__ void cvt_wih(const float* __restrict__ src, f16* __restrict__ dst, int K, int total8) {
  int i = blockIdx.x * 256 + threadIdx.x;
  if (i < total8) {
    int row = (int)(((long long)i * 8) / K);
    float sc = (row >= 512 && row < 768) ? L2E2 : L2E;
    const float* s = src + (size_t)i * 8;
    float4 a = *(const float4*)s;
    float4 b = *(const float4*)(s + 4);
    f16x8 h;
    h[0] = (f16)(a.x * sc); h[1] = (f16)(a.y * sc); h[2] = (f16)(a.z * sc); h[3] = (f16)(a.w * sc);
    h[4] = (f16)(b.x * sc); h[5] = (f16)(b.y * sc); h[6] = (f16)(b.z * sc); h[7] = (f16)(b.w * sc);
    *(f16x8*)(dst + (size_t)i * 8) = h;
  }
}

// ---------------- bias pack: bsum[u][n] = (bih+bhh)*sc ----------------
__global__ void bias_pack(const float* __restrict__ a0, const float* __restrict__ h0,
                          const float* __restrict__ a1, const float* __restrict__ h1,
                          const float* __restrict__ a2, const float* __restrict__ h2,
                          const float* __restrict__ a3, const float* __restrict__ h3,
                          float* __restrict__ bsum) {
  int i = blockIdx.x * 256 + threadIdx.x;
  if (i < 4096) {
    int u = i >> 10, n = i & 1023;
    float sc = (n >= 512 && n < 768) ? L2E2 : L2E;
    const float* pa = u == 0 ? a0 : u == 1 ? a1 : u == 2 ? a2 : a3;
    const float* ph = u == 0 ? h0 : u == 1 ? h1 : u == 2 ? h2 : h3;
    bsum[i] = (pa[n] + ph[n]) * sc;
  }
}

// ---------------- whh f32 -> i8 per-row symmetric quant, log2e pre-scaled ----------------
__global__ __launch_bounds__(256) void quant_whh(const float* __restrict__ src,
                                                 char* __restrict__ dstq,
                                                 float* __restrict__ fsc) {
  const int row = blockIdx.x * 4 + (threadIdx.x >> 6);
  const int lane = threadIdx.x & 63;
  const float sc = (row >= 512 && row < 768) ? L2E2 : L2E;
  float4 v = *(const float4*)(src + (size_t)row * 256 + lane * 4);
  float w0 = v.x * sc, w1 = v.y * sc, w2 = v.z * sc, w3 = v.w * sc;
  float mx = fmaxf(fmaxf(fabsf(w0), fabsf(w1)), fmaxf(fabsf(w2), fabsf(w3)));
#pragma unroll
  for (int off = 1; off < 64; off <<= 1) mx = fmaxf(mx, __shfl_xor(mx, off));
  mx = fmaxf(mx, 1e-20f);
  float inv = 127.0f / mx;
  int q0 = (int)rintf(w0 * inv), q1 = (int)rintf(w1 * inv);
  int q2 = (int)rintf(w2 * inv), q3 = (int)rintf(w3 * inv);
  int pk = (q0 & 0xff) | ((q1 & 0xff) << 8) | ((q2 & 0xff) << 16) | ((q3 & 0xff) << 24);
  ((int*)(dstq + (size_t)row * 256))[lane] = pk;
  if (lane == 0) fsc[row] = mx / 16129.0f;
}

// ---------------- fused input-projection GEMM -> P4 planes ----------------
// grid (16, 256): unit = bx>>2, v = bx&3. Tile: 4 batches x 32 t x 256 cols, K-step 64.
// Round-8 skeleton + (a) B via global_load_lds with pre-swizzled global source,
// (b) granule^row XOR swizzle on both tiles (reads 16-way -> 2-way conflict).
__global__ __launch_bounds__(256) void proj_gemm(const float* __restrict__ x,
                                                 const float* __restrict__ xbin,
                                                 const f16* __restrict__ w16all,
                                                 const float* __restrict__ bsum,
                                                 char* __restrict__ P4) {
  __shared__ __align__(16) char smem[65536];  // As [0,16K) swz ; Bs [16K,48K) swz ; epilogue all
  const int unit = blockIdx.x >> 2;
  const int v = blockIdx.x & 3;
  const int bm = blockIdx.y;
  const int K = (unit < 2) ? 512 : 1536;
  const float* Aptr = (unit < 2) ? x : xbin;
  const size_t woff = (unit == 0) ? 0u : (unit == 1) ? 524288u : (unit == 2) ? 1048576u : 2621440u;
  const f16* W16 = w16all + woff;
  const int bgrp = bm >> 5, t0 = (bm & 31) * 32;
  const int b0 = bgrp * 4, c = bgrp >> 1, lkb = bgrp & 1;
  const int tid = threadIdx.x;
  const int lane = tid & 63, wid = tid >> 6;
  const int wm = wid >> 1, wn = wid & 1;
  const int lr = lane & 15, lk = lane >> 4;
  const int xsw = (lr & 7) << 4;  // read-side granule swizzle

  f32x4 acc[4][8];
#pragma unroll
  for (int i = 0; i < 4; ++i)
#pragma unroll
    for (int n = 0; n < 8; ++n) acc[i][n] = (f32x4){0.f, 0.f, 0.f, 0.f};

  for (int k0 = 0; k0 < K; k0 += 64) {
    // issue B DMA first (fire-and-forget; lands during A staging)
#pragma unroll
    for (int i = 0; i < 8; ++i) {
      int g = (wid * 8 + i) * 64 + lane;  // granule index 0..2047
      int brow = g >> 3, cg = g & 7;
      const f16* bsrc = W16 + (size_t)(v * 256 + brow) * K + k0 + ((cg ^ (brow & 7)) << 3);
      gload16(bsrc, smem + 16384 + (wid * 8 + i) * 1024);
    }
    // stage A: load f32, cvt_pkrtz, swizzled ds_write (4 slots/thread)
#pragma unroll
    for (int s = 0; s < 4; ++s) {
      int slot = s * 256 + tid;
      int row = slot >> 3, seg = slot & 7;
      size_t arow = (size_t)(b0 + (row >> 5)) * 1024 + t0 + (row & 31);
      const float* ga = Aptr + arow * K + k0 + seg * 8;
      float4 v0 = *(const float4*)ga;
      float4 v1 = *(const float4*)(ga + 4);
      *(iv4*)(smem + row * 128 + ((seg ^ (row & 7)) << 4)) = cvt8(v0, v1);
    }
    __syncthreads();  // drains vmcnt (B DMA) + lgkm (A writes)
#pragma unroll
    for (int kk = 0; kk < 2; ++kk) {
      f16x8 af[4], bf[8];
#pragma unroll
      for (int mi = 0; mi < 4; ++mi) {
        int ba = (wm * 64 + mi * 16 + lr) * 128 + kk * 64 + lk * 16;
        af[mi] = *(const f16x8*)(smem + (ba ^ xsw));
      }
#pragma unroll
      for (int ni = 0; ni < 8; ++ni) {
        int bb = (wn * 128 + ni * 16 + lr) * 128 + kk * 64 + lk * 16;
        bf[ni] = *(const f16x8*)(smem + 16384 + (bb ^ xsw));
      }
#pragma unroll
      for (int mi = 0; mi < 4; ++mi)
#pragma unroll
        for (int ni = 0; ni < 8; ++ni)
          acc[mi][ni] = __builtin_amdgcn_mfma_f32_16x16x32_f16(af[mi], bf[ni], acc[mi][ni], 0, 0, 0);
    }
    __syncthreads();
  }

  // epilogue: acc -> LDS (swizzled) -> coalesced 8B stores (round-5/6 proven)
  float biasv[8];
#pragma unroll
  for (int ni = 0; ni < 8; ++ni)
    biasv[ni] = bsum[unit * 1024 + v * 256 + wn * 128 + ni * 16 + lr];
#pragma unroll
  for (int mi = 0; mi < 4; ++mi) {
#pragma unroll
    for (int ni = 0; ni < 8; ++ni) {
      int col = wn * 128 + ni * 16 + lr;
      int wc = col >> 5, jc = (col >> 4) & 1, lc = col & 15;
#pragma unroll
      for (int rr = 0; rr < 4; ++rr) {
        int row = wm * 64 + mi * 16 + lk * 4 + rr;
        int bsub = row >> 5, t_loc = row & 31;
        int unit2 = t_loc * 256 + wc * 32 + jc * 16 + lc;
        int off = (unit2 * 8 + bsub * 2) ^ ((t_loc & 7) << 4);
        *(f16*)(smem + off) = (f16)(acc[mi][ni][rr] + biasv[ni]);
      }
    }
  }
  __syncthreads();
  char* Pv = P4 + ((size_t)unit << 26) + ((size_t)v << 24);
#pragma unroll
  for (int k = 0; k < 32; ++k) {
    int uid = k * 256 + tid;
    int t_loc = uid >> 8, sub = uid & 255;
    int off = (uid * 8) ^ ((t_loc & 7) << 4);
    unsigned long long val = *(const unsigned long long*)(smem + off);
    int wq = sub >> 5, jq = (sub >> 4) & 1, lq = sub & 15;
    size_t didx = (((size_t)((t0 + t_loc) * 4 + c) * 512) + wq * 64 + jq * 32 + lkb * 16 + lq) << 3;
    *(unsigned long long*)(Pv + didx) = val;
  }
}

// ---------------- LSTM recurrence: 64 WGs = (unit, batch-pair), i8 MFMA, 1 cell/lane ----------------
__global__ __attribute__((amdgpu_flat_work_group_size(512, 512), amdgpu_waves_per_eu(2, 2)))
void lstm_rec5(const char* __restrict__ Wq4,
               const float* __restrict__ fsc4,
               const char* __restrict__ P4,
               const float* __restrict__ h0m,
               const float* __restrict__ c0m,
               const float* __restrict__ h0b,
               const float* __restrict__ c0b,
               f16* __restrict__ hid4) {
  const int wg = blockIdx.x;
  const int u = wg >> 4, c16 = wg & 15;
  const int dir = u & 1;
  const int tid = threadIdx.x;
  const int l = tid & 63, w = tid >> 6;
  const int lr = l & 15, lk = l >> 4;
  const int jj = lk >> 1, selb = lk & 1;
  const int r2 = lr & 1;
  const int swzA = r2 ? 80 : 0;
  const int swzW = selb ? 80 : 0;
  const int j = w * 32 + jj * 16 + lr;  // hidden unit owned by this lane

  __shared__ __align__(16) char hbuf[2][512];  // [2 batch rows][256 k] i8, swizzled

  // ---- weights: 32 x iv4 = 128 regs; n = v*256 + w*32 + (nt&1)*16 + lr ----
  iv4 Bf[4][8];
  const char* wb = Wq4 + ((size_t)u << 18);
#pragma unroll
  for (int nt = 0; nt < 8; ++nt) {
    int n = (nt >> 1) * 256 + w * 32 + ((nt & 1) << 4) + lr;
#pragma unroll
    for (int ks = 0; ks < 4; ++ks)
      Bf[ks][nt] = *(const iv4*)(wb + (size_t)n * 256 + ks * 64 + lk * 16);
  }
  float fv[4], fv4[4];
#pragma unroll
  for (int v = 0; v < 4; ++v) {
    fv[v] = fsc4[u * 1024 + v * 256 + j];
    fv4[v] = fv[v] * 4.f;
  }

  // ---- init c / h0 (h0 quantized at scale 127/4, step-0 uses fv4) ----
  const int b = c16 * 2 + selb;
  const float* h0 = (u < 2 ? h0m : h0b) + (size_t)dir * BATCH * HID;
  const float* c0 = (u < 2 ? c0m : c0b) + (size_t)dir * BATCH * HID;
  float cst = c0[b * HID + j];
  {
    float hv = h0[b * HID + j] * 31.75f;
    int hq = (int)rintf(hv);
    hq = hq > 127 ? 127 : (hq < -127 ? -127 : hq);
    hbuf[0][selb * 256 + (j ^ swzW)] = (char)hq;
  }

  // ---- P preload for s=0 ----
  const char* Pc = P4 + ((size_t)u << 26);
  const size_t soff =
      (size_t)((w * 64 + jj * 32 + (((c16 >> 1) & 1) << 4) + lr) * 8 + (c16 & 1) * 4);
  const int cq = c16 >> 2;
  f16x2 Pa[4], Pb[4];
  {
    int t0 = dir ? (S_LEN - 1) : 0;
    size_t tb = ((size_t)((t0 << 2) + cq) << 12) + soff;
#pragma unroll
    for (int v = 0; v < 4; ++v) Pa[v] = *(const f16x2*)(Pc + ((size_t)v << 24) + tb);
  }
  WG_BARRIER();

#define LSTM_STEP(S_, SP_, PC_, PN_, FV_)                                                   \
  {                                                                                         \
    const int t = dir ? (S_LEN - 1 - (S_)) : (S_);                                          \
    {                                                                                       \
      int s2 = ((S_) + 1 < S_LEN) ? (S_) + 1 : (S_);                                        \
      int t2 = dir ? (S_LEN - 1 - s2) : s2;                                                 \
      size_t tb = ((size_t)((t2 << 2) + cq) << 12) + soff;                                  \
      _Pragma("unroll") for (int v = 0; v < 4; ++v)                                         \
          PN_[v] = *(const f16x2*)(Pc + ((size_t)v << 24) + tb);                            \
    }                                                                                       \
    iv4 ia[8];                                                                              \
    _Pragma("unroll") for (int nt = 0; nt < 8; ++nt) ia[nt] = (iv4){0, 0, 0, 0};            \
    const char* hb = hbuf[SP_];                                                             \
    _Pragma("unroll") for (int ks = 0; ks < 4; ++ks) {                                      \
      iv4 Af = *(const iv4*)(hb + r2 * 256 + ((ks * 64 + lk * 16) ^ swzA));                 \
      _Pragma("unroll") for (int nt = 0; nt < 8; ++nt)                                      \
          ia[nt] = __builtin_amdgcn_mfma_i32_16x16x64_i8(Af, Bf[ks][nt], ia[nt], 0, 0, 0);  \
    }                                                                                       \
    float z[4];                                                                             \
    _Pragma("unroll") for (int v = 0; v < 4; ++v) {                                         \
      int e0 = selb ? ia[v * 2][1] : ia[v * 2][0];                                          \
      int e1 = selb ? ia[v * 2 + 1][1] : ia[v * 2 + 1][0];                                  \
      int iz = jj ? e1 : e0;                                                                \
      float pv = selb ? (float)PC_[v][1] : (float)PC_[v][0];                                \
      z[v] = pv + FV_[v] * (float)iz;                                                       \
    }                                                                                       \
    float zi = z[0], zf = z[1], zg = z[2], zo = z[3];                                       \
    float ei = EXP2(-zi), ef = EXP2(-zf), eg = EXP2(-zg), eo = EXP2(-zo);                   \
    float di = 1.f + ei, df = 1.f + ef, dg = 1.f + eg, dof = 1.f + eo;                      \
    float r1 = RCP(di * df);                                                                \
    float si = r1 * df, sf = r1 * di;                                                       \
    float r2x = RCP(dg * dof);                                                              \
    float tg = 2.f * (r2x * dof) - 1.f, so = r2x * dg;                                      \
    float cc = sf * cst + si * tg;                                                          \
    cst = cc;                                                                               \
    float ec = EXP2(-L2E2 * cc);                                                            \
    float th = 2.f * RCP(1.f + ec) - 1.f;                                                   \
    float hh = so * th;                                                                     \
    int hq = (int)rintf(hh * 127.f);                                                        \
    hbuf[SP_ ^ 1][selb * 256 + (j ^ swzW)] = (char)hq;                                      \
    hid4[((size_t)b << 20) + ((size_t)t << 10) + (u << 8) + j] = (f16)hh;                   \
    WG_BARRIER();                                                                           \
  }

  LSTM_STEP(0, 0, Pa, Pb, fv4);
  for (int s = 1; s <= 1021; s += 2) {
    LSTM_STEP(s, 1, Pb, Pa, fv);
    LSTM_STEP(s + 1, 0, Pa, Pb, fv);
  }
  LSTM_STEP(1023, 1, Pb, Pa, fv);
#undef LSTM_STEP
}

// ---------------- emissions ----------------
__global__ __launch_bounds__(256) void emis_kernel(const f16* __restrict__ hid4,
                                                   const f16* __restrict__ wtag,
                                                   const float* __restrict__ btag,
                                                   const f16* __restrict__ wbin,
                                                   const float* __restrict__ bbin,
                                                   float* __restrict__ emis,
                                                   float* __restrict__ emisb) {
  const int tid = threadIdx.x;
  const int rl = tid >> 4, n = tid & 15;
  const size_t row = (size_t)blockIdx.x * 16 + rl;
  const f16x8* hv = (const f16x8*)(hid4 + row * 1024);
  const f16x8* wv = (const f16x8*)(wtag + n * 1024);
  float acc = btag[n];
#pragma unroll 8
  for (int kc = 0; kc < 128; ++kc) acc = dot8(wv[kc], hv[kc], acc);
  emis[row * 16 + n] = acc;
  if (n < 5) {
    const f16x8* hv2 = (const f16x8*)(hid4 + row * 1024 + 512);
    const f16x8* wv2 = (const f16x8*)(wbin + (size_t)n * 512);
    float a2 = bbin[n];
#pragma unroll 8
    for (int kc = 0; kc < 64; ++kc) a2 = dot8(wv2[kc], hv2[kc], a2);
    emisb[row * 5 + n] = a2;
  }
}

// ---------------- CRF forward (logZ): proven round-6 version ----------------
__global__ __launch_bounds__(64) void crf_logz(const float* __restrict__ emis,
                                               const float* __restrict__ trans,
                                               const float* __restrict__ emisb,
                                               const float* __restrict__ transb,
                                               const float* __restrict__ mask,
                                               float* __restrict__ outLogZ) {
  const int crf = blockIdx.x >> 5, b = blockIdx.x & 31;
  const int NTc = crf ? 5 : 16;
  const float* __restrict__ E = crf ? emisb : emis;
  const float* __restrict__ T = crf ? transb : trans;
  const int lane = threadIdx.x;
  const int jn = lane >> 2, p = lane & 3;
  const bool jv = (jn < NTc);
  const int jc = jv ? jn : 0;
  float Tc[4];
#pragma unroll
  for (int ii = 0; ii < 4; ++ii) {
    int i = p * 4 + ii;
    Tc[ii] = (jv && i < NTc) ? T[i * NTc + jn] : -1e30f;
  }
  __shared__ float as_[2][16];
  if (lane < 16) { as_[0][lane] = -1e30f; as_[1][lane] = -1e30f; }
  __syncthreads();
  float alpha = 0.f;
  if (jv && p == 0) {
    alpha = T[1 * NTc + jn] + E[(size_t)(b << 10) * NTc + jn];  // SOS=1, t=0
    as_[0][jn] = alpha;
  }
  __syncthreads();
  int cur = 0;
  const size_t ebase = (size_t)(b << 10) * NTc + jc;
  const int mbase = b << 10;
#define LDE(tt) E[ebase + (size_t)(tt)*NTc]
#define LDM(tt) mask[mbase + (tt)]

  auto step = [&](float e_tj, float m_t) {
    float v0 = (jv && (p * 4 + 0) < NTc) ? (as_[cur][p * 4 + 0] + Tc[0]) : -1e30f;
    float v1 = (jv && (p * 4 + 1) < NTc) ? (as_[cur][p * 4 + 1] + Tc[1]) : -1e30f;
    float v2 = (jv && (p * 4 + 2) < NTc) ? (as_[cur][p * 4 + 2] + Tc[2]) : -1e30f;
    float v3 = (jv && (p * 4 + 3) < NTc) ? (as_[cur][p * 4 + 3] + Tc[3]) : -1e30f;
    float mx = fmaxf(fmaxf(v0, v1), fmaxf(v2, v3));
    mx = fmaxf(mx, __shfl_xor(mx, 1, 4));
    mx = fmaxf(mx, __shfl_xor(mx, 2, 4));
    float ss = __expf(v0 - mx) + __expf(v1 - mx) + __expf(v2 - mx) + __expf(v3 - mx);
    ss += __shfl_xor(ss, 1, 4);
    ss += __shfl_xor(ss, 2, 4);
    if (jv && p == 0) {
      float newv = e_tj + mx + __logf(ss);
      alpha = (m_t > 0.5f) ? newv : alpha;
      as_[cur ^ 1][jn] = alpha;
    }
    __syncthreads();
    cur ^= 1;
  };

  float eb[4], mb[4];
#pragma unroll
  for (int k = 0; k < 4; ++k) { eb[k] = LDE(1 + k); mb[k] = LDM(1 + k); }
  for (int t = 1; t <= 1017; t += 4) {
    float en[4], mn[4];
#pragma unroll
    for (int k = 0; k < 4; ++k) {
      int ix = t + 4 + k;
      ix = ix > 1023 ? 1023 : ix;
      en[k] = LDE(ix);
      mn[k] = LDM(ix);
    }
    step(eb[0], mb[0]); step(eb[1], mb[1]); step(eb[2], mb[2]); step(eb[3], mb[3]);
#pragma unroll
    for (int k = 0; k < 4; ++k) { eb[k] = en[k]; mb[k] = mn[k]; }
  }
  step(eb[0], mb[0]); step(eb[1], mb[1]); step(eb[2], mb[2]);
#undef LDE
#undef LDM

  if (lane == 0) {
    float mx = -1e30f;
    for (int jjx = 0; jjx < NTc; ++jjx) mx = fmaxf(mx, as_[cur][jjx] + T[jjx * NTc + 2]);
    float ss = 0.f;
    for (int jjx = 0; jjx < NTc; ++jjx) ss += __expf(as_[cur][jjx] + T[jjx * NTc + 2] - mx);
    outLogZ[crf * 32 + b] = mx + __logf(ss);
  }
}

// ---------------- CRF gold score ----------------
__global__ __launch_bounds__(64) void crf_score(const float* __restrict__ emis,
                                                const float* __restrict__ trans,
                                                const float* __restrict__ emisb,
                                                const float* __restrict__ transb,
                                                const float* __restrict__ mask,
                                                const int* __restrict__ tags,
                                                const int* __restrict__ tagsb,
                                                float* __restrict__ outScore) {
  const int crf = blockIdx.x >> 5, b = blockIdx.x & 31;
  const int NTc = crf ? 5 : 16;
  const float* __restrict__ E = crf ? emisb : emis;
  const float* __restrict__ T = crf ? transb : trans;
  const int* __restrict__ tg = (crf ? tagsb : tags) + (b << 10);
  const float* __restrict__ mk = mask + (b << 10);
  const int lane = threadIdx.x;
  float s = 0.f, cnt = 0.f;
  for (int t = lane; t < S_LEN; t += 64) {
    float m = mk[t];
    cnt += m;
    if (t >= 1 && m > 0.5f)
      s += E[((size_t)(b << 10) + t) * NTc + tg[t]] + T[tg[t - 1] * NTc + tg[t]];
  }
#pragma unroll
  for (int off = 32; off >= 1; off >>= 1) {
    s += __shfl_down(s, off);
    cnt += __shfl_down(cnt, off);
  }
  if (lane == 0) {
    int L = (int)(cnt + 0.5f);
    int t0 = tg[0];
    float tot = T[1 * NTc + t0] + E[(size_t)(b << 10) * NTc + t0] + s + T[tg[L - 1] * NTc + 2];
    outScore[crf * 32 + b] = tot;
  }
}

__global__ void finalk(const float* __restrict__ logZ, const float* __restrict__ score,
                       float* __restrict__ out) {
  int j = threadIdx.x;
  if (j < 2) {
    float a = 0.f;
    for (int b = 0; b < 32; ++b) a += logZ[j * 32 + b] - score[j * 32 + b];
    out[j] = a;
  }
}

extern "C" void kernel_launch(void* const* d_in, const int* in_sizes, int n_in,
                              void* d_out, int out_size, void* d_ws, size_t ws_size,
                              hipStream_t stream) {
  const float* x       = (const float*)d_in[0];
  const float* xbin    = (const float*)d_in[1];
  const float* mask    = (const float*)d_in[2];
  const int*   tags    = (const int*)d_in[3];
  const int*   tagsb   = (const int*)d_in[4];
  const float* trans   = (const float*)d_in[5];
  const float* transb  = (const float*)d_in[6];
  const float* w2f_ih  = (const float*)d_in[7];
  const float* w2f_hh  = (const float*)d_in[8];
  const float* b2f_ih  = (const float*)d_in[9];
  const float* b2f_hh  = (const float*)d_in[10];
  const float* w2b_ih  = (const float*)d_in[11];
  const float* w2b_hh  = (const float*)d_in[12];
  const float* b2b_ih  = (const float*)d_in[13];
  const float* b2b_hh  = (const float*)d_in[14];
  const float* w_bin   = (const float*)d_in[15];
  const float* bb_bin  = (const float*)d_in[16];
  const float* w1f_ih  = (const float*)d_in[17];
  const float* w1f_hh  = (const float*)d_in[18];
  const float* b1f_ih  = (const float*)d_in[19];
  const float* b1f_hh  = (const float*)d_in[20];
  const float* w1b_ih  = (const float*)d_in[21];
  const float* w1b_hh  = (const float*)d_in[22];
  const float* b1b_ih  = (const float*)d_in[23];
  const float* b1b_hh  = (const float*)d_in[24];
  const float* w_tag   = (const float*)d_in[25];
  const float* b_tag   = (const float*)d_in[26];
  const float* h0_bin  = (const float*)d_in[27];
  const float* c0_bin  = (const float*)d_in[28];
  const float* h0_main = (const float*)d_in[29];
  const float* c0_main = (const float*)d_in[30];

  char* ws = (char*)d_ws;
  char* P4    = ws;                                   // 4u x 64MiB = 256MiB
  f16* hid4   = (f16*)(ws + 268435456);               // 64MiB
  char* Wq4   = ws + 335544320;                       // 1MiB
  float* fsc4 = (float*)(ws + 336592896);             // 16KB
  f16* wtag   = (f16*)(ws + 336609280);
  f16* wbin   = (f16*)(ws + 336642048);
  float* emis  = (float*)(ws + 336647168);            // 2MiB
  float* emisb = (float*)(ws + 338744320);
  float* logZ  = (float*)(ws + 339399680);
  float* score = (float*)(ws + 339399936);
  float* bsum  = (float*)(ws + 339400704);            // 16KB
  f16* w16all  = (f16*)(ws + 340000768);              // 8MiB, ends 348389376

  // weight preps
  quant_whh<<<256, 256, 0, stream>>>(w1f_hh, Wq4 + 0 * 262144, fsc4 + 0 * 1024);
  quant_whh<<<256, 256, 0, stream>>>(w1b_hh, Wq4 + 1 * 262144, fsc4 + 1 * 1024);
  quant_whh<<<256, 256, 0, stream>>>(w2f_hh, Wq4 + 2 * 262144, fsc4 + 2 * 1024);
  quant_whh<<<256, 256, 0, stream>>>(w2b_hh, Wq4 + 3 * 262144, fsc4 + 3 * 1024);
  cvt_f32_f16<<<16, 256, 0, stream>>>(w_tag, wtag, 4096);
  cvt_f32_f16<<<3, 256, 0, stream>>>(w_bin, wbin, 640);
  cvt_wih<<<256, 256, 0, stream>>>(w1f_ih, w16all + 0, 512, 65536);
  cvt_wih<<<256, 256, 0, stream>>>(w1b_ih, w16all + 524288, 512, 65536);
  cvt_wih<<<768, 256, 0, stream>>>(w2f_ih, w16all + 1048576, 1536, 196608);
  cvt_wih<<<768, 256, 0, stream>>>(w2b_ih, w16all + 2621440, 1536, 196608);
  bias_pack<<<16, 256, 0, stream>>>(b1f_ih, b1f_hh, b1b_ih, b1b_hh,
                                    b2f_ih, b2f_hh, b2b_ih, b2b_hh, bsum);

  // fused input projections: blockIdx.x = unit*4 + v
  dim3 gg(16, 256);
  proj_gemm<<<gg, 256, 0, stream>>>(x, xbin, w16all, bsum, P4);

  lstm_rec5<<<64, 512, 0, stream>>>(Wq4, fsc4, P4, h0_main, c0_main, h0_bin, c0_bin, hid4);
  emis_kernel<<<2048, 256, 0, stream>>>(hid4, wtag, b_tag, wbin, bb_bin, emis, emisb);
  crf_logz<<<64, 64, 0, stream>>>(emis, trans, emisb, transb, mask, logZ);
  crf_score<<<64, 64, 0, stream>>>(emis, trans, emisb, transb, mask, tags, tagsb, score);
  finalk<<<1, 64, 0, stream>>>(logZ, score, (float*)d_out);
}

// Round 11
// 1988.229 us; speedup vs baseline: 2.2030x; 1.1684x over previous
//
#include <hip/hip_runtime.h>

typedef _Float16 f16;
typedef _Float16 f16x2 __attribute__((ext_vector_type(2)));
typedef _Float16 f16x4 __attribute__((ext_vector_type(4)));
typedef _Float16 f16x8 __attribute__((ext_vector_type(8)));
typedef float f32x4 __attribute__((ext_vector_type(4)));
typedef int iv4 __attribute__((ext_vector_type(4)));

#define S_LEN 1024
#define BATCH 32
#define HID 256
#define L2E 1.4426950408889634f
#define L2E2 2.8853900817779268f

#if __has_builtin(__builtin_amdgcn_fdot2)
#define FDOT2(a, b, c) __builtin_amdgcn_fdot2((a), (b), (c), false)
#else
static __device__ __forceinline__ float FDOT2(f16x2 a, f16x2 b, float c) {
  return c + (float)a[0] * (float)b[0] + (float)a[1] * (float)b[1];
}
#endif

__device__ __forceinline__ float EXP2(float x) {
#if __has_builtin(__builtin_amdgcn_exp2f)
  return __builtin_amdgcn_exp2f(x);
#else
  return exp2f(x);
#endif
}
__device__ __forceinline__ float RCP(float x) {
#if __has_builtin(__builtin_amdgcn_rcpf)
  return __builtin_amdgcn_rcpf(x);
#else
  return 1.0f / x;
#endif
}

__device__ __forceinline__ iv4 cvt8(float4 a, float4 b) {
#if __has_builtin(__builtin_amdgcn_cvt_pkrtz)
  auto p0 = __builtin_amdgcn_cvt_pkrtz(a.x, a.y);
  auto p1 = __builtin_amdgcn_cvt_pkrtz(a.z, a.w);
  auto p2 = __builtin_amdgcn_cvt_pkrtz(b.x, b.y);
  auto p3 = __builtin_amdgcn_cvt_pkrtz(b.z, b.w);
  iv4 o;
  o[0] = __builtin_bit_cast(int, p0);
  o[1] = __builtin_bit_cast(int, p1);
  o[2] = __builtin_bit_cast(int, p2);
  o[3] = __builtin_bit_cast(int, p3);
  return o;
#else
  f16x8 h;
  h[0] = (f16)a.x; h[1] = (f16)a.y; h[2] = (f16)a.z; h[3] = (f16)a.w;
  h[4] = (f16)b.x; h[5] = (f16)b.y; h[6] = (f16)b.z; h[7] = (f16)b.w;
  return __builtin_bit_cast(iv4, h);
#endif
}

#if __has_builtin(__builtin_amdgcn_global_load_lds)
__device__ __forceinline__ void gload16(const void* g, void* l) {
  __builtin_amdgcn_global_load_lds((const __attribute__((address_space(1))) void*)g,
                                   (__attribute__((address_space(3))) void*)l, 16, 0, 0);
}
#else
__device__ __forceinline__ void gload16(const void* g, void* l) {
  int lane = __builtin_amdgcn_mbcnt_hi(~0u, __builtin_amdgcn_mbcnt_lo(~0u, 0));
  ((f16x8*)l)[lane] = *(const f16x8*)g;  // emulate base + lane*16
}
#endif

// barrier that waits LDS only (no vmcnt drain)
#define WG_BARRIER()                                                  \
  do {                                                                \
    __builtin_amdgcn_sched_barrier(0);                                \
    asm volatile("s_waitcnt lgkmcnt(0)\n\ts_barrier" ::: "memory");   \
    __builtin_amdgcn_sched_barrier(0);                                \
  } while (0)

__device__ __forceinline__ float dot8(f16x8 w, f16x8 h, float acc) {
  f16x2 a, b;
  a[0] = w[0]; a[1] = w[1]; b[0] = h[0]; b[1] = h[1]; acc = FDOT2(a, b, acc);
  a[0] = w[2]; a[1] = w[3]; b[0] = h[2]; b[1] = h[3]; acc = FDOT2(a, b, acc);
  a[0] = w[4]; a[1] = w[5]; b[0] = h[4]; b[1] = h[5]; acc = FDOT2(a, b, acc);
  a[0] = w[6]; a[1] = w[7]; b[0] = h[6]; b[1] = h[7]; acc = FDOT2(a, b, acc);
  return acc;
}

// ---------------- f32 -> f16 convert (plain) ----------------
__global__ void cvt_f32_f16(const float* __restrict__ src, f16* __restrict__ dst, int n4) {
  int i = blockIdx.x * 256 + threadIdx.x;
  if (i < n4) {
    float4 v = ((const float4*)src)[i];
    f16x4 h;
    h[0] = (f16)v.x; h[1] = (f16)v.y; h[2] = (f16)v.z; h[3] = (f16)v.w;
    ((f16x4*)dst)[i] = h;
  }
}

// ---------------- w_ih f32 -> f16, log2e row-scaled ----------------
__global__ void cvt_wih(const float* __restrict__ src, f16* __restrict__ dst, int K, int total8) {
  int i = blockIdx.x * 256 + threadIdx.x;
  if (i < total8) {
    int row = (int)(((long long)i * 8) / K);
    float sc = (row >= 512 && row < 768) ? L2E2 : L2E;
    const float* s = src + (size_t)i * 8;
    float4 a = *(const float4*)s;
    float4 b = *(const float4*)(s + 4);
    f16x8 h;
    h[0] = (f16)(a.x * sc); h[1] = (f16)(a.y * sc); h[2] = (f16)(a.z * sc); h[3] = (f16)(a.w * sc);
    h[4] = (f16)(b.x * sc); h[5] = (f16)(b.y * sc); h[6] = (f16)(b.z * sc); h[7] = (f16)(b.w * sc);
    *(f16x8*)(dst + (size_t)i * 8) = h;
  }
}

// ---------------- bias pack: bsum[u][n] = (bih+bhh)*sc ----------------
__global__ void bias_pack(const float* __restrict__ a0, const float* __restrict__ h0,
                          const float* __restrict__ a1, const float* __restrict__ h1,
                          const float* __restrict__ a2, const float* __restrict__ h2,
                          const float* __restrict__ a3, const float* __restrict__ h3,
                          float* __restrict__ bsum) {
  int i = blockIdx.x * 256 + threadIdx.x;
  if (i < 4096) {
    int u = i >> 10, n = i & 1023;
    float sc = (n >= 512 && n < 768) ? L2E2 : L2E;
    const float* pa = u == 0 ? a0 : u == 1 ? a1 : u == 2 ? a2 : a3;
    const float* ph = u == 0 ? h0 : u == 1 ? h1 : u == 2 ? h2 : h3;
    bsum[i] = (pa[n] + ph[n]) * sc;
  }
}

// ---------------- whh f32 -> i8 per-row symmetric quant, log2e pre-scaled ----------------
__global__ __launch_bounds__(256) void quant_whh(const float* __restrict__ src,
                                                 char* __restrict__ dstq,
                                                 float* __restrict__ fsc) {
  const int row = blockIdx.x * 4 + (threadIdx.x >> 6);
  const int lane = threadIdx.x & 63;
  const float sc = (row >= 512 && row < 768) ? L2E2 : L2E;
  float4 v = *(const float4*)(src + (size_t)row * 256 + lane * 4);
  float w0 = v.x * sc, w1 = v.y * sc, w2 = v.z * sc, w3 = v.w * sc;
  float mx = fmaxf(fmaxf(fabsf(w0), fabsf(w1)), fmaxf(fabsf(w2), fabsf(w3)));
#pragma unroll
  for (int off = 1; off < 64; off <<= 1) mx = fmaxf(mx, __shfl_xor(mx, off));
  mx = fmaxf(mx, 1e-20f);
  float inv = 127.0f / mx;
  int q0 = (int)rintf(w0 * inv), q1 = (int)rintf(w1 * inv);
  int q2 = (int)rintf(w2 * inv), q3 = (int)rintf(w3 * inv);
  int pk = (q0 & 0xff) | ((q1 & 0xff) << 8) | ((q2 & 0xff) << 16) | ((q3 & 0xff) << 24);
  ((int*)(dstq + (size_t)row * 256))[lane] = pk;
  if (lane == 0) fsc[row] = mx / 16129.0f;
}

// ---------------- fused input-projection GEMM -> P4 planes ----------------
// 1D grid 4096, XCD-grouped: L = q*32 + r; v = r>>3; (unit,bm) = q*8 + (r&7).
// The 4 v-blocks of one (unit,bm) share a linear-id residue mod 8 -> same XCD L2,
// so the A panel is fetched from HBM once and L2-shared 4x.
// 48KB LDS (two-pass epilogue) -> 3 blocks/CU.
__global__ __launch_bounds__(256) void proj_gemm(const float* __restrict__ x,
                                                 const float* __restrict__ xbin,
                                                 const f16* __restrict__ w16all,
                                                 const float* __restrict__ bsum,
                                                 char* __restrict__ P4) {
  __shared__ __align__(16) char smem[49152];  // As [0,16K) swz ; Bs [16K,48K) swz ; epi [0,32K)
  const int L = blockIdx.x;
  const int q = L >> 5, r = L & 31;
  const int v = r >> 3;
  const int ub = q * 8 + (r & 7);
  const int unit = ub >> 8;
  const int bm = ub & 255;
  const int K = (unit < 2) ? 512 : 1536;
  const float* Aptr = (unit < 2) ? x : xbin;
  const size_t woff = (unit == 0) ? 0u : (unit == 1) ? 524288u : (unit == 2) ? 1048576u : 2621440u;
  const f16* W16 = w16all + woff;
  const int bgrp = bm >> 5, t0 = (bm & 31) * 32;
  const int b0 = bgrp * 4, c = bgrp >> 1, lkb = bgrp & 1;
  const int tid = threadIdx.x;
  const int lane = tid & 63, wid = tid >> 6;
  const int wm = wid >> 1, wn = wid & 1;
  const int lr = lane & 15, lk = lane >> 4;
  const int xsw = (lr & 7) << 4;  // read-side granule swizzle

  f32x4 acc[4][8];
#pragma unroll
  for (int i = 0; i < 4; ++i)
#pragma unroll
    for (int n = 0; n < 8; ++n) acc[i][n] = (f32x4){0.f, 0.f, 0.f, 0.f};

  for (int k0 = 0; k0 < K; k0 += 64) {
    // issue B DMA first (fire-and-forget; lands during A staging)
#pragma unroll
    for (int i = 0; i < 8; ++i) {
      int g = (wid * 8 + i) * 64 + lane;  // granule index 0..2047
      int brow = g >> 3, cg = g & 7;
      const f16* bsrc = W16 + (size_t)(v * 256 + brow) * K + k0 + ((cg ^ (brow & 7)) << 3);
      gload16(bsrc, smem + 16384 + (wid * 8 + i) * 1024);
    }
    // stage A: load f32, cvt_pkrtz, swizzled ds_write (4 slots/thread)
#pragma unroll
    for (int s = 0; s < 4; ++s) {
      int slot = s * 256 + tid;
      int row = slot >> 3, seg = slot & 7;
      size_t arow = (size_t)(b0 + (row >> 5)) * 1024 + t0 + (row & 31);
      const float* ga = Aptr + arow * K + k0 + seg * 8;
      float4 v0 = *(const float4*)ga;
      float4 v1 = *(const float4*)(ga + 4);
      *(iv4*)(smem + row * 128 + ((seg ^ (row & 7)) << 4)) = cvt8(v0, v1);
    }
    __syncthreads();  // drains vmcnt (B DMA) + lgkm (A writes)
#pragma unroll
    for (int kk = 0; kk < 2; ++kk) {
      f16x8 af[4], bf[8];
#pragma unroll
      for (int mi = 0; mi < 4; ++mi) {
        int ba = (wm * 64 + mi * 16 + lr) * 128 + kk * 64 + lk * 16;
        af[mi] = *(const f16x8*)(smem + (ba ^ xsw));
      }
#pragma unroll
      for (int ni = 0; ni < 8; ++ni) {
        int bb = (wn * 128 + ni * 16 + lr) * 128 + kk * 64 + lk * 16;
        bf[ni] = *(const f16x8*)(smem + 16384 + (bb ^ xsw));
      }
#pragma unroll
      for (int mi = 0; mi < 4; ++mi)
#pragma unroll
        for (int ni = 0; ni < 8; ++ni)
          acc[mi][ni] = __builtin_amdgcn_mfma_f32_16x16x32_f16(af[mi], bf[ni], acc[mi][ni], 0, 0, 0);
    }
    __syncthreads();
  }

  // epilogue: two passes (t_loc halves selected by mi&1), 32KB LDS each
  float biasv[8];
#pragma unroll
  for (int ni = 0; ni < 8; ++ni)
    biasv[ni] = bsum[unit * 1024 + v * 256 + wn * 128 + ni * 16 + lr];
  char* Pv = P4 + ((size_t)unit << 26) + ((size_t)v << 24);
#pragma unroll
  for (int pass = 0; pass < 2; ++pass) {
    __syncthreads();
#pragma unroll
    for (int mi2 = 0; mi2 < 2; ++mi2) {
      int mi = mi2 * 2 + pass;  // pass0: mi 0,2 (t_loc<16) ; pass1: mi 1,3
#pragma unroll
      for (int ni = 0; ni < 8; ++ni) {
        int col = wn * 128 + ni * 16 + lr;
        int wc = col >> 5, jc = (col >> 4) & 1, lc = col & 15;
#pragma unroll
        for (int rr = 0; rr < 4; ++rr) {
          int row = wm * 64 + mi * 16 + lk * 4 + rr;
          int bsub = row >> 5, tl = row & 15;
          int unit2 = tl * 256 + wc * 32 + jc * 16 + lc;
          int off = (unit2 * 8 + bsub * 2) ^ ((tl & 7) << 4);
          *(f16*)(smem + off) = (f16)(acc[mi][ni][rr] + biasv[ni]);
        }
      }
    }
    __syncthreads();
#pragma unroll
    for (int k = 0; k < 16; ++k) {
      int uid = k * 256 + tid;
      int tl = uid >> 8, sub = uid & 255;
      int off = (uid * 8) ^ ((tl & 7) << 4);
      unsigned long long val = *(const unsigned long long*)(smem + off);
      int t_loc = pass * 16 + tl;
      int wq = sub >> 5, jq = (sub >> 4) & 1, lq = sub & 15;
      size_t didx =
          (((size_t)((t0 + t_loc) * 4 + c) * 512) + wq * 64 + jq * 32 + lkb * 16 + lq) << 3;
      *(unsigned long long*)(Pv + didx) = val;
    }
  }
}

// ---------------- LSTM recurrence: 64 WGs = (unit, batch-pair), i8 MFMA, 1 cell/lane ----------------
__global__ __attribute__((amdgpu_flat_work_group_size(512, 512), amdgpu_waves_per_eu(2, 2)))
void lstm_rec5(const char* __restrict__ Wq4,
               const float* __restrict__ fsc4,
               const char* __restrict__ P4,
               const float* __restrict__ h0m,
               const float* __restrict__ c0m,
               const float* __restrict__ h0b,
               const float* __restrict__ c0b,
               f16* __restrict__ hid4) {
  const int wg = blockIdx.x;
  const int u = wg >> 4, c16 = wg & 15;
  const int dir = u & 1;
  const int tid = threadIdx.x;
  const int l = tid & 63, w = tid >> 6;
  const int lr = l & 15, lk = l >> 4;
  const int jj = lk >> 1, selb = lk & 1;
  const int r2 = lr & 1;
  const int swzA = r2 ? 80 : 0;
  const int swzW = selb ? 80 : 0;
  const int j = w * 32 + jj * 16 + lr;  // hidden unit owned by this lane

  __shared__ __align__(16) char hbuf[2][512];  // [2 batch rows][256 k] i8, swizzled

  // ---- weights: 32 x iv4 = 128 regs; n = v*256 + w*32 + (nt&1)*16 + lr ----
  iv4 Bf[4][8];
  const char* wb = Wq4 + ((size_t)u << 18);
#pragma unroll
  for (int nt = 0; nt < 8; ++nt) {
    int n = (nt >> 1) * 256 + w * 32 + ((nt & 1) << 4) + lr;
#pragma unroll
    for (int ks = 0; ks < 4; ++ks)
      Bf[ks][nt] = *(const iv4*)(wb + (size_t)n * 256 + ks * 64 + lk * 16);
  }
  float fv[4], fv4[4];
#pragma unroll
  for (int v = 0; v < 4; ++v) {
    fv[v] = fsc4[u * 1024 + v * 256 + j];
    fv4[v] = fv[v] * 4.f;
  }

  // ---- init c / h0 (h0 quantized at scale 127/4, step-0 uses fv4) ----
  const int b = c16 * 2 + selb;
  const float* h0 = (u < 2 ? h0m : h0b) + (size_t)dir * BATCH * HID;
  const float* c0 = (u < 2 ? c0m : c0b) + (size_t)dir * BATCH * HID;
  float cst = c0[b * HID + j];
  {
    float hv = h0[b * HID + j] * 31.75f;
    int hq = (int)rintf(hv);
    hq = hq > 127 ? 127 : (hq < -127 ? -127 : hq);
    hbuf[0][selb * 256 + (j ^ swzW)] = (char)hq;
  }

  // ---- P preload for s=0 ----
  const char* Pc = P4 + ((size_t)u << 26);
  const size_t soff =
      (size_t)((w * 64 + jj * 32 + (((c16 >> 1) & 1) << 4) + lr) * 8 + (c16 & 1) * 4);
  const int cq = c16 >> 2;
  f16x2 Pa[4], Pb[4];
  {
    int t0 = dir ? (S_LEN - 1) : 0;
    size_t tb = ((size_t)((t0 << 2) + cq) << 12) + soff;
#pragma unroll
    for (int v = 0; v < 4; ++v) Pa[v] = *(const f16x2*)(Pc + ((size_t)v << 24) + tb);
  }
  WG_BARRIER();

#define LSTM_STEP(S_, SP_, PC_, PN_, FV_)                                                   \
  {                                                                                         \
    const int t = dir ? (S_LEN - 1 - (S_)) : (S_);                                          \
    {                                                                                       \
      int s2 = ((S_) + 1 < S_LEN) ? (S_) + 1 : (S_);                                        \
      int t2 = dir ? (S_LEN - 1 - s2) : s2;                                                 \
      size_t tb = ((size_t)((t2 << 2) + cq) << 12) + soff;                                  \
      _Pragma("unroll") for (int v = 0; v < 4; ++v)                                         \
          PN_[v] = *(const f16x2*)(Pc + ((size_t)v << 24) + tb);                            \
    }                                                                                       \
    iv4 ia[8];                                                                              \
    _Pragma("unroll") for (int nt = 0; nt < 8; ++nt) ia[nt] = (iv4){0, 0, 0, 0};            \
    const char* hb = hbuf[SP_];                                                             \
    _Pragma("unroll") for (int ks = 0; ks < 4; ++ks) {                                      \
      iv4 Af = *(const iv4*)(hb + r2 * 256 + ((ks * 64 + lk * 16) ^ swzA));                 \
      _Pragma("unroll") for (int nt = 0; nt < 8; ++nt)                                      \
          ia[nt] = __builtin_amdgcn_mfma_i32_16x16x64_i8(Af, Bf[ks][nt], ia[nt], 0, 0, 0);  \
    }                                                                                       \
    float z[4];                                                                             \
    _Pragma("unroll") for (int v = 0; v < 4; ++v) {                                         \
      int e0 = selb ? ia[v * 2][1] : ia[v * 2][0];                                          \
      int e1 = selb ? ia[v * 2 + 1][1] : ia[v * 2 + 1][0];                                  \
      int iz = jj ? e1 : e0;                                                                \
      float pv = selb ? (float)PC_[v][1] : (float)PC_[v][0];                                \
      z[v] = pv + FV_[v] * (float)iz;                                                       \
    }                                                                                       \
    float zi = z[0], zf = z[1], zg = z[2], zo = z[3];                                       \
    float ei = EXP2(-zi), ef = EXP2(-zf), eg = EXP2(-zg), eo = EXP2(-zo);                   \
    float di = 1.f + ei, df = 1.f + ef, dg = 1.f + eg, dof = 1.f + eo;                      \
    float r1 = RCP(di * df);                                                                \
    float si = r1 * df, sf = r1 * di;                                                       \
    float r2x = RCP(dg * dof);                                                              \
    float tg = 2.f * (r2x * dof) - 1.f, so = r2x * dg;                                      \
    float cc = sf * cst + si * tg;                                                          \
    cst = cc;                                                                               \
    float ec = EXP2(-L2E2 * cc);                                                            \
    float th = 2.f * RCP(1.f + ec) - 1.f;                                                   \
    float hh = so * th;                                                                     \
    int hq = (int)rintf(hh * 127.f);                                                        \
    hbuf[SP_ ^ 1][selb * 256 + (j ^ swzW)] = (char)hq;                                      \
    hid4[((size_t)b << 20) + ((size_t)t << 10) + (u << 8) + j] = (f16)hh;                   \
    WG_BARRIER();                                                                           \
  }

  LSTM_STEP(0, 0, Pa, Pb, fv4);
  for (int s = 1; s <= 1021; s += 2) {
    LSTM_STEP(s, 1, Pb, Pa, fv);
    LSTM_STEP(s + 1, 0, Pa, Pb, fv);
  }
  LSTM_STEP(1023, 1, Pb, Pa, fv);
#undef LSTM_STEP
}

// ---------------- emissions ----------------
__global__ __launch_bounds__(256) void emis_kernel(const f16* __restrict__ hid4,
                                                   const f16* __restrict__ wtag,
                                                   const float* __restrict__ btag,
                                                   const f16* __restrict__ wbin,
                                                   const float* __restrict__ bbin,
                                                   float* __restrict__ emis,
                                                   float* __restrict__ emisb) {
  const int tid = threadIdx.x;
  const int rl = tid >> 4, n = tid & 15;
  const size_t row = (size_t)blockIdx.x * 16 + rl;
  const f16x8* hv = (const f16x8*)(hid4 + row * 1024);
  const f16x8* wv = (const f16x8*)(wtag + n * 1024);
  float acc = btag[n];
#pragma unroll 8
  for (int kc = 0; kc < 128; ++kc) acc = dot8(wv[kc], hv[kc], acc);
  emis[row * 16 + n] = acc;
  if (n < 5) {
    const f16x8* hv2 = (const f16x8*)(hid4 + row * 1024 + 512);
    const f16x8* wv2 = (const f16x8*)(wbin + (size_t)n * 512);
    float a2 = bbin[n];
#pragma unroll 8
    for (int kc = 0; kc < 64; ++kc) a2 = dot8(wv2[kc], hv2[kc], a2);
    emisb[row * 5 + n] = a2;
  }
}

// ---------------- CRF forward (logZ): proven round-6 version ----------------
__global__ __launch_bounds__(64) void crf_logz(const float* __restrict__ emis,
                                               const float* __restrict__ trans,
                                               const float* __restrict__ emisb,
                                               const float* __restrict__ transb,
                                               const float* __restrict__ mask,
                                               float* __restrict__ outLogZ) {
  const int crf = blockIdx.x >> 5, b = blockIdx.x & 31;
  const int NTc = crf ? 5 : 16;
  const float* __restrict__ E = crf ? emisb : emis;
  const float* __restrict__ T = crf ? transb : trans;
  const int lane = threadIdx.x;
  const int jn = lane >> 2, p = lane & 3;
  const bool jv = (jn < NTc);
  const int jc = jv ? jn : 0;
  float Tc[4];
#pragma unroll
  for (int ii = 0; ii < 4; ++ii) {
    int i = p * 4 + ii;
    Tc[ii] = (jv && i < NTc) ? T[i * NTc + jn] : -1e30f;
  }
  __shared__ float as_[2][16];
  if (lane < 16) { as_[0][lane] = -1e30f; as_[1][lane] = -1e30f; }
  __syncthreads();
  float alpha = 0.f;
  if (jv && p == 0) {
    alpha = T[1 * NTc + jn] + E[(size_t)(b << 10) * NTc + jn];  // SOS=1, t=0
    as_[0][jn] = alpha;
  }
  __syncthreads();
  int cur = 0;
  const size_t ebase = (size_t)(b << 10) * NTc + jc;
  const int mbase = b << 10;
#define LDE(tt) E[ebase + (size_t)(tt)*NTc]
#define LDM(tt) mask[mbase + (tt)]

  auto step = [&](float e_tj, float m_t) {
    float v0 = (jv && (p * 4 + 0) < NTc) ? (as_[cur][p * 4 + 0] + Tc[0]) : -1e30f;
    float v1 = (jv && (p * 4 + 1) < NTc) ? (as_[cur][p * 4 + 1] + Tc[1]) : -1e30f;
    float v2 = (jv && (p * 4 + 2) < NTc) ? (as_[cur][p * 4 + 2] + Tc[2]) : -1e30f;
    float v3 = (jv && (p * 4 + 3) < NTc) ? (as_[cur][p * 4 + 3] + Tc[3]) : -1e30f;
    float mx = fmaxf(fmaxf(v0, v1), fmaxf(v2, v3));
    mx = fmaxf(mx, __shfl_xor(mx, 1, 4));
    mx = fmaxf(mx, __shfl_xor(mx, 2, 4));
    float ss = __expf(v0 - mx) + __expf(v1 - mx) + __expf(v2 - mx) + __expf(v3 - mx);
    ss += __shfl_xor(ss, 1, 4);
    ss += __shfl_xor(ss, 2, 4);
    if (jv && p == 0) {
      float newv = e_tj + mx + __logf(ss);
      alpha = (m_t > 0.5f) ? newv : alpha;
      as_[cur ^ 1][jn] = alpha;
    }
    __syncthreads();
    cur ^= 1;
  };

  float eb[4], mb[4];
#pragma unroll
  for (int k = 0; k < 4; ++k) { eb[k] = LDE(1 + k); mb[k] = LDM(1 + k); }
  for (int t = 1; t <= 1017; t += 4) {
    float en[4], mn[4];
#pragma unroll
    for (int k = 0; k < 4; ++k) {
      int ix = t + 4 + k;
      ix = ix > 1023 ? 1023 : ix;
      en[k] = LDE(ix);
      mn[k] = LDM(ix);
    }
    step(eb[0], mb[0]); step(eb[1], mb[1]); step(eb[2], mb[2]); step(eb[3], mb[3]);
#pragma unroll
    for (int k = 0; k < 4; ++k) { eb[k] = en[k]; mb[k] = mn[k]; }
  }
  step(eb[0], mb[0]); step(eb[1], mb[1]); step(eb[2], mb[2]);
#undef LDE
#undef LDM

  if (lane == 0) {
    float mx = -1e30f;
    for (int jjx = 0; jjx < NTc; ++jjx) mx = fmaxf(mx, as_[cur][jjx] + T[jjx * NTc + 2]);
    float ss = 0.f;
    for (int jjx = 0; jjx < NTc; ++jjx) ss += __expf(as_[cur][jjx] + T[jjx * NTc + 2] - mx);
    outLogZ[crf * 32 + b] = mx + __logf(ss);
  }
}

// ---------------- CRF gold score ----------------
__global__ __launch_bounds__(64) void crf_score(const float* __restrict__ emis,
                                                const float* __restrict__ trans,
                                                const float* __restrict__ emisb,
                                                const float* __restrict__ transb,
                                                const float* __restrict__ mask,
                                                const int* __restrict__ tags,
                                                const int* __restrict__ tagsb,
                                                float* __restrict__ outScore) {
  const int crf = blockIdx.x >> 5, b = blockIdx.x & 31;
  const int NTc = crf ? 5 : 16;
  const float* __restrict__ E = crf ? emisb : emis;
  const float* __restrict__ T = crf ? transb : trans;
  const int* __restrict__ tg = (crf ? tagsb : tags) + (b << 10);
  const float* __restrict__ mk = mask + (b << 10);
  const int lane = threadIdx.x;
  float s = 0.f, cnt = 0.f;
  for (int t = lane; t < S_LEN; t += 64) {
    float m = mk[t];
    cnt += m;
    if (t >= 1 && m > 0.5f)
      s += E[((size_t)(b << 10) + t) * NTc + tg[t]] + T[tg[t - 1] * NTc + tg[t]];
  }
#pragma unroll
  for (int off = 32; off >= 1; off >>= 1) {
    s += __shfl_down(s, off);
    cnt += __shfl_down(cnt, off);
  }
  if (lane == 0) {
    int L = (int)(cnt + 0.5f);
    int t0 = tg[0];
    float tot = T[1 * NTc + t0] + E[(size_t)(b << 10) * NTc + t0] + s + T[tg[L - 1] * NTc + 2];
    outScore[crf * 32 + b] = tot;
  }
}

__global__ void finalk(const float* __restrict__ logZ, const float* __restrict__ score,
                       float* __restrict__ out) {
  int j = threadIdx.x;
  if (j < 2) {
    float a = 0.f;
    for (int b = 0; b < 32; ++b) a += logZ[j * 32 + b] - score[j * 32 + b];
    out[j] = a;
  }
}

extern "C" void kernel_launch(void* const* d_in, const int* in_sizes, int n_in,
                              void* d_out, int out_size, void* d_ws, size_t ws_size,
                              hipStream_t stream) {
  const float* x       = (const float*)d_in[0];
  const float* xbin    = (const float*)d_in[1];
  const float* mask    = (const float*)d_in[2];
  const int*   tags    = (const int*)d_in[3];
  const int*   tagsb   = (const int*)d_in[4];
  const float* trans   = (const float*)d_in[5];
  const float* transb  = (const float*)d_in[6];
  const float* w2f_ih  = (const float*)d_in[7];
  const float* w2f_hh  = (const float*)d_in[8];
  const float* b2f_ih  = (const float*)d_in[9];
  const float* b2f_hh  = (const float*)d_in[10];
  const float* w2b_ih  = (const float*)d_in[11];
  const float* w2b_hh  = (const float*)d_in[12];
  const float* b2b_ih  = (const float*)d_in[13];
  const float* b2b_hh  = (const float*)d_in[14];
  const float* w_bin   = (const float*)d_in[15];
  const float* bb_bin  = (const float*)d_in[16];
  const float* w1f_ih  = (const float*)d_in[17];
  const float* w1f_hh  = (const float*)d_in[18];
  const float* b1f_ih  = (const float*)d_in[19];
  const float* b1f_hh  = (const float*)d_in[20];
  const float* w1b_ih  = (const float*)d_in[21];
  const float* w1b_hh  = (const float*)d_in[22];
  const float* b1b_ih  = (const float*)d_in[23];
  const float* b1b_hh  = (const float*)d_in[24];
  const float* w_tag   = (const float*)d_in[25];
  const float* b_tag   = (const float*)d_in[26];
  const float* h0_bin  = (const float*)d_in[27];
  const float* c0_bin  = (const float*)d_in[28];
  const float* h0_main = (const float*)d_in[29];
  const float* c0_main = (const float*)d_in[30];

  char* ws = (char*)d_ws;
  char* P4    = ws;                                   // 4u x 64MiB = 256MiB
  f16* hid4   = (f16*)(ws + 268435456);               // 64MiB
  char* Wq4   = ws + 335544320;                       // 1MiB
  float* fsc4 = (float*)(ws + 336592896);             // 16KB
  f16* wtag   = (f16*)(ws + 336609280);
  f16* wbin   = (f16*)(ws + 336642048);
  float* emis  = (float*)(ws + 336647168);            // 2MiB
  float* emisb = (float*)(ws + 338744320);
  float* logZ  = (float*)(ws + 339399680);
  float* score = (float*)(ws + 339399936);
  float* bsum  = (float*)(ws + 339400704);            // 16KB
  f16* w16all  = (f16*)(ws + 340000768);              // 8MiB, ends 348389376

  // weight preps
  quant_whh<<<256, 256, 0, stream>>>(w1f_hh, Wq4 + 0 * 262144, fsc4 + 0 * 1024);
  quant_whh<<<256, 256, 0, stream>>>(w1b_hh, Wq4 + 1 * 262144, fsc4 + 1 * 1024);
  quant_whh<<<256, 256, 0, stream>>>(w2f_hh, Wq4 + 2 * 262144, fsc4 + 2 * 1024);
  quant_whh<<<256, 256, 0, stream>>>(w2b_hh, Wq4 + 3 * 262144, fsc4 + 3 * 1024);
  cvt_f32_f16<<<16, 256, 0, stream>>>(w_tag, wtag, 4096);
  cvt_f32_f16<<<3, 256, 0, stream>>>(w_bin, wbin, 640);
  cvt_wih<<<256, 256, 0, stream>>>(w1f_ih, w16all + 0, 512, 65536);
  cvt_wih<<<256, 256, 0, stream>>>(w1b_ih, w16all + 524288, 512, 65536);
  cvt_wih<<<768, 256, 0, stream>>>(w2f_ih, w16all + 1048576, 1536, 196608);
  cvt_wih<<<768, 256, 0, stream>>>(w2b_ih, w16all + 2621440, 1536, 196608);
  bias_pack<<<16, 256, 0, stream>>>(b1f_ih, b1f_hh, b1b_ih, b1b_hh,
                                    b2f_ih, b2f_hh, b2b_ih, b2b_hh, bsum);

  // fused input projections: 1D grid, XCD-grouped (see proj_gemm header)
  proj_gemm<<<4096, 256, 0, stream>>>(x, xbin, w16all, bsum, P4);

  lstm_rec5<<<64, 512, 0, stream>>>(Wq4, fsc4, P4, h0_main, c0_main, h0_bin, c0_bin, hid4);
  emis_kernel<<<2048, 256, 0, stream>>>(hid4, wtag, b_tag, wbin, bb_bin, emis, emisb);
  crf_logz<<<64, 64, 0, stream>>>(emis, trans, emisb, transb, mask, logZ);
  crf_score<<<64, 64, 0, stream>>>(emis, trans, emisb, transb, mask, tags, tagsb, score);
  finalk<<<1, 64, 0, stream>>>(logZ, score, (float*)d_out);
}

// Round 12
// 1968.404 us; speedup vs baseline: 2.2251x; 1.0101x over previous
//
#include <hip/hip_runtime.h>

typedef _Float16 f16;
typedef _Float16 f16x2 __attribute__((ext_vector_type(2)));
typedef _Float16 f16x4 __attribute__((ext_vector_type(4)));
typedef _Float16 f16x8 __attribute__((ext_vector_type(8)));
typedef float f32x4 __attribute__((ext_vector_type(4)));
typedef int iv4 __attribute__((ext_vector_type(4)));

#define S_LEN 1024
#define BATCH 32
#define HID 256
#define L2E 1.4426950408889634f
#define L2E2 2.8853900817779268f

#if __has_builtin(__builtin_amdgcn_fdot2)
#define FDOT2(a, b, c) __builtin_amdgcn_fdot2((a), (b), (c), false)
#else
static __device__ __forceinline__ float FDOT2(f16x2 a, f16x2 b, float c) {
  return c + (float)a[0] * (float)b[0] + (float)a[1] * (float)b[1];
}
#endif

__device__ __forceinline__ float EXP2(float x) {
#if __has_builtin(__builtin_amdgcn_exp2f)
  return __builtin_amdgcn_exp2f(x);
#else
  return exp2f(x);
#endif
}
__device__ __forceinline__ float RCP(float x) {
#if __has_builtin(__builtin_amdgcn_rcpf)
  return __builtin_amdgcn_rcpf(x);
#else
  return 1.0f / x;
#endif
}

__device__ __forceinline__ iv4 cvt8(float4 a, float4 b) {
#if __has_builtin(__builtin_amdgcn_cvt_pkrtz)
  auto p0 = __builtin_amdgcn_cvt_pkrtz(a.x, a.y);
  auto p1 = __builtin_amdgcn_cvt_pkrtz(a.z, a.w);
  auto p2 = __builtin_amdgcn_cvt_pkrtz(b.x, b.y);
  auto p3 = __builtin_amdgcn_cvt_pkrtz(b.z, b.w);
  iv4 o;
  o[0] = __builtin_bit_cast(int, p0);
  o[1] = __builtin_bit_cast(int, p1);
  o[2] = __builtin_bit_cast(int, p2);
  o[3] = __builtin_bit_cast(int, p3);
  return o;
#else
  f16x8 h;
  h[0] = (f16)a.x; h[1] = (f16)a.y; h[2] = (f16)a.z; h[3] = (f16)a.w;
  h[4] = (f16)b.x; h[5] = (f16)b.y; h[6] = (f16)b.z; h[7] = (f16)b.w;
  return __builtin_bit_cast(iv4, h);
#endif
}

#if __has_builtin(__builtin_amdgcn_global_load_lds)
__device__ __forceinline__ void gload16(const void* g, void* l) {
  __builtin_amdgcn_global_load_lds((const __attribute__((address_space(1))) void*)g,
                                   (__attribute__((address_space(3))) void*)l, 16, 0, 0);
}
#else
__device__ __forceinline__ void gload16(const void* g, void* l) {
  int lane = __builtin_amdgcn_mbcnt_hi(~0u, __builtin_amdgcn_mbcnt_lo(~0u, 0));
  ((f16x8*)l)[lane] = *(const f16x8*)g;  // emulate base + lane*16
}
#endif

// barrier that waits LDS only (no vmcnt drain)
#define WG_BARRIER()                                                  \
  do {                                                                \
    __builtin_amdgcn_sched_barrier(0);                                \
    asm volatile("s_waitcnt lgkmcnt(0)\n\ts_barrier" ::: "memory");   \
    __builtin_amdgcn_sched_barrier(0);                                \
  } while (0)

// single-wave LDS visibility (block == 1 wave64): no s_barrier needed
#define WAVE_SYNC()                                                   \
  do {                                                                \
    __builtin_amdgcn_sched_barrier(0);                                \
    asm volatile("s_waitcnt lgkmcnt(0)" ::: "memory");                \
    __builtin_amdgcn_sched_barrier(0);                                \
  } while (0)

__device__ __forceinline__ float dot8(f16x8 w, f16x8 h, float acc) {
  f16x2 a, b;
  a[0] = w[0]; a[1] = w[1]; b[0] = h[0]; b[1] = h[1]; acc = FDOT2(a, b, acc);
  a[0] = w[2]; a[1] = w[3]; b[0] = h[2]; b[1] = h[3]; acc = FDOT2(a, b, acc);
  a[0] = w[4]; a[1] = w[5]; b[0] = h[4]; b[1] = h[5]; acc = FDOT2(a, b, acc);
  a[0] = w[6]; a[1] = w[7]; b[0] = h[6]; b[1] = h[7]; acc = FDOT2(a, b, acc);
  return acc;
}

// ---------------- f32 -> f16 convert (plain) ----------------
__global__ void cvt_f32_f16(const float* __restrict__ src, f16* __restrict__ dst, int n4) {
  int i = blockIdx.x * 256 + threadIdx.x;
  if (i < n4) {
    float4 v = ((const float4*)src)[i];
    f16x4 h;
    h[0] = (f16)v.x; h[1] = (f16)v.y; h[2] = (f16)v.z; h[3] = (f16)v.w;
    ((f16x4*)dst)[i] = h;
  }
}

// ---------------- bulk f32 -> f16 (8 elems/thread) ----------------
__global__ void cvt_x16(const float* __restrict__ src, f16* __restrict__ dst, int n8) {
  int i = blockIdx.x * 256 + threadIdx.x;
  if (i < n8) {
    const float* s = src + (size_t)i * 8;
    float4 a = *(const float4*)s;
    float4 b = *(const float4*)(s + 4);
    *(iv4*)(dst + (size_t)i * 8) = cvt8(a, b);
  }
}

// ---------------- w_ih f32 -> f16, log2e row-scaled ----------------
__global__ void cvt_wih(const float* __restrict__ src, f16* __restrict__ dst, int K, int total8) {
  int i = blockIdx.x * 256 + threadIdx.x;
  if (i < total8) {
    int row = (int)(((long long)i * 8) / K);
    float sc = (row >= 512 && row < 768) ? L2E2 : L2E;
    const float* s = src + (size_t)i * 8;
    float4 a = *(const float4*)s;
    float4 b = *(const float4*)(s + 4);
    f16x8 h;
    h[0] = (f16)(a.x * sc); h[1] = (f16)(a.y * sc); h[2] = (f16)(a.z * sc); h[3] = (f16)(a.w * sc);
    h[4] = (f16)(b.x * sc); h[5] = (f16)(b.y * sc); h[6] = (f16)(b.z * sc); h[7] = (f16)(b.w * sc);
    *(f16x8*)(dst + (size_t)i * 8) = h;
  }
}

// ---------------- bias pack: bsum[u][n] = (bih+bhh)*sc ----------------
__global__ void bias_pack(const float* __restrict__ a0, const float* __restrict__ h0,
                          const float* __restrict__ a1, const float* __restrict__ h1,
                          const float* __restrict__ a2, const float* __restrict__ h2,
                          const float* __restrict__ a3, const float* __restrict__ h3,
                          float* __restrict__ bsum) {
  int i = blockIdx.x * 256 + threadIdx.x;
  if (i < 4096) {
    int u = i >> 10, n = i & 1023;
    float sc = (n >= 512 && n < 768) ? L2E2 : L2E;
    const float* pa = u == 0 ? a0 : u == 1 ? a1 : u == 2 ? a2 : a3;
    const float* ph = u == 0 ? h0 : u == 1 ? h1 : u == 2 ? h2 : h3;
    bsum[i] = (pa[n] + ph[n]) * sc;
  }
}

// ---------------- whh f32 -> i8 per-row symmetric quant, log2e pre-scaled ----------------
__global__ __launch_bounds__(256) void quant_whh(const float* __restrict__ src,
                                                 char* __restrict__ dstq,
                                                 float* __restrict__ fsc) {
  const int row = blockIdx.x * 4 + (threadIdx.x >> 6);
  const int lane = threadIdx.x & 63;
  const float sc = (row >= 512 && row < 768) ? L2E2 : L2E;
  float4 v = *(const float4*)(src + (size_t)row * 256 + lane * 4);
  float w0 = v.x * sc, w1 = v.y * sc, w2 = v.z * sc, w3 = v.w * sc;
  float mx = fmaxf(fmaxf(fabsf(w0), fabsf(w1)), fmaxf(fabsf(w2), fabsf(w3)));
#pragma unroll
  for (int off = 1; off < 64; off <<= 1) mx = fmaxf(mx, __shfl_xor(mx, off));
  mx = fmaxf(mx, 1e-20f);
  float inv = 127.0f / mx;
  int q0 = (int)rintf(w0 * inv), q1 = (int)rintf(w1 * inv);
  int q2 = (int)rintf(w2 * inv), q3 = (int)rintf(w3 * inv);
  int pk = (q0 & 0xff) | ((q1 & 0xff) << 8) | ((q2 & 0xff) << 16) | ((q3 & 0xff) << 24);
  ((int*)(dstq + (size_t)row * 256))[lane] = pk;
  if (lane == 0) fsc[row] = mx / 16129.0f;
}

// ---------------- fused input-projection GEMM -> P4 planes ----------------
// 1D grid 4096, XCD-grouped. PRE=1: A pre-converted f16, both tiles via global_load_lds
// (linear dest + inverse-swizzled source). PRE=0: round-11 proven reg-staged A path.
template <bool PRE>
__global__ __launch_bounds__(256) void proj_gemm(const float* __restrict__ x,
                                                 const float* __restrict__ xbin,
                                                 const f16* __restrict__ x16,
                                                 const f16* __restrict__ xbin16,
                                                 const f16* __restrict__ w16all,
                                                 const float* __restrict__ bsum,
                                                 char* __restrict__ P4) {
  __shared__ __align__(16) char smem[49152];  // As [0,16K) swz ; Bs [16K,48K) swz ; epi [0,32K)
  const int L = blockIdx.x;
  const int q = L >> 5, r = L & 31;
  const int v = r >> 3;
  const int ub = q * 8 + (r & 7);
  const int unit = ub >> 8;
  const int bm = ub & 255;
  const int K = (unit < 2) ? 512 : 1536;
  const float* Aptr = (unit < 2) ? x : xbin;
  const f16* A16 = (unit < 2) ? x16 : xbin16;
  const size_t woff = (unit == 0) ? 0u : (unit == 1) ? 524288u : (unit == 2) ? 1048576u : 2621440u;
  const f16* W16 = w16all + woff;
  const int bgrp = bm >> 5, t0 = (bm & 31) * 32;
  const int b0 = bgrp * 4, c = bgrp >> 1, lkb = bgrp & 1;
  const int tid = threadIdx.x;
  const int lane = tid & 63, wid = tid >> 6;
  const int wm = wid >> 1, wn = wid & 1;
  const int lr = lane & 15, lk = lane >> 4;
  const int xsw = (lr & 7) << 4;  // read-side granule swizzle

  f32x4 acc[4][8];
#pragma unroll
  for (int i = 0; i < 4; ++i)
#pragma unroll
    for (int n = 0; n < 8; ++n) acc[i][n] = (f32x4){0.f, 0.f, 0.f, 0.f};

  for (int k0 = 0; k0 < K; k0 += 64) {
    // issue B DMA first (fire-and-forget)
#pragma unroll
    for (int i = 0; i < 8; ++i) {
      int g = (wid * 8 + i) * 64 + lane;  // granule index 0..2047
      int brow = g >> 3, cg = g & 7;
      const f16* bsrc = W16 + (size_t)(v * 256 + brow) * K + k0 + ((cg ^ (brow & 7)) << 3);
      gload16(bsrc, smem + 16384 + (wid * 8 + i) * 1024);
    }
    if constexpr (PRE) {
      // A via DMA too: linear dest granule g, source column seg = pos ^ (row&7)
#pragma unroll
      for (int s = 0; s < 4; ++s) {
        int g = s * 256 + tid;
        int row = g >> 3, pos = g & 7;
        int seg = pos ^ (row & 7);
        size_t arow = (size_t)(b0 + (row >> 5)) * 1024 + t0 + (row & 31);
        const f16* asrc = A16 + arow * K + k0 + seg * 8;
        gload16(asrc, smem + (s * 256 + (tid >> 6) * 64) * 16 + (tid & 63) * 16);
      }
    } else {
      // stage A: load f32, cvt_pkrtz, swizzled ds_write (4 slots/thread)
#pragma unroll
      for (int s = 0; s < 4; ++s) {
        int slot = s * 256 + tid;
        int row = slot >> 3, seg = slot & 7;
        size_t arow = (size_t)(b0 + (row >> 5)) * 1024 + t0 + (row & 31);
        const float* ga = Aptr + arow * K + k0 + seg * 8;
        float4 v0 = *(const float4*)ga;
        float4 v1 = *(const float4*)(ga + 4);
        *(iv4*)(smem + row * 128 + ((seg ^ (row & 7)) << 4)) = cvt8(v0, v1);
      }
    }
    __syncthreads();  // drains vmcnt (DMAs) + lgkm
#pragma unroll
    for (int kk = 0; kk < 2; ++kk) {
      f16x8 af[4], bf[8];
#pragma unroll
      for (int mi = 0; mi < 4; ++mi) {
        int ba = (wm * 64 + mi * 16 + lr) * 128 + kk * 64 + lk * 16;
        af[mi] = *(const f16x8*)(smem + (ba ^ xsw));
      }
#pragma unroll
      for (int ni = 0; ni < 8; ++ni) {
        int bb = (wn * 128 + ni * 16 + lr) * 128 + kk * 64 + lk * 16;
        bf[ni] = *(const f16x8*)(smem + 16384 + (bb ^ xsw));
      }
#pragma unroll
      for (int mi = 0; mi < 4; ++mi)
#pragma unroll
        for (int ni = 0; ni < 8; ++ni)
          acc[mi][ni] = __builtin_amdgcn_mfma_f32_16x16x32_f16(af[mi], bf[ni], acc[mi][ni], 0, 0, 0);
    }
    __syncthreads();
  }

  // epilogue: two passes (t_loc halves), 32KB LDS each (round-11 proven)
  float biasv[8];
#pragma unroll
  for (int ni = 0; ni < 8; ++ni)
    biasv[ni] = bsum[unit * 1024 + v * 256 + wn * 128 + ni * 16 + lr];
  char* Pv = P4 + ((size_t)unit << 26) + ((size_t)v << 24);
#pragma unroll
  for (int pass = 0; pass < 2; ++pass) {
    __syncthreads();
#pragma unroll
    for (int mi2 = 0; mi2 < 2; ++mi2) {
      int mi = mi2 * 2 + pass;
#pragma unroll
      for (int ni = 0; ni < 8; ++ni) {
        int col = wn * 128 + ni * 16 + lr;
        int wc = col >> 5, jc = (col >> 4) & 1, lc = col & 15;
#pragma unroll
        for (int rr = 0; rr < 4; ++rr) {
          int row = wm * 64 + mi * 16 + lk * 4 + rr;
          int bsub = row >> 5, tl = row & 15;
          int unit2 = tl * 256 + wc * 32 + jc * 16 + lc;
          int off = (unit2 * 8 + bsub * 2) ^ ((tl & 7) << 4);
          *(f16*)(smem + off) = (f16)(acc[mi][ni][rr] + biasv[ni]);
        }
      }
    }
    __syncthreads();
#pragma unroll
    for (int k = 0; k < 16; ++k) {
      int uid = k * 256 + tid;
      int tl = uid >> 8, sub = uid & 255;
      int off = (uid * 8) ^ ((tl & 7) << 4);
      unsigned long long val = *(const unsigned long long*)(smem + off);
      int t_loc = pass * 16 + tl;
      int wq = sub >> 5, jq = (sub >> 4) & 1, lq = sub & 15;
      size_t didx =
          (((size_t)((t0 + t_loc) * 4 + c) * 512) + wq * 64 + jq * 32 + lkb * 16 + lq) << 3;
      *(unsigned long long*)(Pv + didx) = val;
    }
  }
}

// ---------------- LSTM recurrence: 64 WGs = (unit, batch-pair), i8 MFMA, 1 cell/lane ----------------
__global__ __attribute__((amdgpu_flat_work_group_size(512, 512), amdgpu_waves_per_eu(2, 2)))
void lstm_rec5(const char* __restrict__ Wq4,
               const float* __restrict__ fsc4,
               const char* __restrict__ P4,
               const float* __restrict__ h0m,
               const float* __restrict__ c0m,
               const float* __restrict__ h0b,
               const float* __restrict__ c0b,
               f16* __restrict__ hid4) {
  const int wg = blockIdx.x;
  const int u = wg >> 4, c16 = wg & 15;
  const int dir = u & 1;
  const int tid = threadIdx.x;
  const int l = tid & 63, w = tid >> 6;
  const int lr = l & 15, lk = l >> 4;
  const int jj = lk >> 1, selb = lk & 1;
  const int r2 = lr & 1;
  const int swzA = r2 ? 80 : 0;
  const int swzW = selb ? 80 : 0;
  const int j = w * 32 + jj * 16 + lr;  // hidden unit owned by this lane

  __shared__ __align__(16) char hbuf[2][512];  // [2 batch rows][256 k] i8, swizzled

  // ---- weights: 32 x iv4 = 128 regs ----
  iv4 Bf[4][8];
  const char* wb = Wq4 + ((size_t)u << 18);
#pragma unroll
  for (int nt = 0; nt < 8; ++nt) {
    int n = (nt >> 1) * 256 + w * 32 + ((nt & 1) << 4) + lr;
#pragma unroll
    for (int ks = 0; ks < 4; ++ks)
      Bf[ks][nt] = *(const iv4*)(wb + (size_t)n * 256 + ks * 64 + lk * 16);
  }
  float fv[4], fv4[4];
#pragma unroll
  for (int v = 0; v < 4; ++v) {
    fv[v] = fsc4[u * 1024 + v * 256 + j];
    fv4[v] = fv[v] * 4.f;
  }

  // ---- init c / h0 (h0 quantized at scale 127/4, step-0 uses fv4) ----
  const int b = c16 * 2 + selb;
  const float* h0 = (u < 2 ? h0m : h0b) + (size_t)dir * BATCH * HID;
  const float* c0 = (u < 2 ? c0m : c0b) + (size_t)dir * BATCH * HID;
  float cst = c0[b * HID + j];
  {
    float hv = h0[b * HID + j] * 31.75f;
    int hq = (int)rintf(hv);
    hq = hq > 127 ? 127 : (hq < -127 ? -127 : hq);
    hbuf[0][selb * 256 + (j ^ swzW)] = (char)hq;
  }

  // ---- P preload for s=0 ----
  const char* Pc = P4 + ((size_t)u << 26);
  const size_t soff =
      (size_t)((w * 64 + jj * 32 + (((c16 >> 1) & 1) << 4) + lr) * 8 + (c16 & 1) * 4);
  const int cq = c16 >> 2;
  f16x2 Pa[4], Pb[4];
  {
    int t0 = dir ? (S_LEN - 1) : 0;
    size_t tb = ((size_t)((t0 << 2) + cq) << 12) + soff;
#pragma unroll
    for (int v = 0; v < 4; ++v) Pa[v] = *(const f16x2*)(Pc + ((size_t)v << 24) + tb);
  }
  WG_BARRIER();

#define LSTM_STEP(S_, SP_, PC_, PN_, FV_)                                                   \
  {                                                                                         \
    const int t = dir ? (S_LEN - 1 - (S_)) : (S_);                                          \
    {                                                                                       \
      int s2 = ((S_) + 1 < S_LEN) ? (S_) + 1 : (S_);                                        \
      int t2 = dir ? (S_LEN - 1 - s2) : s2;                                                 \
      size_t tb = ((size_t)((t2 << 2) + cq) << 12) + soff;                                  \
      _Pragma("unroll") for (int v = 0; v < 4; ++v)                                         \
          PN_[v] = *(const f16x2*)(Pc + ((size_t)v << 24) + tb);                            \
    }                                                                                       \
    iv4 ia[8];                                                                              \
    _Pragma("unroll") for (int nt = 0; nt < 8; ++nt) ia[nt] = (iv4){0, 0, 0, 0};            \
    const char* hb = hbuf[SP_];                                                             \
    _Pragma("unroll") for (int ks = 0; ks < 4; ++ks) {                                      \
      iv4 Af = *(const iv4*)(hb + r2 * 256 + ((ks * 64 + lk * 16) ^ swzA));                 \
      _Pragma("unroll") for (int nt = 0; nt < 8; ++nt)                                      \
          ia[nt] = __builtin_amdgcn_mfma_i32_16x16x64_i8(Af, Bf[ks][nt], ia[nt], 0, 0, 0);  \
    }                                                                                       \
    float z[4];                                                                             \
    _Pragma("unroll") for (int v = 0; v < 4; ++v) {                                         \
      int e0 = selb ? ia[v * 2][1] : ia[v * 2][0];                                          \
      int e1 = selb ? ia[v * 2 + 1][1] : ia[v * 2 + 1][0];                                  \
      int iz = jj ? e1 : e0;                                                                \
      float pv = selb ? (float)PC_[v][1] : (float)PC_[v][0];                                \
      z[v] = pv + FV_[v] * (float)iz;                                                       \
    }                                                                                       \
    float zi = z[0], zf = z[1], zg = z[2], zo = z[3];                                       \
    float ei = EXP2(-zi), ef = EXP2(-zf), eg = EXP2(-zg), eo = EXP2(-zo);                   \
    float di = 1.f + ei, df = 1.f + ef, dg = 1.f + eg, dof = 1.f + eo;                      \
    float r1 = RCP(di * df);                                                                \
    float si = r1 * df, sf = r1 * di;                                                       \
    float r2x = RCP(dg * dof);                                                              \
    float tg = 2.f * (r2x * dof) - 1.f, so = r2x * dg;                                      \
    float cc = sf * cst + si * tg;                                                          \
    cst = cc;                                                                               \
    float ec = EXP2(-L2E2 * cc);                                                            \
    float th = 2.f * RCP(1.f + ec) - 1.f;                                                   \
    float hh = so * th;                                                                     \
    int hq = (int)rintf(hh * 127.f);                                                        \
    hbuf[SP_ ^ 1][selb * 256 + (j ^ swzW)] = (char)hq;                                      \
    hid4[((size_t)b << 20) + ((size_t)t << 10) + (u << 8) + j] = (f16)hh;                   \
    WG_BARRIER();                                                                           \
  }

  LSTM_STEP(0, 0, Pa, Pb, fv4);
  for (int s = 1; s <= 1021; s += 2) {
    LSTM_STEP(s, 1, Pb, Pa, fv);
    LSTM_STEP(s + 1, 0, Pa, Pb, fv);
  }
  LSTM_STEP(1023, 1, Pb, Pa, fv);
#undef LSTM_STEP
}

// ---------------- emissions ----------------
__global__ __launch_bounds__(256) void emis_kernel(const f16* __restrict__ hid4,
                                                   const f16* __restrict__ wtag,
                                                   const float* __restrict__ btag,
                                                   const f16* __restrict__ wbin,
                                                   const float* __restrict__ bbin,
                                                   float* __restrict__ emis,
                                                   float* __restrict__ emisb) {
  const int tid = threadIdx.x;
  const int rl = tid >> 4, n = tid & 15;
  const size_t row = (size_t)blockIdx.x * 16 + rl;
  const f16x8* hv = (const f16x8*)(hid4 + row * 1024);
  const f16x8* wv = (const f16x8*)(wtag + n * 1024);
  float acc = btag[n];
#pragma unroll 8
  for (int kc = 0; kc < 128; ++kc) acc = dot8(wv[kc], hv[kc], acc);
  emis[row * 16 + n] = acc;
  if (n < 5) {
    const f16x8* hv2 = (const f16x8*)(hid4 + row * 1024 + 512);
    const f16x8* wv2 = (const f16x8*)(wbin + (size_t)n * 512);
    float a2 = bbin[n];
#pragma unroll 8
    for (int kc = 0; kc < 64; ++kc) a2 = dot8(wv2[kc], hv2[kc], a2);
    emisb[row * 5 + n] = a2;
  }
}

// ---------------- CRF forward (logZ): round-6 dataflow, single-wave sync ----------------
__global__ __launch_bounds__(64) void crf_logz(const float* __restrict__ emis,
                                               const float* __restrict__ trans,
                                               const float* __restrict__ emisb,
                                               const float* __restrict__ transb,
                                               const float* __restrict__ mask,
                                               float* __restrict__ outLogZ) {
  const int crf = blockIdx.x >> 5, b = blockIdx.x & 31;
  const int NTc = crf ? 5 : 16;
  const float* __restrict__ E = crf ? emisb : emis;
  const float* __restrict__ T = crf ? transb : trans;
  const int lane = threadIdx.x;
  const int jn = lane >> 2, p = lane & 3;
  const bool jv = (jn < NTc);
  const int jc = jv ? jn : 0;
  float Tc[4];
#pragma unroll
  for (int ii = 0; ii < 4; ++ii) {
    int i = p * 4 + ii;
    Tc[ii] = (jv && i < NTc) ? T[i * NTc + jn] : -1e30f;
  }
  __shared__ float as_[2][16];
  if (lane < 16) { as_[0][lane] = -1e30f; as_[1][lane] = -1e30f; }
  WAVE_SYNC();
  float alpha = 0.f;
  if (jv && p == 0) {
    alpha = T[1 * NTc + jn] + E[(size_t)(b << 10) * NTc + jn];  // SOS=1, t=0
    as_[0][jn] = alpha;
  }
  WAVE_SYNC();
  int cur = 0;
  const size_t ebase = (size_t)(b << 10) * NTc + jc;
  const int mbase = b << 10;
#define LDE(tt) E[ebase + (size_t)(tt)*NTc]
#define LDM(tt) mask[mbase + (tt)]

  auto step = [&](float e_tj, float m_t) {
    float v0 = (jv && (p * 4 + 0) < NTc) ? (as_[cur][p * 4 + 0] + Tc[0]) : -1e30f;
    float v1 = (jv && (p * 4 + 1) < NTc) ? (as_[cur][p * 4 + 1] + Tc[1]) : -1e30f;
    float v2 = (jv && (p * 4 + 2) < NTc) ? (as_[cur][p * 4 + 2] + Tc[2]) : -1e30f;
    float v3 = (jv && (p * 4 + 3) < NTc) ? (as_[cur][p * 4 + 3] + Tc[3]) : -1e30f;
    float mx = fmaxf(fmaxf(v0, v1), fmaxf(v2, v3));
    mx = fmaxf(mx, __shfl_xor(mx, 1, 4));
    mx = fmaxf(mx, __shfl_xor(mx, 2, 4));
    float ss = __expf(v0 - mx) + __expf(v1 - mx) + __expf(v2 - mx) + __expf(v3 - mx);
    ss += __shfl_xor(ss, 1, 4);
    ss += __shfl_xor(ss, 2, 4);
    if (jv && p == 0) {
      float newv = e_tj + mx + __logf(ss);
      alpha = (m_t > 0.5f) ? newv : alpha;
      as_[cur ^ 1][jn] = alpha;
    }
    WAVE_SYNC();
    cur ^= 1;
  };

  float eb[4], mb[4];
#pragma unroll
  for (int k = 0; k < 4; ++k) { eb[k] = LDE(1 + k); mb[k] = LDM(1 + k); }
  for (int t = 1; t <= 1017; t += 4) {
    float en[4], mn[4];
#pragma unroll
    for (int k = 0; k < 4; ++k) {
      int ix = t + 4 + k;
      ix = ix > 1023 ? 1023 : ix;
      en[k] = LDE(ix);
      mn[k] = LDM(ix);
    }
    step(eb[0], mb[0]); step(eb[1], mb[1]); step(eb[2], mb[2]); step(eb[3], mb[3]);
#pragma unroll
    for (int k = 0; k < 4; ++k) { eb[k] = en[k]; mb[k] = mn[k]; }
  }
  step(eb[0], mb[0]); step(eb[1], mb[1]); step(eb[2], mb[2]);
#undef LDE
#undef LDM

  if (lane == 0) {
    float mx = -1e30f;
    for (int jjx = 0; jjx < NTc; ++jjx) mx = fmaxf(mx, as_[cur][jjx] + T[jjx * NTc + 2]);
    float ss = 0.f;
    for (int jjx = 0; jjx < NTc; ++jjx) ss += __expf(as_[cur][jjx] + T[jjx * NTc + 2] - mx);
    outLogZ[crf * 32 + b] = mx + __logf(ss);
  }
}

// ---------------- CRF gold score ----------------
__global__ __launch_bounds__(64) void crf_score(const float* __restrict__ emis,
                                                const float* __restrict__ trans,
                                                const float* __restrict__ emisb,
                                                const float* __restrict__ transb,
                                                const float* __restrict__ mask,
                                                const int* __restrict__ tags,
                                                const int* __restrict__ tagsb,
                                                float* __restrict__ outScore) {
  const int crf = blockIdx.x >> 5, b = blockIdx.x & 31;
  const int NTc = crf ? 5 : 16;
  const float* __restrict__ E = crf ? emisb : emis;
  const float* __restrict__ T = crf ? transb : trans;
  const int* __restrict__ tg = (crf ? tagsb : tags) + (b << 10);
  const float* __restrict__ mk = mask + (b << 10);
  const int lane = threadIdx.x;
  float s = 0.f, cnt = 0.f;
  for (int t = lane; t < S_LEN; t += 64) {
    float m = mk[t];
    cnt += m;
    if (t >= 1 && m > 0.5f)
      s += E[((size_t)(b << 10) + t) * NTc + tg[t]] + T[tg[t - 1] * NTc + tg[t]];
  }
#pragma unroll
  for (int off = 32; off >= 1; off >>= 1) {
    s += __shfl_down(s, off);
    cnt += __shfl_down(cnt, off);
  }
  if (lane == 0) {
    int L = (int)(cnt + 0.5f);
    int t0 = tg[0];
    float tot = T[1 * NTc + t0] + E[(size_t)(b << 10) * NTc + t0] + s + T[tg[L - 1] * NTc + 2];
    outScore[crf * 32 + b] = tot;
  }
}

__global__ void finalk(const float* __restrict__ logZ, const float* __restrict__ score,
                       float* __restrict__ out) {
  int j = threadIdx.x;
  if (j < 2) {
    float a = 0.f;
    for (int b = 0; b < 32; ++b) a += logZ[j * 32 + b] - score[j * 32 + b];
    out[j] = a;
  }
}

extern "C" void kernel_launch(void* const* d_in, const int* in_sizes, int n_in,
                              void* d_out, int out_size, void* d_ws, size_t ws_size,
                              hipStream_t stream) {
  const float* x       = (const float*)d_in[0];
  const float* xbin    = (const float*)d_in[1];
  const float* mask    = (const float*)d_in[2];
  const int*   tags    = (const int*)d_in[3];
  const int*   tagsb   = (const int*)d_in[4];
  const float* trans   = (const float*)d_in[5];
  const float* transb  = (const float*)d_in[6];
  const float* w2f_ih  = (const float*)d_in[7];
  const float* w2f_hh  = (const float*)d_in[8];
  const float* b2f_ih  = (const float*)d_in[9];
  const float* b2f_hh  = (const float*)d_in[10];
  const float* w2b_ih  = (const float*)d_in[11];
  const float* w2b_hh  = (const float*)d_in[12];
  const float* b2b_ih  = (const float*)d_in[13];
  const float* b2b_hh  = (const float*)d_in[14];
  const float* w_bin   = (const float*)d_in[15];
  const float* bb_bin  = (const float*)d_in[16];
  const float* w1f_ih  = (const float*)d_in[17];
  const float* w1f_hh  = (const float*)d_in[18];
  const float* b1f_ih  = (const float*)d_in[19];
  const float* b1f_hh  = (const float*)d_in[20];
  const float* w1b_ih  = (const float*)d_in[21];
  const float* w1b_hh  = (const float*)d_in[22];
  const float* b1b_ih  = (const float*)d_in[23];
  const float* b1b_hh  = (const float*)d_in[24];
  const float* w_tag   = (const float*)d_in[25];
  const float* b_tag   = (const float*)d_in[26];
  const float* h0_bin  = (const float*)d_in[27];
  const float* c0_bin  = (const float*)d_in[28];
  const float* h0_main = (const float*)d_in[29];
  const float* c0_main = (const float*)d_in[30];

  char* ws = (char*)d_ws;
  char* P4    = ws;                                   // 4u x 64MiB = 256MiB
  f16* hid4   = (f16*)(ws + 268435456);               // 64MiB
  char* Wq4   = ws + 335544320;                       // 1MiB
  float* fsc4 = (float*)(ws + 336592896);             // 16KB
  f16* wtag   = (f16*)(ws + 336609280);
  f16* wbin   = (f16*)(ws + 336642048);
  float* emis  = (float*)(ws + 336647168);            // 2MiB
  float* emisb = (float*)(ws + 338744320);
  float* logZ  = (float*)(ws + 339399680);
  float* score = (float*)(ws + 339399936);
  float* bsum  = (float*)(ws + 339400704);            // 16KB
  f16* w16all  = (f16*)(ws + 340000768);              // 8MiB, ends 348389376
  f16* x16     = (f16*)(ws + 348389376);              // 32MiB
  f16* xbin16  = (f16*)(ws + 381943808);              // 96MiB, ends 482607104
  const bool pre = (ws_size >= 482607104ULL);

  // weight preps
  quant_whh<<<256, 256, 0, stream>>>(w1f_hh, Wq4 + 0 * 262144, fsc4 + 0 * 1024);
  quant_whh<<<256, 256, 0, stream>>>(w1b_hh, Wq4 + 1 * 262144, fsc4 + 1 * 1024);
  quant_whh<<<256, 256, 0, stream>>>(w2f_hh, Wq4 + 2 * 262144, fsc4 + 2 * 1024);
  quant_whh<<<256, 256, 0, stream>>>(w2b_hh, Wq4 + 3 * 262144, fsc4 + 3 * 1024);
  cvt_f32_f16<<<16, 256, 0, stream>>>(w_tag, wtag, 4096);
  cvt_f32_f16<<<3, 256, 0, stream>>>(w_bin, wbin, 640);
  cvt_wih<<<256, 256, 0, stream>>>(w1f_ih, w16all + 0, 512, 65536);
  cvt_wih<<<256, 256, 0, stream>>>(w1b_ih, w16all + 524288, 512, 65536);
  cvt_wih<<<768, 256, 0, stream>>>(w2f_ih, w16all + 1048576, 1536, 196608);
  cvt_wih<<<768, 256, 0, stream>>>(w2b_ih, w16all + 2621440, 1536, 196608);
  bias_pack<<<16, 256, 0, stream>>>(b1f_ih, b1f_hh, b1b_ih, b1b_hh,
                                    b2f_ih, b2f_hh, b2b_ih, b2b_hh, bsum);

  // fused input projections: 1D grid, XCD-grouped
  if (pre) {
    cvt_x16<<<8192, 256, 0, stream>>>(x, x16, 2097152);
    cvt_x16<<<24576, 256, 0, stream>>>(xbin, xbin16, 6291456);
    proj_gemm<true><<<4096, 256, 0, stream>>>(x, xbin, x16, xbin16, w16all, bsum, P4);
  } else {
    proj_gemm<false><<<4096, 256, 0, stream>>>(x, xbin, x16, xbin16, w16all, bsum, P4);
  }

  lstm_rec5<<<64, 512, 0, stream>>>(Wq4, fsc4, P4, h0_main, c0_main, h0_bin, c0_bin, hid4);
  emis_kernel<<<2048, 256, 0, stream>>>(hid4, wtag, b_tag, wbin, bb_bin, emis, emisb);
  crf_logz<<<64, 64, 0, stream>>>(emis, trans, emisb, transb, mask, logZ);
  crf_score<<<64, 64, 0, stream>>>(emis, trans, emisb, transb, mask, tags, tagsb, score);
  finalk<<<1, 64, 0, stream>>>(logZ, score, (float*)d_out);
}

// Round 13
// 1958.629 us; speedup vs baseline: 2.2362x; 1.0050x over previous
//
#include <hip/hip_runtime.h>

typedef _Float16 f16;
typedef _Float16 f16x2 __attribute__((ext_vector_type(2)));
typedef _Float16 f16x4 __attribute__((ext_vector_type(4)));
typedef _Float16 f16x8 __attribute__((ext_vector_type(8)));
typedef float f32x4 __attribute__((ext_vector_type(4)));
typedef int iv4 __attribute__((ext_vector_type(4)));

#define S_LEN 1024
#define BATCH 32
#define HID 256
#define L2E 1.4426950408889634f
#define L2E2 2.8853900817779268f

#if __has_builtin(__builtin_amdgcn_fdot2)
#define FDOT2(a, b, c) __builtin_amdgcn_fdot2((a), (b), (c), false)
#else
static __device__ __forceinline__ float FDOT2(f16x2 a, f16x2 b, float c) {
  return c + (float)a[0] * (float)b[0] + (float)a[1] * (float)b[1];
}
#endif

__device__ __forceinline__ float EXP2(float x) {
#if __has_builtin(__builtin_amdgcn_exp2f)
  return __builtin_amdgcn_exp2f(x);
#else
  return exp2f(x);
#endif
}
__device__ __forceinline__ float RCP(float x) {
#if __has_builtin(__builtin_amdgcn_rcpf)
  return __builtin_amdgcn_rcpf(x);
#else
  return 1.0f / x;
#endif
}

__device__ __forceinline__ iv4 cvt8(float4 a, float4 b) {
#if __has_builtin(__builtin_amdgcn_cvt_pkrtz)
  auto p0 = __builtin_amdgcn_cvt_pkrtz(a.x, a.y);
  auto p1 = __builtin_amdgcn_cvt_pkrtz(a.z, a.w);
  auto p2 = __builtin_amdgcn_cvt_pkrtz(b.x, b.y);
  auto p3 = __builtin_amdgcn_cvt_pkrtz(b.z, b.w);
  iv4 o;
  o[0] = __builtin_bit_cast(int, p0);
  o[1] = __builtin_bit_cast(int, p1);
  o[2] = __builtin_bit_cast(int, p2);
  o[3] = __builtin_bit_cast(int, p3);
  return o;
#else
  f16x8 h;
  h[0] = (f16)a.x; h[1] = (f16)a.y; h[2] = (f16)a.z; h[3] = (f16)a.w;
  h[4] = (f16)b.x; h[5] = (f16)b.y; h[6] = (f16)b.z; h[7] = (f16)b.w;
  return __builtin_bit_cast(iv4, h);
#endif
}

#if __has_builtin(__builtin_amdgcn_global_load_lds)
__device__ __forceinline__ void gload16(const void* g, void* l) {
  __builtin_amdgcn_global_load_lds((const __attribute__((address_space(1))) void*)g,
                                   (__attribute__((address_space(3))) void*)l, 16, 0, 0);
}
#else
__device__ __forceinline__ void gload16(const void* g, void* l) {
  int lane = __builtin_amdgcn_mbcnt_hi(~0u, __builtin_amdgcn_mbcnt_lo(~0u, 0));
  ((f16x8*)l)[lane] = *(const f16x8*)g;  // emulate base + lane*16
}
#endif

// barrier that waits LDS only (no vmcnt drain)
#define WG_BARRIER()                                                  \
  do {                                                                \
    __builtin_amdgcn_sched_barrier(0);                                \
    asm volatile("s_waitcnt lgkmcnt(0)\n\ts_barrier" ::: "memory");   \
    __builtin_amdgcn_sched_barrier(0);                                \
  } while (0)

// single-wave LDS visibility (block == 1 wave64): no s_barrier needed
#define WAVE_SYNC()                                                   \
  do {                                                                \
    __builtin_amdgcn_sched_barrier(0);                                \
    asm volatile("s_waitcnt lgkmcnt(0)" ::: "memory");                \
    __builtin_amdgcn_sched_barrier(0);                                \
  } while (0)

__device__ __forceinline__ float dot8(f16x8 w, f16x8 h, float acc) {
  f16x2 a, b;
  a[0] = w[0]; a[1] = w[1]; b[0] = h[0]; b[1] = h[1]; acc = FDOT2(a, b, acc);
  a[0] = w[2]; a[1] = w[3]; b[0] = h[2]; b[1] = h[3]; acc = FDOT2(a, b, acc);
  a[0] = w[4]; a[1] = w[5]; b[0] = h[4]; b[1] = h[5]; acc = FDOT2(a, b, acc);
  a[0] = w[6]; a[1] = w[7]; b[0] = h[6]; b[1] = h[7]; acc = FDOT2(a, b, acc);
  return acc;
}

// ---------------- f32 -> f16 convert (plain) ----------------
__global__ void cvt_f32_f16(const float* __restrict__ src, f16* __restrict__ dst, int n4) {
  int i = blockIdx.x * 256 + threadIdx.x;
  if (i < n4) {
    float4 v = ((const float4*)src)[i];
    f16x4 h;
    h[0] = (f16)v.x; h[1] = (f16)v.y; h[2] = (f16)v.z; h[3] = (f16)v.w;
    ((f16x4*)dst)[i] = h;
  }
}

// ---------------- w_ih f32 -> f16, log2e row-scaled ----------------
__global__ void cvt_wih(const float* __restrict__ src, f16* __restrict__ dst, int K, int total8) {
  int i = blockIdx.x * 256 + threadIdx.x;
  if (i < total8) {
    int row = (int)(((long long)i * 8) / K);
    float sc = (row >= 512 && row < 768) ? L2E2 : L2E;
    const float* s = src + (size_t)i * 8;
    float4 a = *(const float4*)s;
    float4 b = *(const float4*)(s + 4);
    f16x8 h;
    h[0] = (f16)(a.x * sc); h[1] = (f16)(a.y * sc); h[2] = (f16)(a.z * sc); h[3] = (f16)(a.w * sc);
    h[4] = (f16)(b.x * sc); h[5] = (f16)(b.y * sc); h[6] = (f16)(b.z * sc); h[7] = (f16)(b.w * sc);
    *(f16x8*)(dst + (size_t)i * 8) = h;
  }
}

// ---------------- bias pack: bsum[u][n] = (bih+bhh)*sc ----------------
__global__ void bias_pack(const float* __restrict__ a0, const float* __restrict__ h0,
                          const float* __restrict__ a1, const float* __restrict__ h1,
                          const float* __restrict__ a2, const float* __restrict__ h2,
                          const float* __restrict__ a3, const float* __restrict__ h3,
                          float* __restrict__ bsum) {
  int i = blockIdx.x * 256 + threadIdx.x;
  if (i < 4096) {
    int u = i >> 10, n = i & 1023;
    float sc = (n >= 512 && n < 768) ? L2E2 : L2E;
    const float* pa = u == 0 ? a0 : u == 1 ? a1 : u == 2 ? a2 : a3;
    const float* ph = u == 0 ? h0 : u == 1 ? h1 : u == 2 ? h2 : h3;
    bsum[i] = (pa[n] + ph[n]) * sc;
  }
}

// ---------------- whh f32 -> i8 per-row symmetric quant, log2e pre-scaled ----------------
__global__ __launch_bounds__(256) void quant_whh(const float* __restrict__ src,
                                                 char* __restrict__ dstq,
                                                 float* __restrict__ fsc) {
  const int row = blockIdx.x * 4 + (threadIdx.x >> 6);
  const int lane = threadIdx.x & 63;
  const float sc = (row >= 512 && row < 768) ? L2E2 : L2E;
  float4 v = *(const float4*)(src + (size_t)row * 256 + lane * 4);
  float w0 = v.x * sc, w1 = v.y * sc, w2 = v.z * sc, w3 = v.w * sc;
  float mx = fmaxf(fmaxf(fabsf(w0), fabsf(w1)), fmaxf(fabsf(w2), fabsf(w3)));
#pragma unroll
  for (int off = 1; off < 64; off <<= 1) mx = fmaxf(mx, __shfl_xor(mx, off));
  mx = fmaxf(mx, 1e-20f);
  float inv = 127.0f / mx;
  int q0 = (int)rintf(w0 * inv), q1 = (int)rintf(w1 * inv);
  int q2 = (int)rintf(w2 * inv), q3 = (int)rintf(w3 * inv);
  int pk = (q0 & 0xff) | ((q1 & 0xff) << 8) | ((q2 & 0xff) << 16) | ((q3 & 0xff) << 24);
  ((int*)(dstq + (size_t)row * 256))[lane] = pk;
  if (lane == 0) fsc[row] = mx / 16129.0f;
}

// ---------------- fused input-projection GEMM -> P4 planes (pipelined dbuf) ----------------
// 1D grid 4096, XCD-grouped. LDS 96KB: A dbuf [0,32K), B dbuf [32K,96K).
// Per step: issue next-A reg-loads, next-B DMAs, cvt+write next-A (implicit vmcnt<=8
// retires current-B + next-A by FIFO, next-B stays in flight); lgkm-only barriers.
__global__ __launch_bounds__(256) void proj_gemm(const float* __restrict__ x,
                                                 const float* __restrict__ xbin,
                                                 const f16* __restrict__ w16all,
                                                 const float* __restrict__ bsum,
                                                 char* __restrict__ P4) {
  __shared__ __align__(16) char smem[98304];  // A0 [0,16K) A1 [16K,32K) B0 [32K,64K) B1 [64K,96K)
  const int L = blockIdx.x;
  const int q = L >> 5, r = L & 31;
  const int v = r >> 3;
  const int ub = q * 8 + (r & 7);
  const int unit = ub >> 8;
  const int bm = ub & 255;
  const int K = (unit < 2) ? 512 : 1536;
  const float* Aptr = (unit < 2) ? x : xbin;
  const size_t woff = (unit == 0) ? 0u : (unit == 1) ? 524288u : (unit == 2) ? 1048576u : 2621440u;
  const f16* W16 = w16all + woff;
  const int bgrp = bm >> 5, t0 = (bm & 31) * 32;
  const int b0 = bgrp * 4, c = bgrp >> 1, lkb = bgrp & 1;
  const int tid = threadIdx.x;
  const int lane = tid & 63, wid = tid >> 6;
  const int wm = wid >> 1, wn = wid & 1;
  const int lr = lane & 15, lk = lane >> 4;
  const int xsw = (lr & 7) << 4;  // read-side granule swizzle

  f32x4 acc[4][8];
#pragma unroll
  for (int i = 0; i < 4; ++i)
#pragma unroll
    for (int n = 0; n < 8; ++n) acc[i][n] = (f32x4){0.f, 0.f, 0.f, 0.f};

#define PROJ_PREFETCH(KN_, AO_, BO_)                                                        \
  if ((KN_) < K) {                                                                          \
    float4 ar0[4], ar1[4];                                                                  \
    _Pragma("unroll") for (int s = 0; s < 4; ++s) {                                         \
      int slot = s * 256 + tid;                                                             \
      int row = slot >> 3, seg = slot & 7;                                                  \
      size_t arow = (size_t)(b0 + (row >> 5)) * 1024 + t0 + (row & 31);                     \
      const float* ga = Aptr + arow * K + (KN_) + seg * 8;                                  \
      ar0[s] = *(const float4*)ga;                                                          \
      ar1[s] = *(const float4*)(ga + 4);                                                    \
    }                                                                                       \
    __builtin_amdgcn_sched_barrier(0);                                                      \
    _Pragma("unroll") for (int i = 0; i < 8; ++i) {                                         \
      int g = (wid * 8 + i) * 64 + lane;                                                    \
      int brow = g >> 3, cg = g & 7;                                                        \
      const f16* bsrc = W16 + (size_t)(v * 256 + brow) * K + (KN_) + ((cg ^ (brow & 7)) << 3); \
      gload16(bsrc, smem + (BO_) + (wid * 8 + i) * 1024);                                   \
    }                                                                                       \
    __builtin_amdgcn_sched_barrier(0);                                                      \
    _Pragma("unroll") for (int s = 0; s < 4; ++s) {                                         \
      int slot = s * 256 + tid;                                                             \
      int row = slot >> 3, seg = slot & 7;                                                  \
      *(iv4*)(smem + (AO_) + row * 128 + ((seg ^ (row & 7)) << 4)) = cvt8(ar0[s], ar1[s]);  \
    }                                                                                       \
    __builtin_amdgcn_sched_barrier(0);                                                      \
  } else {                                                                                  \
    __builtin_amdgcn_sched_barrier(0);                                                      \
    asm volatile("s_waitcnt vmcnt(0)" ::: "memory");                                        \
    __builtin_amdgcn_sched_barrier(0);                                                      \
  }

#define PROJ_COMPUTE(AO_, BO_)                                                              \
  _Pragma("unroll") for (int kk = 0; kk < 2; ++kk) {                                        \
    f16x8 af[4], bf[8];                                                                     \
    _Pragma("unroll") for (int mi = 0; mi < 4; ++mi) {                                      \
      int ba = (wm * 64 + mi * 16 + lr) * 128 + kk * 64 + lk * 16;                          \
      af[mi] = *(const f16x8*)(smem + (AO_) + (ba ^ xsw));                                  \
    }                                                                                       \
    _Pragma("unroll") for (int ni = 0; ni < 8; ++ni) {                                      \
      int bb = (wn * 128 + ni * 16 + lr) * 128 + kk * 64 + lk * 16;                         \
      bf[ni] = *(const f16x8*)(smem + (BO_) + (bb ^ xsw));                                  \
    }                                                                                       \
    _Pragma("unroll") for (int mi = 0; mi < 4; ++mi)                                        \
      _Pragma("unroll") for (int ni = 0; ni < 8; ++ni)                                      \
        acc[mi][ni] = __builtin_amdgcn_mfma_f32_16x16x32_f16(af[mi], bf[ni], acc[mi][ni], 0, 0, 0); \
  }

  PROJ_PREFETCH(0, 0, 32768);
  for (int k0 = 0; k0 < K; k0 += 128) {
    PROJ_PREFETCH(k0 + 64, 16384, 65536);
    WG_BARRIER();
    PROJ_COMPUTE(0, 32768);
    WG_BARRIER();
    PROJ_PREFETCH(k0 + 128, 0, 32768);
    WG_BARRIER();
    PROJ_COMPUTE(16384, 65536);
    WG_BARRIER();
  }
#undef PROJ_PREFETCH
#undef PROJ_COMPUTE

  // epilogue: two passes (t_loc halves), 32KB LDS each (round-11 proven; reuses A dbuf region)
  float biasv[8];
#pragma unroll
  for (int ni = 0; ni < 8; ++ni)
    biasv[ni] = bsum[unit * 1024 + v * 256 + wn * 128 + ni * 16 + lr];
  char* Pv = P4 + ((size_t)unit << 26) + ((size_t)v << 24);
#pragma unroll
  for (int pass = 0; pass < 2; ++pass) {
    __syncthreads();
#pragma unroll
    for (int mi2 = 0; mi2 < 2; ++mi2) {
      int mi = mi2 * 2 + pass;
#pragma unroll
      for (int ni = 0; ni < 8; ++ni) {
        int col = wn * 128 + ni * 16 + lr;
        int wc = col >> 5, jc = (col >> 4) & 1, lc = col & 15;
#pragma unroll
        for (int rr = 0; rr < 4; ++rr) {
          int row = wm * 64 + mi * 16 + lk * 4 + rr;
          int bsub = row >> 5, tl = row & 15;
          int unit2 = tl * 256 + wc * 32 + jc * 16 + lc;
          int off = (unit2 * 8 + bsub * 2) ^ ((tl & 7) << 4);
          *(f16*)(smem + off) = (f16)(acc[mi][ni][rr] + biasv[ni]);
        }
      }
    }
    __syncthreads();
#pragma unroll
    for (int k = 0; k < 16; ++k) {
      int uid = k * 256 + tid;
      int tl = uid >> 8, sub = uid & 255;
      int off = (uid * 8) ^ ((tl & 7) << 4);
      unsigned long long val = *(const unsigned long long*)(smem + off);
      int t_loc = pass * 16 + tl;
      int wq = sub >> 5, jq = (sub >> 4) & 1, lq = sub & 15;
      size_t didx =
          (((size_t)((t0 + t_loc) * 4 + c) * 512) + wq * 64 + jq * 32 + lkb * 16 + lq) << 3;
      *(unsigned long long*)(Pv + didx) = val;
    }
  }
}

// ---------------- LSTM recurrence: 64 WGs = (unit, batch-pair), i8 MFMA, 1 cell/lane ----------------
__global__ __attribute__((amdgpu_flat_work_group_size(512, 512), amdgpu_waves_per_eu(2, 2)))
void lstm_rec5(const char* __restrict__ Wq4,
               const float* __restrict__ fsc4,
               const char* __restrict__ P4,
               const float* __restrict__ h0m,
               const float* __restrict__ c0m,
               const float* __restrict__ h0b,
               const float* __restrict__ c0b,
               f16* __restrict__ hid4) {
  const int wg = blockIdx.x;
  const int u = wg >> 4, c16 = wg & 15;
  const int dir = u & 1;
  const int tid = threadIdx.x;
  const int l = tid & 63, w = tid >> 6;
  const int lr = l & 15, lk = l >> 4;
  const int jj = lk >> 1, selb = lk & 1;
  const int r2 = lr & 1;
  const int swzA = r2 ? 80 : 0;
  const int swzW = selb ? 80 : 0;
  const int j = w * 32 + jj * 16 + lr;  // hidden unit owned by this lane

  __shared__ __align__(16) char hbuf[2][512];  // [2 batch rows][256 k] i8, swizzled

  // ---- weights: 32 x iv4 = 128 regs ----
  iv4 Bf[4][8];
  const char* wb = Wq4 + ((size_t)u << 18);
#pragma unroll
  for (int nt = 0; nt < 8; ++nt) {
    int n = (nt >> 1) * 256 + w * 32 + ((nt & 1) << 4) + lr;
#pragma unroll
    for (int ks = 0; ks < 4; ++ks)
      Bf[ks][nt] = *(const iv4*)(wb + (size_t)n * 256 + ks * 64 + lk * 16);
  }
  float fv[4], fv4[4];
#pragma unroll
  for (int v = 0; v < 4; ++v) {
    fv[v] = fsc4[u * 1024 + v * 256 + j];
    fv4[v] = fv[v] * 4.f;
  }

  // ---- init c / h0 (h0 quantized at scale 127/4, step-0 uses fv4) ----
  const int b = c16 * 2 + selb;
  const float* h0 = (u < 2 ? h0m : h0b) + (size_t)dir * BATCH * HID;
  const float* c0 = (u < 2 ? c0m : c0b) + (size_t)dir * BATCH * HID;
  float cst = c0[b * HID + j];
  {
    float hv = h0[b * HID + j] * 31.75f;
    int hq = (int)rintf(hv);
    hq = hq > 127 ? 127 : (hq < -127 ? -127 : hq);
    hbuf[0][selb * 256 + (j ^ swzW)] = (char)hq;
  }

  // ---- P preload for s=0 ----
  const char* Pc = P4 + ((size_t)u << 26);
  const size_t soff =
      (size_t)((w * 64 + jj * 32 + (((c16 >> 1) & 1) << 4) + lr) * 8 + (c16 & 1) * 4);
  const int cq = c16 >> 2;
  f16x2 Pa[4], Pb[4];
  {
    int t0 = dir ? (S_LEN - 1) : 0;
    size_t tb = ((size_t)((t0 << 2) + cq) << 12) + soff;
#pragma unroll
    for (int v = 0; v < 4; ++v) Pa[v] = *(const f16x2*)(Pc + ((size_t)v << 24) + tb);
  }
  WG_BARRIER();

#define LSTM_STEP(S_, SP_, PC_, PN_, FV_)                                                   \
  {                                                                                         \
    const int t = dir ? (S_LEN - 1 - (S_)) : (S_);                                          \
    {                                                                                       \
      int s2 = ((S_) + 1 < S_LEN) ? (S_) + 1 : (S_);                                        \
      int t2 = dir ? (S_LEN - 1 - s2) : s2;                                                 \
      size_t tb = ((size_t)((t2 << 2) + cq) << 12) + soff;                                  \
      _Pragma("unroll") for (int v = 0; v < 4; ++v)                                         \
          PN_[v] = *(const f16x2*)(Pc + ((size_t)v << 24) + tb);                            \
    }                                                                                       \
    iv4 ia[8];                                                                              \
    _Pragma("unroll") for (int nt = 0; nt < 8; ++nt) ia[nt] = (iv4){0, 0, 0, 0};            \
    const char* hb = hbuf[SP_];                                                             \
    _Pragma("unroll") for (int ks = 0; ks < 4; ++ks) {                                      \
      iv4 Af = *(const iv4*)(hb + r2 * 256 + ((ks * 64 + lk * 16) ^ swzA));                 \
      _Pragma("unroll") for (int nt = 0; nt < 8; ++nt)                                      \
          ia[nt] = __builtin_amdgcn_mfma_i32_16x16x64_i8(Af, Bf[ks][nt], ia[nt], 0, 0, 0);  \
    }                                                                                       \
    float z[4];                                                                             \
    _Pragma("unroll") for (int v = 0; v < 4; ++v) {                                         \
      int e0 = selb ? ia[v * 2][1] : ia[v * 2][0];                                          \
      int e1 = selb ? ia[v * 2 + 1][1] : ia[v * 2 + 1][0];                                  \
      int iz = jj ? e1 : e0;                                                                \
      float pv = selb ? (float)PC_[v][1] : (float)PC_[v][0];                                \
      z[v] = pv + FV_[v] * (float)iz;                                                       \
    }                                                                                       \
    float zi = z[0], zf = z[1], zg = z[2], zo = z[3];                                       \
    float ei = EXP2(-zi), ef = EXP2(-zf), eg = EXP2(-zg), eo = EXP2(-zo);                   \
    float di = 1.f + ei, df = 1.f + ef, dg = 1.f + eg, dof = 1.f + eo;                      \
    float r1 = RCP(di * df);                                                                \
    float si = r1 * df, sf = r1 * di;                                                       \
    float r2x = RCP(dg * dof);                                                              \
    float tg = 2.f * (r2x * dof) - 1.f, so = r2x * dg;                                      \
    float cc = sf * cst + si * tg;                                                          \
    cst = cc;                                                                               \
    float ec = EXP2(-L2E2 * cc);                                                            \
    float th = 2.f * RCP(1.f + ec) - 1.f;                                                   \
    float hh = so * th;                                                                     \
    int hq = (int)rintf(hh * 127.f);                                                        \
    hbuf[SP_ ^ 1][selb * 256 + (j ^ swzW)] = (char)hq;                                      \
    hid4[((size_t)b << 20) + ((size_t)t << 10) + (u << 8) + j] = (f16)hh;                   \
    WG_BARRIER();                                                                           \
  }

  LSTM_STEP(0, 0, Pa, Pb, fv4);
  for (int s = 1; s <= 1021; s += 2) {
    LSTM_STEP(s, 1, Pb, Pa, fv);
    LSTM_STEP(s + 1, 0, Pa, Pb, fv);
  }
  LSTM_STEP(1023, 1, Pb, Pa, fv);
#undef LSTM_STEP
}

// ---------------- emissions ----------------
__global__ __launch_bounds__(256) void emis_kernel(const f16* __restrict__ hid4,
                                                   const f16* __restrict__ wtag,
                                                   const float* __restrict__ btag,
                                                   const f16* __restrict__ wbin,
                                                   const float* __restrict__ bbin,
                                                   float* __restrict__ emis,
                                                   float* __restrict__ emisb) {
  const int tid = threadIdx.x;
  const int rl = tid >> 4, n = tid & 15;
  const size_t row = (size_t)blockIdx.x * 16 + rl;
  const f16x8* hv = (const f16x8*)(hid4 + row * 1024);
  const f16x8* wv = (const f16x8*)(wtag + n * 1024);
  float acc = btag[n];
#pragma unroll 8
  for (int kc = 0; kc < 128; ++kc) acc = dot8(wv[kc], hv[kc], acc);
  emis[row * 16 + n] = acc;
  if (n < 5) {
    const f16x8* hv2 = (const f16x8*)(hid4 + row * 1024 + 512);
    const f16x8* wv2 = (const f16x8*)(wbin + (size_t)n * 512);
    float a2 = bbin[n];
#pragma unroll 8
    for (int kc = 0; kc < 64; ++kc) a2 = dot8(wv2[kc], hv2[kc], a2);
    emisb[row * 5 + n] = a2;
  }
}

// ---------------- CRF forward (logZ): round-6 dataflow, single-wave sync ----------------
__global__ __launch_bounds__(64) void crf_logz(const float* __restrict__ emis,
                                               const float* __restrict__ trans,
                                               const float* __restrict__ emisb,
                                               const float* __restrict__ transb,
                                               const float* __restrict__ mask,
                                               float* __restrict__ outLogZ) {
  const int crf = blockIdx.x >> 5, b = blockIdx.x & 31;
  const int NTc = crf ? 5 : 16;
  const float* __restrict__ E = crf ? emisb : emis;
  const float* __restrict__ T = crf ? transb : trans;
  const int lane = threadIdx.x;
  const int jn = lane >> 2, p = lane & 3;
  const bool jv = (jn < NTc);
  const int jc = jv ? jn : 0;
  float Tc[4];
#pragma unroll
  for (int ii = 0; ii < 4; ++ii) {
    int i = p * 4 + ii;
    Tc[ii] = (jv && i < NTc) ? T[i * NTc + jn] : -1e30f;
  }
  __shared__ float as_[2][16];
  if (lane < 16) { as_[0][lane] = -1e30f; as_[1][lane] = -1e30f; }
  WAVE_SYNC();
  float alpha = 0.f;
  if (jv && p == 0) {
    alpha = T[1 * NTc + jn] + E[(size_t)(b << 10) * NTc + jn];  // SOS=1, t=0
    as_[0][jn] = alpha;
  }
  WAVE_SYNC();
  int cur = 0;
  const size_t ebase = (size_t)(b << 10) * NTc + jc;
  const int mbase = b << 10;
#define LDE(tt) E[ebase + (size_t)(tt)*NTc]
#define LDM(tt) mask[mbase + (tt)]

  auto step = [&](float e_tj, float m_t) {
    float v0 = (jv && (p * 4 + 0) < NTc) ? (as_[cur][p * 4 + 0] + Tc[0]) : -1e30f;
    float v1 = (jv && (p * 4 + 1) < NTc) ? (as_[cur][p * 4 + 1] + Tc[1]) : -1e30f;
    float v2 = (jv && (p * 4 + 2) < NTc) ? (as_[cur][p * 4 + 2] + Tc[2]) : -1e30f;
    float v3 = (jv && (p * 4 + 3) < NTc) ? (as_[cur][p * 4 + 3] + Tc[3]) : -1e30f;
    float mx = fmaxf(fmaxf(v0, v1), fmaxf(v2, v3));
    mx = fmaxf(mx, __shfl_xor(mx, 1, 4));
    mx = fmaxf(mx, __shfl_xor(mx, 2, 4));
    float ss = __expf(v0 - mx) + __expf(v1 - mx) + __expf(v2 - mx) + __expf(v3 - mx);
    ss += __shfl_xor(ss, 1, 4);
    ss += __shfl_xor(ss, 2, 4);
    if (jv && p == 0) {
      float newv = e_tj + mx + __logf(ss);
      alpha = (m_t > 0.5f) ? newv : alpha;
      as_[cur ^ 1][jn] = alpha;
    }
    WAVE_SYNC();
    cur ^= 1;
  };

  float eb[4], mb[4];
#pragma unroll
  for (int k = 0; k < 4; ++k) { eb[k] = LDE(1 + k); mb[k] = LDM(1 + k); }
  for (int t = 1; t <= 1017; t += 4) {
    float en[4], mn[4];
#pragma unroll
    for (int k = 0; k < 4; ++k) {
      int ix = t + 4 + k;
      ix = ix > 1023 ? 1023 : ix;
      en[k] = LDE(ix);
      mn[k] = LDM(ix);
    }
    step(eb[0], mb[0]); step(eb[1], mb[1]); step(eb[2], mb[2]); step(eb[3], mb[3]);
#pragma unroll
    for (int k = 0; k < 4; ++k) { eb[k] = en[k]; mb[k] = mn[k]; }
  }
  step(eb[0], mb[0]); step(eb[1], mb[1]); step(eb[2], mb[2]);
#undef LDE
#undef LDM

  if (lane == 0) {
    float mx = -1e30f;
    for (int jjx = 0; jjx < NTc; ++jjx) mx = fmaxf(mx, as_[cur][jjx] + T[jjx * NTc + 2]);
    float ss = 0.f;
    for (int jjx = 0; jjx < NTc; ++jjx) ss += __expf(as_[cur][jjx] + T[jjx * NTc + 2] - mx);
    outLogZ[crf * 32 + b] = mx + __logf(ss);
  }
}

// ---------------- CRF gold score ----------------
__global__ __launch_bounds__(64) void crf_score(const float* __restrict__ emis,
                                                const float* __restrict__ trans,
                                                const float* __restrict__ emisb,
                                                const float* __restrict__ transb,
                                                const float* __restrict__ mask,
                                                const int* __restrict__ tags,
                                                const int* __restrict__ tagsb,
                                                float* __restrict__ outScore) {
  const int crf = blockIdx.x >> 5, b = blockIdx.x & 31;
  const int NTc = crf ? 5 : 16;
  const float* __restrict__ E = crf ? emisb : emis;
  const float* __restrict__ T = crf ? transb : trans;
  const int* __restrict__ tg = (crf ? tagsb : tags) + (b << 10);
  const float* __restrict__ mk = mask + (b << 10);
  const int lane = threadIdx.x;
  float s = 0.f, cnt = 0.f;
  for (int t = lane; t < S_LEN; t += 64) {
    float m = mk[t];
    cnt += m;
    if (t >= 1 && m > 0.5f)
      s += E[((size_t)(b << 10) + t) * NTc + tg[t]] + T[tg[t - 1] * NTc + tg[t]];
  }
#pragma unroll
  for (int off = 32; off >= 1; off >>= 1) {
    s += __shfl_down(s, off);
    cnt += __shfl_down(cnt, off);
  }
  if (lane == 0) {
    int L = (int)(cnt + 0.5f);
    int t0 = tg[0];
    float tot = T[1 * NTc + t0] + E[(size_t)(b << 10) * NTc + t0] + s + T[tg[L - 1] * NTc + 2];
    outScore[crf * 32 + b] = tot;
  }
}

__global__ void finalk(const float* __restrict__ logZ, const float* __restrict__ score,
                       float* __restrict__ out) {
  int j = threadIdx.x;
  if (j < 2) {
    float a = 0.f;
    for (int b = 0; b < 32; ++b) a += logZ[j * 32 + b] - score[j * 32 + b];
    out[j] = a;
  }
}

extern "C" void kernel_launch(void* const* d_in, const int* in_sizes, int n_in,
                              void* d_out, int out_size, void* d_ws, size_t ws_size,
                              hipStream_t stream) {
  const float* x       = (const float*)d_in[0];
  const float* xbin    = (const float*)d_in[1];
  const float* mask    = (const float*)d_in[2];
  const int*   tags    = (const int*)d_in[3];
  const int*   tagsb   = (const int*)d_in[4];
  const float* trans   = (const float*)d_in[5];
  const float* transb  = (const float*)d_in[6];
  const float* w2f_ih  = (const float*)d_in[7];
  const float* w2f_hh  = (const float*)d_in[8];
  const float* b2f_ih  = (const float*)d_in[9];
  const float* b2f_hh  = (const float*)d_in[10];
  const float* w2b_ih  = (const float*)d_in[11];
  const float* w2b_hh  = (const float*)d_in[12];
  const float* b2b_ih  = (const float*)d_in[13];
  const float* b2b_hh  = (const float*)d_in[14];
  const float* w_bin   = (const float*)d_in[15];
  const float* bb_bin  = (const float*)d_in[16];
  const float* w1f_ih  = (const float*)d_in[17];
  const float* w1f_hh  = (const float*)d_in[18];
  const float* b1f_ih  = (const float*)d_in[19];
  const float* b1f_hh  = (const float*)d_in[20];
  const float* w1b_ih  = (const float*)d_in[21];
  const float* w1b_hh  = (const float*)d_in[22];
  const float* b1b_ih  = (const float*)d_in[23];
  const float* b1b_hh  = (const float*)d_in[24];
  const float* w_tag   = (const float*)d_in[25];
  const float* b_tag   = (const float*)d_in[26];
  const float* h0_bin  = (const float*)d_in[27];
  const float* c0_bin  = (const float*)d_in[28];
  const float* h0_main = (const float*)d_in[29];
  const float* c0_main = (const float*)d_in[30];

  char* ws = (char*)d_ws;
  char* P4    = ws;                                   // 4u x 64MiB = 256MiB
  f16* hid4   = (f16*)(ws + 268435456);               // 64MiB
  char* Wq4   = ws + 335544320;                       // 1MiB
  float* fsc4 = (float*)(ws + 336592896);             // 16KB
  f16* wtag   = (f16*)(ws + 336609280);
  f16* wbin   = (f16*)(ws + 336642048);
  float* emis  = (float*)(ws + 336647168);            // 2MiB
  float* emisb = (float*)(ws + 338744320);
  float* logZ  = (float*)(ws + 339399680);
  float* score = (float*)(ws + 339399936);
  float* bsum  = (float*)(ws + 339400704);            // 16KB
  f16* w16all  = (f16*)(ws + 340000768);              // 8MiB, ends 348389376

  // weight preps
  quant_whh<<<256, 256, 0, stream>>>(w1f_hh, Wq4 + 0 * 262144, fsc4 + 0 * 1024);
  quant_whh<<<256, 256, 0, stream>>>(w1b_hh, Wq4 + 1 * 262144, fsc4 + 1 * 1024);
  quant_whh<<<256, 256, 0, stream>>>(w2f_hh, Wq4 + 2 * 262144, fsc4 + 2 * 1024);
  quant_whh<<<256, 256, 0, stream>>>(w2b_hh, Wq4 + 3 * 262144, fsc4 + 3 * 1024);
  cvt_f32_f16<<<16, 256, 0, stream>>>(w_tag, wtag, 4096);
  cvt_f32_f16<<<3, 256, 0, stream>>>(w_bin, wbin, 640);
  cvt_wih<<<256, 256, 0, stream>>>(w1f_ih, w16all + 0, 512, 65536);
  cvt_wih<<<256, 256, 0, stream>>>(w1b_ih, w16all + 524288, 512, 65536);
  cvt_wih<<<768, 256, 0, stream>>>(w2f_ih, w16all + 1048576, 1536, 196608);
  cvt_wih<<<768, 256, 0, stream>>>(w2b_ih, w16all + 2621440, 1536, 196608);
  bias_pack<<<16, 256, 0, stream>>>(b1f_ih, b1f_hh, b1b_ih, b1b_hh,
                                    b2f_ih, b2f_hh, b2b_ih, b2b_hh, bsum);

  // fused input projections: 1D grid, XCD-grouped, pipelined dbuf
  proj_gemm<<<4096, 256, 0, stream>>>(x, xbin, w16all, bsum, P4);

  lstm_rec5<<<64, 512, 0, stream>>>(Wq4, fsc4, P4, h0_main, c0_main, h0_bin, c0_bin, hid4);
  emis_kernel<<<2048, 256, 0, stream>>>(hid4, wtag, b_tag, wbin, bb_bin, emis, emisb);
  crf_logz<<<64, 64, 0, stream>>>(emis, trans, emisb, transb, mask, logZ);
  crf_score<<<64, 64, 0, stream>>>(emis, trans, emisb, transb, mask, tags, tagsb, score);
  finalk<<<1, 64, 0, stream>>>(logZ, score, (float*)d_out);
}

// Round 14
// 1777.546 us; speedup vs baseline: 2.4641x; 1.1019x over previous
//
#include <hip/hip_runtime.h>

typedef _Float16 f16;
typedef _Float16 f16x2 __attribute__((ext_vector_type(2)));
typedef _Float16 f16x4 __attribute__((ext_vector_type(4)));
typedef _Float16 f16x8 __attribute__((ext_vector_type(8)));
typedef float f32x4 __attribute__((ext_vector_type(4)));
typedef int iv4 __attribute__((ext_vector_type(4)));

#define S_LEN 1024
#define BATCH 32
#define HID 256
#define L2E 1.4426950408889634f
#define L2E2 2.8853900817779268f

#if __has_builtin(__builtin_amdgcn_fdot2)
#define FDOT2(a, b, c) __builtin_amdgcn_fdot2((a), (b), (c), false)
#else
static __device__ __forceinline__ float FDOT2(f16x2 a, f16x2 b, float c) {
  return c + (float)a[0] * (float)b[0] + (float)a[1] * (float)b[1];
}
#endif

__device__ __forceinline__ float EXP2(float x) {
#if __has_builtin(__builtin_amdgcn_exp2f)
  return __builtin_amdgcn_exp2f(x);
#else
  return exp2f(x);
#endif
}
__device__ __forceinline__ float RCP(float x) {
#if __has_builtin(__builtin_amdgcn_rcpf)
  return __builtin_amdgcn_rcpf(x);
#else
  return 1.0f / x;
#endif
}

__device__ __forceinline__ iv4 cvt8(float4 a, float4 b) {
#if __has_builtin(__builtin_amdgcn_cvt_pkrtz)
  auto p0 = __builtin_amdgcn_cvt_pkrtz(a.x, a.y);
  auto p1 = __builtin_amdgcn_cvt_pkrtz(a.z, a.w);
  auto p2 = __builtin_amdgcn_cvt_pkrtz(b.x, b.y);
  auto p3 = __builtin_amdgcn_cvt_pkrtz(b.z, b.w);
  iv4 o;
  o[0] = __builtin_bit_cast(int, p0);
  o[1] = __builtin_bit_cast(int, p1);
  o[2] = __builtin_bit_cast(int, p2);
  o[3] = __builtin_bit_cast(int, p3);
  return o;
#else
  f16x8 h;
  h[0] = (f16)a.x; h[1] = (f16)a.y; h[2] = (f16)a.z; h[3] = (f16)a.w;
  h[4] = (f16)b.x; h[5] = (f16)b.y; h[6] = (f16)b.z; h[7] = (f16)b.w;
  return __builtin_bit_cast(iv4, h);
#endif
}

#if __has_builtin(__builtin_amdgcn_global_load_lds)
__device__ __forceinline__ void gload16(const void* g, void* l) {
  __builtin_amdgcn_global_load_lds((const __attribute__((address_space(1))) void*)g,
                                   (__attribute__((address_space(3))) void*)l, 16, 0, 0);
}
#else
__device__ __forceinline__ void gload16(const void* g, void* l) {
  int lane = __builtin_amdgcn_mbcnt_hi(~0u, __builtin_amdgcn_mbcnt_lo(~0u, 0));
  ((f16x8*)l)[lane] = *(const f16x8*)g;  // emulate base + lane*16
}
#endif

// barrier that waits LDS only (no vmcnt drain)
#define WG_BARRIER()                                                  \
  do {                                                                \
    __builtin_amdgcn_sched_barrier(0);                                \
    asm volatile("s_waitcnt lgkmcnt(0)\n\ts_barrier" ::: "memory");   \
    __builtin_amdgcn_sched_barrier(0);                                \
  } while (0)

__device__ __forceinline__ float dot8(f16x8 w, f16x8 h, float acc) {
  f16x2 a, b;
  a[0] = w[0]; a[1] = w[1]; b[0] = h[0]; b[1] = h[1]; acc = FDOT2(a, b, acc);
  a[0] = w[2]; a[1] = w[3]; b[0] = h[2]; b[1] = h[3]; acc = FDOT2(a, b, acc);
  a[0] = w[4]; a[1] = w[5]; b[0] = h[4]; b[1] = h[5]; acc = FDOT2(a, b, acc);
  a[0] = w[6]; a[1] = w[7]; b[0] = h[6]; b[1] = h[7]; acc = FDOT2(a, b, acc);
  return acc;
}

// ---------------- fused weight-prep kernel ----------------
// blocks [0,1024): quant_whh x4 ; [1024,1040): wtag ; [1040,1043): wbin ;
// [1043,3091): cvt_wih x4 ; [3091,3107): bias_pack
__global__ __launch_bounds__(256) void prep_all(
    const float* __restrict__ w1f_hh, const float* __restrict__ w1b_hh,
    const float* __restrict__ w2f_hh, const float* __restrict__ w2b_hh,
    char* __restrict__ Wq4, float* __restrict__ fsc4,
    const float* __restrict__ w_tag, f16* __restrict__ wtag,
    const float* __restrict__ w_bin, f16* __restrict__ wbin,
    const float* __restrict__ w1f_ih, const float* __restrict__ w1b_ih,
    const float* __restrict__ w2f_ih, const float* __restrict__ w2b_ih,
    f16* __restrict__ w16all,
    const float* __restrict__ b1f_ih, const float* __restrict__ b1f_hh,
    const float* __restrict__ b1b_ih, const float* __restrict__ b1b_hh,
    const float* __restrict__ b2f_ih, const float* __restrict__ b2f_hh,
    const float* __restrict__ b2b_ih, const float* __restrict__ b2b_hh,
    float* __restrict__ bsum) {
  const int blk = blockIdx.x;
  const int tid = threadIdx.x;
  if (blk < 1024) {
    // quant_whh: unit = blk>>8, local block = blk&255
    const int u = blk >> 8, sb = blk & 255;
    const float* src = u == 0 ? w1f_hh : u == 1 ? w1b_hh : u == 2 ? w2f_hh : w2b_hh;
    char* dstq = Wq4 + (size_t)u * 262144;
    float* fsc = fsc4 + u * 1024;
    const int row = sb * 4 + (tid >> 6);
    const int lane = tid & 63;
    const float sc = (row >= 512 && row < 768) ? L2E2 : L2E;
    float4 v = *(const float4*)(src + (size_t)row * 256 + lane * 4);
    float w0 = v.x * sc, w1 = v.y * sc, w2 = v.z * sc, w3 = v.w * sc;
    float mx = fmaxf(fmaxf(fabsf(w0), fabsf(w1)), fmaxf(fabsf(w2), fabsf(w3)));
#pragma unroll
    for (int off = 1; off < 64; off <<= 1) mx = fmaxf(mx, __shfl_xor(mx, off));
    mx = fmaxf(mx, 1e-20f);
    float inv = 127.0f / mx;
    int q0 = (int)rintf(w0 * inv), q1 = (int)rintf(w1 * inv);
    int q2 = (int)rintf(w2 * inv), q3 = (int)rintf(w3 * inv);
    int pk = (q0 & 0xff) | ((q1 & 0xff) << 8) | ((q2 & 0xff) << 16) | ((q3 & 0xff) << 24);
    ((int*)(dstq + (size_t)row * 256))[lane] = pk;
    if (lane == 0) fsc[row] = mx / 16129.0f;
  } else if (blk < 1040) {
    int i = (blk - 1024) * 256 + tid;
    if (i < 4096) {
      float4 v = ((const float4*)w_tag)[i];
      f16x4 h;
      h[0] = (f16)v.x; h[1] = (f16)v.y; h[2] = (f16)v.z; h[3] = (f16)v.w;
      ((f16x4*)wtag)[i] = h;
    }
  } else if (blk < 1043) {
    int i = (blk - 1040) * 256 + tid;
    if (i < 640) {
      float4 v = ((const float4*)w_bin)[i];
      f16x4 h;
      h[0] = (f16)v.x; h[1] = (f16)v.y; h[2] = (f16)v.z; h[3] = (f16)v.w;
      ((f16x4*)wbin)[i] = h;
    }
  } else if (blk < 3091) {
    int rel = blk - 1043;
    const float* src;
    f16* dst;
    int K, total8;
    if (rel < 256) { src = w1f_ih; dst = w16all; K = 512; total8 = 65536; }
    else if (rel < 512) { src = w1b_ih; dst = w16all + 524288; K = 512; total8 = 65536; rel -= 256; }
    else if (rel < 1280) { src = w2f_ih; dst = w16all + 1048576; K = 1536; total8 = 196608; rel -= 512; }
    else { src = w2b_ih; dst = w16all + 2621440; K = 1536; total8 = 196608; rel -= 1280; }
    int i = rel * 256 + tid;
    if (i < total8) {
      int row = (int)(((long long)i * 8) / K);
      float sc = (row >= 512 && row < 768) ? L2E2 : L2E;
      const float* s = src + (size_t)i * 8;
      float4 a = *(const float4*)s;
      float4 b = *(const float4*)(s + 4);
      f16x8 h;
      h[0] = (f16)(a.x * sc); h[1] = (f16)(a.y * sc); h[2] = (f16)(a.z * sc); h[3] = (f16)(a.w * sc);
      h[4] = (f16)(b.x * sc); h[5] = (f16)(b.y * sc); h[6] = (f16)(b.z * sc); h[7] = (f16)(b.w * sc);
      *(f16x8*)(dst + (size_t)i * 8) = h;
    }
  } else {
    int i = (blk - 3091) * 256 + tid;
    if (i < 4096) {
      int u = i >> 10, n = i & 1023;
      float sc = (n >= 512 && n < 768) ? L2E2 : L2E;
      const float* pa = u == 0 ? b1f_ih : u == 1 ? b1b_ih : u == 2 ? b2f_ih : b2b_ih;
      const float* ph = u == 0 ? b1f_hh : u == 1 ? b1b_hh : u == 2 ? b2f_hh : b2b_hh;
      bsum[i] = (pa[n] + ph[n]) * sc;
    }
  }
}

// ---------------- fused input-projection GEMM -> P4 planes (round-13 structure) ----------------
__global__ __launch_bounds__(256) void proj_gemm(const float* __restrict__ x,
                                                 const float* __restrict__ xbin,
                                                 const f16* __restrict__ w16all,
                                                 const float* __restrict__ bsum,
                                                 char* __restrict__ P4) {
  __shared__ __align__(16) char smem[98304];  // A0 A1 B0 B1
  const int L = blockIdx.x;
  const int q = L >> 5, r = L & 31;
  const int v = r >> 3;
  const int ub = q * 8 + (r & 7);
  const int unit = ub >> 8;
  const int bm = ub & 255;
  const int K = (unit < 2) ? 512 : 1536;
  const float* Aptr = (unit < 2) ? x : xbin;
  const size_t woff = (unit == 0) ? 0u : (unit == 1) ? 524288u : (unit == 2) ? 1048576u : 2621440u;
  const f16* W16 = w16all + woff;
  const int bgrp = bm >> 5, t0 = (bm & 31) * 32;
  const int b0 = bgrp * 4, c = bgrp >> 1, lkb = bgrp & 1;
  const int tid = threadIdx.x;
  const int lane = tid & 63, wid = tid >> 6;
  const int wm = wid >> 1, wn = wid & 1;
  const int lr = lane & 15, lk = lane >> 4;
  const int xsw = (lr & 7) << 4;

  f32x4 acc[4][8];
#pragma unroll
  for (int i = 0; i < 4; ++i)
#pragma unroll
    for (int n = 0; n < 8; ++n) acc[i][n] = (f32x4){0.f, 0.f, 0.f, 0.f};

#define PROJ_PREFETCH(KN_, AO_, BO_)                                                        \
  if ((KN_) < K) {                                                                          \
    float4 ar0[4], ar1[4];                                                                  \
    _Pragma("unroll") for (int s = 0; s < 4; ++s) {                                         \
      int slot = s * 256 + tid;                                                             \
      int row = slot >> 3, seg = slot & 7;                                                  \
      size_t arow = (size_t)(b0 + (row >> 5)) * 1024 + t0 + (row & 31);                     \
      const float* ga = Aptr + arow * K + (KN_) + seg * 8;                                  \
      ar0[s] = *(const float4*)ga;                                                          \
      ar1[s] = *(const float4*)(ga + 4);                                                    \
    }                                                                                       \
    __builtin_amdgcn_sched_barrier(0);                                                      \
    _Pragma("unroll") for (int i = 0; i < 8; ++i) {                                         \
      int g = (wid * 8 + i) * 64 + lane;                                                    \
      int brow = g >> 3, cg = g & 7;                                                        \
      const f16* bsrc = W16 + (size_t)(v * 256 + brow) * K + (KN_) + ((cg ^ (brow & 7)) << 3); \
      gload16(bsrc, smem + (BO_) + (wid * 8 + i) * 1024);                                   \
    }                                                                                       \
    __builtin_amdgcn_sched_barrier(0);                                                      \
    _Pragma("unroll") for (int s = 0; s < 4; ++s) {                                         \
      int slot = s * 256 + tid;                                                             \
      int row = slot >> 3, seg = slot & 7;                                                  \
      *(iv4*)(smem + (AO_) + row * 128 + ((seg ^ (row & 7)) << 4)) = cvt8(ar0[s], ar1[s]);  \
    }                                                                                       \
    __builtin_amdgcn_sched_barrier(0);                                                      \
  } else {                                                                                  \
    __builtin_amdgcn_sched_barrier(0);                                                      \
    asm volatile("s_waitcnt vmcnt(0)" ::: "memory");                                        \
    __builtin_amdgcn_sched_barrier(0);                                                      \
  }

#define PROJ_COMPUTE(AO_, BO_)                                                              \
  _Pragma("unroll") for (int kk = 0; kk < 2; ++kk) {                                        \
    f16x8 af[4], bf[8];                                                                     \
    _Pragma("unroll") for (int mi = 0; mi < 4; ++mi) {                                      \
      int ba = (wm * 64 + mi * 16 + lr) * 128 + kk * 64 + lk * 16;                          \
      af[mi] = *(const f16x8*)(smem + (AO_) + (ba ^ xsw));                                  \
    }                                                                                       \
    _Pragma("unroll") for (int ni = 0; ni < 8; ++ni) {                                      \
      int bb = (wn * 128 + ni * 16 + lr) * 128 + kk * 64 + lk * 16;                         \
      bf[ni] = *(const f16x8*)(smem + (BO_) + (bb ^ xsw));                                  \
    }                                                                                       \
    _Pragma("unroll") for (int mi = 0; mi < 4; ++mi)                                        \
      _Pragma("unroll") for (int ni = 0; ni < 8; ++ni)                                      \
        acc[mi][ni] = __builtin_amdgcn_mfma_f32_16x16x32_f16(af[mi], bf[ni], acc[mi][ni], 0, 0, 0); \
  }

  PROJ_PREFETCH(0, 0, 32768);
  for (int k0 = 0; k0 < K; k0 += 128) {
    PROJ_PREFETCH(k0 + 64, 16384, 65536);
    WG_BARRIER();
    PROJ_COMPUTE(0, 32768);
    WG_BARRIER();
    PROJ_PREFETCH(k0 + 128, 0, 32768);
    WG_BARRIER();
    PROJ_COMPUTE(16384, 65536);
    WG_BARRIER();
  }
#undef PROJ_PREFETCH
#undef PROJ_COMPUTE

  // epilogue: two passes, 32KB LDS each
  float biasv[8];
#pragma unroll
  for (int ni = 0; ni < 8; ++ni)
    biasv[ni] = bsum[unit * 1024 + v * 256 + wn * 128 + ni * 16 + lr];
  char* Pv = P4 + ((size_t)unit << 26) + ((size_t)v << 24);
#pragma unroll
  for (int pass = 0; pass < 2; ++pass) {
    __syncthreads();
#pragma unroll
    for (int mi2 = 0; mi2 < 2; ++mi2) {
      int mi = mi2 * 2 + pass;
#pragma unroll
      for (int ni = 0; ni < 8; ++ni) {
        int col = wn * 128 + ni * 16 + lr;
        int wc = col >> 5, jc = (col >> 4) & 1, lc = col & 15;
#pragma unroll
        for (int rr = 0; rr < 4; ++rr) {
          int row = wm * 64 + mi * 16 + lk * 4 + rr;
          int bsub = row >> 5, tl = row & 15;
          int unit2 = tl * 256 + wc * 32 + jc * 16 + lc;
          int off = (unit2 * 8 + bsub * 2) ^ ((tl & 7) << 4);
          *(f16*)(smem + off) = (f16)(acc[mi][ni][rr] + biasv[ni]);
        }
      }
    }
    __syncthreads();
#pragma unroll
    for (int k = 0; k < 16; ++k) {
      int uid = k * 256 + tid;
      int tl = uid >> 8, sub = uid & 255;
      int off = (uid * 8) ^ ((tl & 7) << 4);
      unsigned long long val = *(const unsigned long long*)(smem + off);
      int t_loc = pass * 16 + tl;
      int wq = sub >> 5, jq = (sub >> 4) & 1, lq = sub & 15;
      size_t didx =
          (((size_t)((t0 + t_loc) * 4 + c) * 512) + wq * 64 + jq * 32 + lkb * 16 + lq) << 3;
      *(unsigned long long*)(Pv + didx) = val;
    }
  }
}

// ---------------- LSTM recurrence (round-13 proven, unchanged) ----------------
__global__ __attribute__((amdgpu_flat_work_group_size(512, 512), amdgpu_waves_per_eu(2, 2)))
void lstm_rec5(const char* __restrict__ Wq4,
               const float* __restrict__ fsc4,
               const char* __restrict__ P4,
               const float* __restrict__ h0m,
               const float* __restrict__ c0m,
               const float* __restrict__ h0b,
               const float* __restrict__ c0b,
               f16* __restrict__ hid4) {
  const int wg = blockIdx.x;
  const int u = wg >> 4, c16 = wg & 15;
  const int dir = u & 1;
  const int tid = threadIdx.x;
  const int l = tid & 63, w = tid >> 6;
  const int lr = l & 15, lk = l >> 4;
  const int jj = lk >> 1, selb = lk & 1;
  const int r2 = lr & 1;
  const int swzA = r2 ? 80 : 0;
  const int swzW = selb ? 80 : 0;
  const int j = w * 32 + jj * 16 + lr;

  __shared__ __align__(16) char hbuf[2][512];

  iv4 Bf[4][8];
  const char* wb = Wq4 + ((size_t)u << 18);
#pragma unroll
  for (int nt = 0; nt < 8; ++nt) {
    int n = (nt >> 1) * 256 + w * 32 + ((nt & 1) << 4) + lr;
#pragma unroll
    for (int ks = 0; ks < 4; ++ks)
      Bf[ks][nt] = *(const iv4*)(wb + (size_t)n * 256 + ks * 64 + lk * 16);
  }
  float fv[4], fv4[4];
#pragma unroll
  for (int v = 0; v < 4; ++v) {
    fv[v] = fsc4[u * 1024 + v * 256 + j];
    fv4[v] = fv[v] * 4.f;
  }

  const int b = c16 * 2 + selb;
  const float* h0 = (u < 2 ? h0m : h0b) + (size_t)dir * BATCH * HID;
  const float* c0 = (u < 2 ? c0m : c0b) + (size_t)dir * BATCH * HID;
  float cst = c0[b * HID + j];
  {
    float hv = h0[b * HID + j] * 31.75f;
    int hq = (int)rintf(hv);
    hq = hq > 127 ? 127 : (hq < -127 ? -127 : hq);
    hbuf[0][selb * 256 + (j ^ swzW)] = (char)hq;
  }

  const char* Pc = P4 + ((size_t)u << 26);
  const size_t soff =
      (size_t)((w * 64 + jj * 32 + (((c16 >> 1) & 1) << 4) + lr) * 8 + (c16 & 1) * 4);
  const int cq = c16 >> 2;
  f16x2 Pa[4], Pb[4];
  {
    int t0 = dir ? (S_LEN - 1) : 0;
    size_t tb = ((size_t)((t0 << 2) + cq) << 12) + soff;
#pragma unroll
    for (int v = 0; v < 4; ++v) Pa[v] = *(const f16x2*)(Pc + ((size_t)v << 24) + tb);
  }
  WG_BARRIER();

#define LSTM_STEP(S_, SP_, PC_, PN_, FV_)                                                   \
  {                                                                                         \
    const int t = dir ? (S_LEN - 1 - (S_)) : (S_);                                          \
    {                                                                                       \
      int s2 = ((S_) + 1 < S_LEN) ? (S_) + 1 : (S_);                                        \
      int t2 = dir ? (S_LEN - 1 - s2) : s2;                                                 \
      size_t tb = ((size_t)((t2 << 2) + cq) << 12) + soff;                                  \
      _Pragma("unroll") for (int v = 0; v < 4; ++v)                                         \
          PN_[v] = *(const f16x2*)(Pc + ((size_t)v << 24) + tb);                            \
    }                                                                                       \
    iv4 ia[8];                                                                              \
    _Pragma("unroll") for (int nt = 0; nt < 8; ++nt) ia[nt] = (iv4){0, 0, 0, 0};            \
    const char* hb = hbuf[SP_];                                                             \
    _Pragma("unroll") for (int ks = 0; ks < 4; ++ks) {                                      \
      iv4 Af = *(const iv4*)(hb + r2 * 256 + ((ks * 64 + lk * 16) ^ swzA));                 \
      _Pragma("unroll") for (int nt = 0; nt < 8; ++nt)                                      \
          ia[nt] = __builtin_amdgcn_mfma_i32_16x16x64_i8(Af, Bf[ks][nt], ia[nt], 0, 0, 0);  \
    }                                                                                       \
    float z[4];                                                                             \
    _Pragma("unroll") for (int v = 0; v < 4; ++v) {                                         \
      int e0 = selb ? ia[v * 2][1] : ia[v * 2][0];                                          \
      int e1 = selb ? ia[v * 2 + 1][1] : ia[v * 2 + 1][0];                                  \
      int iz = jj ? e1 : e0;                                                                \
      float pv = selb ? (float)PC_[v][1] : (float)PC_[v][0];                                \
      z[v] = pv + FV_[v] * (float)iz;                                                       \
    }                                                                                       \
    float zi = z[0], zf = z[1], zg = z[2], zo = z[3];                                       \
    float ei = EXP2(-zi), ef = EXP2(-zf), eg = EXP2(-zg), eo = EXP2(-zo);                   \
    float di = 1.f + ei, df = 1.f + ef, dg = 1.f + eg, dof = 1.f + eo;                      \
    float r1 = RCP(di * df);                                                                \
    float si = r1 * df, sf = r1 * di;                                                       \
    float r2x = RCP(dg * dof);                                                              \
    float tg = 2.f * (r2x * dof) - 1.f, so = r2x * dg;                                      \
    float cc = sf * cst + si * tg;                                                          \
    cst = cc;                                                                               \
    float ec = EXP2(-L2E2 * cc);                                                            \
    float th = 2.f * RCP(1.f + ec) - 1.f;                                                   \
    float hh = so * th;                                                                     \
    int hq = (int)rintf(hh * 127.f);                                                        \
    hbuf[SP_ ^ 1][selb * 256 + (j ^ swzW)] = (char)hq;                                      \
    hid4[((size_t)b << 20) + ((size_t)t << 10) + (u << 8) + j] = (f16)hh;                   \
    WG_BARRIER();                                                                           \
  }

  LSTM_STEP(0, 0, Pa, Pb, fv4);
  for (int s = 1; s <= 1021; s += 2) {
    LSTM_STEP(s, 1, Pb, Pa, fv);
    LSTM_STEP(s + 1, 0, Pa, Pb, fv);
  }
  LSTM_STEP(1023, 1, Pb, Pa, fv);
#undef LSTM_STEP
}

// ---------------- emissions (unchanged) ----------------
__global__ __launch_bounds__(256) void emis_kernel(const f16* __restrict__ hid4,
                                                   const f16* __restrict__ wtag,
                                                   const float* __restrict__ btag,
                                                   const f16* __restrict__ wbin,
                                                   const float* __restrict__ bbin,
                                                   float* __restrict__ emis,
                                                   float* __restrict__ emisb) {
  const int tid = threadIdx.x;
  const int rl = tid >> 4, n = tid & 15;
  const size_t row = (size_t)blockIdx.x * 16 + rl;
  const f16x8* hv = (const f16x8*)(hid4 + row * 1024);
  const f16x8* wv = (const f16x8*)(wtag + n * 1024);
  float acc = btag[n];
#pragma unroll 8
  for (int kc = 0; kc < 128; ++kc) acc = dot8(wv[kc], hv[kc], acc);
  emis[row * 16 + n] = acc;
  if (n < 5) {
    const f16x8* hv2 = (const f16x8*)(hid4 + row * 1024 + 512);
    const f16x8* wv2 = (const f16x8*)(wbin + (size_t)n * 512);
    float a2 = bbin[n];
#pragma unroll 8
    for (int kc = 0; kc < 64; ++kc) a2 = dot8(wv2[kc], hv2[kc], a2);
    emisb[row * 5 + n] = a2;
  }
}

// ---------------- fused CRF: blocks 0-63 logZ (register alpha), 64-127 gold score ----------------
__global__ __launch_bounds__(64) void crf_fused(const float* __restrict__ emis,
                                                const float* __restrict__ trans,
                                                const float* __restrict__ emisb,
                                                const float* __restrict__ transb,
                                                const float* __restrict__ mask,
                                                const int* __restrict__ tags,
                                                const int* __restrict__ tagsb,
                                                float* __restrict__ outLogZ,
                                                float* __restrict__ outScore) {
  const int lane = threadIdx.x;
  if (blockIdx.x < 64) {
    // ---- logZ, alpha in registers: lane (i*4+p) holds alpha(tag i) ----
    const int crf = blockIdx.x >> 5, b = blockIdx.x & 31;
    const int NTc = crf ? 5 : 16;
    const float* __restrict__ E = crf ? emisb : emis;
    const float* __restrict__ T = crf ? transb : trans;
    const int jn = lane >> 2, p = lane & 3;
    const bool jv = (jn < NTc);
    const int jc = jv ? jn : 0;
    float Tc[4];
#pragma unroll
    for (int ii = 0; ii < 4; ++ii) {
      int i = p * 4 + ii;
      Tc[ii] = (jv && i < NTc) ? T[i * NTc + jn] : -1e30f;
    }
    float alpha = jv ? (T[1 * NTc + jc] + E[(size_t)(b << 10) * NTc + jc]) : -1e30f;
    const size_t ebase = (size_t)(b << 10) * NTc + jc;
    const int mbase = b << 10;
#define LDE(tt) E[ebase + (size_t)(tt)*NTc]
#define LDM(tt) mask[mbase + (tt)]

    auto step = [&](float e_tj, float m_t) {
      float a0 = __shfl(alpha, ((p * 4 + 0) << 2) | p);
      float a1 = __shfl(alpha, ((p * 4 + 1) << 2) | p);
      float a2 = __shfl(alpha, ((p * 4 + 2) << 2) | p);
      float a3 = __shfl(alpha, ((p * 4 + 3) << 2) | p);
      float v0 = a0 + Tc[0], v1 = a1 + Tc[1], v2 = a2 + Tc[2], v3 = a3 + Tc[3];
      float mx = fmaxf(fmaxf(v0, v1), fmaxf(v2, v3));
      mx = fmaxf(mx, __shfl_xor(mx, 1, 4));
      mx = fmaxf(mx, __shfl_xor(mx, 2, 4));
      float ss = __expf(v0 - mx) + __expf(v1 - mx) + __expf(v2 - mx) + __expf(v3 - mx);
      ss += __shfl_xor(ss, 1, 4);
      ss += __shfl_xor(ss, 2, 4);
      float newv = e_tj + mx + __logf(ss);
      alpha = (m_t > 0.5f) ? newv : alpha;
    };

    float eb[4], mb[4];
#pragma unroll
    for (int k = 0; k < 4; ++k) { eb[k] = LDE(1 + k); mb[k] = LDM(1 + k); }
    for (int t = 1; t <= 1017; t += 4) {
      float en[4], mn[4];
#pragma unroll
      for (int k = 0; k < 4; ++k) {
        int ix = t + 4 + k;
        ix = ix > 1023 ? 1023 : ix;
        en[k] = LDE(ix);
        mn[k] = LDM(ix);
      }
      step(eb[0], mb[0]); step(eb[1], mb[1]); step(eb[2], mb[2]); step(eb[3], mb[3]);
#pragma unroll
      for (int k = 0; k < 4; ++k) { eb[k] = en[k]; mb[k] = mn[k]; }
    }
    step(eb[0], mb[0]); step(eb[1], mb[1]); step(eb[2], mb[2]);
#undef LDE
#undef LDM

    // wave-uniform final logsumexp over tags (count each tag once via p==0)
    float fin = (jv && p == 0) ? (alpha + T[jn * NTc + 2]) : -1e30f;
    float mx = fin;
#pragma unroll
    for (int off = 1; off < 64; off <<= 1) mx = fmaxf(mx, __shfl_xor(mx, off));
    float ss = __expf(fin - mx);
#pragma unroll
    for (int off = 1; off < 64; off <<= 1) ss += __shfl_xor(ss, off);
    if (lane == 0) outLogZ[crf * 32 + b] = mx + __logf(ss);
  } else {
    // ---- gold score (unchanged logic) ----
    const int bi = blockIdx.x - 64;
    const int crf = bi >> 5, b = bi & 31;
    const int NTc = crf ? 5 : 16;
    const float* __restrict__ E = crf ? emisb : emis;
    const float* __restrict__ T = crf ? transb : trans;
    const int* __restrict__ tg = (crf ? tagsb : tags) + (b << 10);
    const float* __restrict__ mk = mask + (b << 10);
    float s = 0.f, cnt = 0.f;
    for (int t = lane; t < S_LEN; t += 64) {
      float m = mk[t];
      cnt += m;
      if (t >= 1 && m > 0.5f)
        s += E[((size_t)(b << 10) + t) * NTc + tg[t]] + T[tg[t - 1] * NTc + tg[t]];
    }
#pragma unroll
    for (int off = 32; off >= 1; off >>= 1) {
      s += __shfl_down(s, off);
      cnt += __shfl_down(cnt, off);
    }
    if (lane == 0) {
      int L = (int)(cnt + 0.5f);
      int t0 = tg[0];
      float tot = T[1 * NTc + t0] + E[(size_t)(b << 10) * NTc + t0] + s + T[tg[L - 1] * NTc + 2];
      outScore[crf * 32 + b] = tot;
    }
  }
}

__global__ void finalk(const float* __restrict__ logZ, const float* __restrict__ score,
                       float* __restrict__ out) {
  int j = threadIdx.x;
  if (j < 2) {
    float a = 0.f;
    for (int b = 0; b < 32; ++b) a += logZ[j * 32 + b] - score[j * 32 + b];
    out[j] = a;
  }
}

extern "C" void kernel_launch(void* const* d_in, const int* in_sizes, int n_in,
                              void* d_out, int out_size, void* d_ws, size_t ws_size,
                              hipStream_t stream) {
  const float* x       = (const float*)d_in[0];
  const float* xbin    = (const float*)d_in[1];
  const float* mask    = (const float*)d_in[2];
  const int*   tags    = (const int*)d_in[3];
  const int*   tagsb   = (const int*)d_in[4];
  const float* trans   = (const float*)d_in[5];
  const float* transb  = (const float*)d_in[6];
  const float* w2f_ih  = (const float*)d_in[7];
  const float* w2f_hh  = (const float*)d_in[8];
  const float* b2f_ih  = (const float*)d_in[9];
  const float* b2f_hh  = (const float*)d_in[10];
  const float* w2b_ih  = (const float*)d_in[11];
  const float* w2b_hh  = (const float*)d_in[12];
  const float* b2b_ih  = (const float*)d_in[13];
  const float* b2b_hh  = (const float*)d_in[14];
  const float* w_bin   = (const float*)d_in[15];
  const float* bb_bin  = (const float*)d_in[16];
  const float* w1f_ih  = (const float*)d_in[17];
  const float* w1f_hh  = (const float*)d_in[18];
  const float* b1f_ih  = (const float*)d_in[19];
  const float* b1f_hh  = (const float*)d_in[20];
  const float* w1b_ih  = (const float*)d_in[21];
  const float* w1b_hh  = (const float*)d_in[22];
  const float* b1b_ih  = (const float*)d_in[23];
  const float* b1b_hh  = (const float*)d_in[24];
  const float* w_tag   = (const float*)d_in[25];
  const float* b_tag   = (const float*)d_in[26];
  const float* h0_bin  = (const float*)d_in[27];
  const float* c0_bin  = (const float*)d_in[28];
  const float* h0_main = (const float*)d_in[29];
  const float* c0_main = (const float*)d_in[30];

  char* ws = (char*)d_ws;
  char* P4    = ws;                                   // 256MiB
  f16* hid4   = (f16*)(ws + 268435456);               // 64MiB
  char* Wq4   = ws + 335544320;                       // 1MiB
  float* fsc4 = (float*)(ws + 336592896);             // 16KB
  f16* wtag   = (f16*)(ws + 336609280);
  f16* wbin   = (f16*)(ws + 336642048);
  float* emis  = (float*)(ws + 336647168);            // 2MiB
  float* emisb = (float*)(ws + 338744320);
  float* logZ  = (float*)(ws + 339399680);
  float* score = (float*)(ws + 339399936);
  float* bsum  = (float*)(ws + 339400704);            // 16KB
  f16* w16all  = (f16*)(ws + 340000768);              // 8MiB

  prep_all<<<3107, 256, 0, stream>>>(w1f_hh, w1b_hh, w2f_hh, w2b_hh, Wq4, fsc4,
                                     w_tag, wtag, w_bin, wbin,
                                     w1f_ih, w1b_ih, w2f_ih, w2b_ih, w16all,
                                     b1f_ih, b1f_hh, b1b_ih, b1b_hh,
                                     b2f_ih, b2f_hh, b2b_ih, b2b_hh, bsum);
  proj_gemm<<<4096, 256, 0, stream>>>(x, xbin, w16all, bsum, P4);
  lstm_rec5<<<64, 512, 0, stream>>>(Wq4, fsc4, P4, h0_main, c0_main, h0_bin, c0_bin, hid4);
  emis_kernel<<<2048, 256, 0, stream>>>(hid4, wtag, b_tag, wbin, bb_bin, emis, emisb);
  crf_fused<<<128, 64, 0, stream>>>(emis, trans, emisb, transb, mask, tags, tagsb, logZ, score);
  finalk<<<1, 64, 0, stream>>>(logZ, score, (float*)d_out);
}

// Round 15
// 1604.683 us; speedup vs baseline: 2.7295x; 1.1077x over previous
//
#include <hip/hip_runtime.h>

typedef _Float16 f16;
typedef _Float16 f16x2 __attribute__((ext_vector_type(2)));
typedef _Float16 f16x4 __attribute__((ext_vector_type(4)));
typedef _Float16 f16x8 __attribute__((ext_vector_type(8)));
typedef float f32x4 __attribute__((ext_vector_type(4)));
typedef int iv4 __attribute__((ext_vector_type(4)));

#define S_LEN 1024
#define BATCH 32
#define HID 256
#define L2E 1.4426950408889634f
#define L2E2 2.8853900817779268f

#if __has_builtin(__builtin_amdgcn_fdot2)
#define FDOT2(a, b, c) __builtin_amdgcn_fdot2((a), (b), (c), false)
#else
static __device__ __forceinline__ float FDOT2(f16x2 a, f16x2 b, float c) {
  return c + (float)a[0] * (float)b[0] + (float)a[1] * (float)b[1];
}
#endif

__device__ __forceinline__ float EXP2(float x) {
#if __has_builtin(__builtin_amdgcn_exp2f)
  return __builtin_amdgcn_exp2f(x);
#else
  return exp2f(x);
#endif
}
__device__ __forceinline__ float RCP(float x) {
#if __has_builtin(__builtin_amdgcn_rcpf)
  return __builtin_amdgcn_rcpf(x);
#else
  return 1.0f / x;
#endif
}

__device__ __forceinline__ iv4 cvt8(float4 a, float4 b) {
#if __has_builtin(__builtin_amdgcn_cvt_pkrtz)
  auto p0 = __builtin_amdgcn_cvt_pkrtz(a.x, a.y);
  auto p1 = __builtin_amdgcn_cvt_pkrtz(a.z, a.w);
  auto p2 = __builtin_amdgcn_cvt_pkrtz(b.x, b.y);
  auto p3 = __builtin_amdgcn_cvt_pkrtz(b.z, b.w);
  iv4 o;
  o[0] = __builtin_bit_cast(int, p0);
  o[1] = __builtin_bit_cast(int, p1);
  o[2] = __builtin_bit_cast(int, p2);
  o[3] = __builtin_bit_cast(int, p3);
  return o;
#else
  f16x8 h;
  h[0] = (f16)a.x; h[1] = (f16)a.y; h[2] = (f16)a.z; h[3] = (f16)a.w;
  h[4] = (f16)b.x; h[5] = (f16)b.y; h[6] = (f16)b.z; h[7] = (f16)b.w;
  return __builtin_bit_cast(iv4, h);
#endif
}

#if __has_builtin(__builtin_amdgcn_global_load_lds)
__device__ __forceinline__ void gload16(const void* g, void* l) {
  __builtin_amdgcn_global_load_lds((const __attribute__((address_space(1))) void*)g,
                                   (__attribute__((address_space(3))) void*)l, 16, 0, 0);
}
#else
__device__ __forceinline__ void gload16(const void* g, void* l) {
  int lane = __builtin_amdgcn_mbcnt_hi(~0u, __builtin_amdgcn_mbcnt_lo(~0u, 0));
  ((f16x8*)l)[lane] = *(const f16x8*)g;  // emulate base + lane*16
}
#endif

// barrier that waits LDS only (no vmcnt drain)
#define WG_BARRIER()                                                  \
  do {                                                                \
    __builtin_amdgcn_sched_barrier(0);                                \
    asm volatile("s_waitcnt lgkmcnt(0)\n\ts_barrier" ::: "memory");   \
    __builtin_amdgcn_sched_barrier(0);                                \
  } while (0)

__device__ __forceinline__ float dot8(f16x8 w, f16x8 h, float acc) {
  f16x2 a, b;
  a[0] = w[0]; a[1] = w[1]; b[0] = h[0]; b[1] = h[1]; acc = FDOT2(a, b, acc);
  a[0] = w[2]; a[1] = w[3]; b[0] = h[2]; b[1] = h[3]; acc = FDOT2(a, b, acc);
  a[0] = w[4]; a[1] = w[5]; b[0] = h[4]; b[1] = h[5]; acc = FDOT2(a, b, acc);
  a[0] = w[6]; a[1] = w[7]; b[0] = h[6]; b[1] = h[7]; acc = FDOT2(a, b, acc);
  return acc;
}

// ---------------- fused weight-prep kernel ----------------
__global__ __launch_bounds__(256) void prep_all(
    const float* __restrict__ w1f_hh, const float* __restrict__ w1b_hh,
    const float* __restrict__ w2f_hh, const float* __restrict__ w2b_hh,
    char* __restrict__ Wq4, float* __restrict__ fsc4,
    const float* __restrict__ w_tag, f16* __restrict__ wtag,
    const float* __restrict__ w_bin, f16* __restrict__ wbin,
    const float* __restrict__ w1f_ih, const float* __restrict__ w1b_ih,
    const float* __restrict__ w2f_ih, const float* __restrict__ w2b_ih,
    f16* __restrict__ w16all,
    const float* __restrict__ b1f_ih, const float* __restrict__ b1f_hh,
    const float* __restrict__ b1b_ih, const float* __restrict__ b1b_hh,
    const float* __restrict__ b2f_ih, const float* __restrict__ b2f_hh,
    const float* __restrict__ b2b_ih, const float* __restrict__ b2b_hh,
    float* __restrict__ bsum) {
  const int blk = blockIdx.x;
  const int tid = threadIdx.x;
  if (blk < 1024) {
    const int u = blk >> 8, sb = blk & 255;
    const float* src = u == 0 ? w1f_hh : u == 1 ? w1b_hh : u == 2 ? w2f_hh : w2b_hh;
    char* dstq = Wq4 + (size_t)u * 262144;
    float* fsc = fsc4 + u * 1024;
    const int row = sb * 4 + (tid >> 6);
    const int lane = tid & 63;
    const float sc = (row >= 512 && row < 768) ? L2E2 : L2E;
    float4 v = *(const float4*)(src + (size_t)row * 256 + lane * 4);
    float w0 = v.x * sc, w1 = v.y * sc, w2 = v.z * sc, w3 = v.w * sc;
    float mx = fmaxf(fmaxf(fabsf(w0), fabsf(w1)), fmaxf(fabsf(w2), fabsf(w3)));
#pragma unroll
    for (int off = 1; off < 64; off <<= 1) mx = fmaxf(mx, __shfl_xor(mx, off));
    mx = fmaxf(mx, 1e-20f);
    float inv = 127.0f / mx;
    int q0 = (int)rintf(w0 * inv), q1 = (int)rintf(w1 * inv);
    int q2 = (int)rintf(w2 * inv), q3 = (int)rintf(w3 * inv);
    int pk = (q0 & 0xff) | ((q1 & 0xff) << 8) | ((q2 & 0xff) << 16) | ((q3 & 0xff) << 24);
    ((int*)(dstq + (size_t)row * 256))[lane] = pk;
    if (lane == 0) fsc[row] = mx / 16129.0f;
  } else if (blk < 1040) {
    int i = (blk - 1024) * 256 + tid;
    if (i < 4096) {
      float4 v = ((const float4*)w_tag)[i];
      f16x4 h;
      h[0] = (f16)v.x; h[1] = (f16)v.y; h[2] = (f16)v.z; h[3] = (f16)v.w;
      ((f16x4*)wtag)[i] = h;
    }
  } else if (blk < 1043) {
    int i = (blk - 1040) * 256 + tid;
    if (i < 640) {
      float4 v = ((const float4*)w_bin)[i];
      f16x4 h;
      h[0] = (f16)v.x; h[1] = (f16)v.y; h[2] = (f16)v.z; h[3] = (f16)v.w;
      ((f16x4*)wbin)[i] = h;
    }
  } else if (blk < 3091) {
    int rel = blk - 1043;
    const float* src;
    f16* dst;
    int K, total8;
    if (rel < 256) { src = w1f_ih; dst = w16all; K = 512; total8 = 65536; }
    else if (rel < 512) { src = w1b_ih; dst = w16all + 524288; K = 512; total8 = 65536; rel -= 256; }
    else if (rel < 1280) { src = w2f_ih; dst = w16all + 1048576; K = 1536; total8 = 196608; rel -= 512; }
    else { src = w2b_ih; dst = w16all + 2621440; K = 1536; total8 = 196608; rel -= 1280; }
    int i = rel * 256 + tid;
    if (i < total8) {
      int row = (int)(((long long)i * 8) / K);
      float sc = (row >= 512 && row < 768) ? L2E2 : L2E;
      const float* s = src + (size_t)i * 8;
      float4 a = *(const float4*)s;
      float4 b = *(const float4*)(s + 4);
      f16x8 h;
      h[0] = (f16)(a.x * sc); h[1] = (f16)(a.y * sc); h[2] = (f16)(a.z * sc); h[3] = (f16)(a.w * sc);
      h[4] = (f16)(b.x * sc); h[5] = (f16)(b.y * sc); h[6] = (f16)(b.z * sc); h[7] = (f16)(b.w * sc);
      *(f16x8*)(dst + (size_t)i * 8) = h;
    }
  } else {
    int i = (blk - 3091) * 256 + tid;
    if (i < 4096) {
      int u = i >> 10, n = i & 1023;
      float sc = (n >= 512 && n < 768) ? L2E2 : L2E;
      const float* pa = u == 0 ? b1f_ih : u == 1 ? b1b_ih : u == 2 ? b2f_ih : b2b_ih;
      const float* ph = u == 0 ? b1f_hh : u == 1 ? b1b_hh : u == 2 ? b2f_hh : b2b_hh;
      bsum[i] = (pa[n] + ph[n]) * sc;
    }
  }
}

// ---------------- fused input-projection GEMM -> P4 planes (round-13/14 proven) ----------------
__global__ __launch_bounds__(256) void proj_gemm(const float* __restrict__ x,
                                                 const float* __restrict__ xbin,
                                                 const f16* __restrict__ w16all,
                                                 const float* __restrict__ bsum,
                                                 char* __restrict__ P4) {
  __shared__ __align__(16) char smem[98304];  // A0 A1 B0 B1
  const int L = blockIdx.x;
  const int q = L >> 5, r = L & 31;
  const int v = r >> 3;
  const int ub = q * 8 + (r & 7);
  const int unit = ub >> 8;
  const int bm = ub & 255;
  const int K = (unit < 2) ? 512 : 1536;
  const float* Aptr = (unit < 2) ? x : xbin;
  const size_t woff = (unit == 0) ? 0u : (unit == 1) ? 524288u : (unit == 2) ? 1048576u : 2621440u;
  const f16* W16 = w16all + woff;
  const int bgrp = bm >> 5, t0 = (bm & 31) * 32;
  const int b0 = bgrp * 4, c = bgrp >> 1, lkb = bgrp & 1;
  const int tid = threadIdx.x;
  const int lane = tid & 63, wid = tid >> 6;
  const int wm = wid >> 1, wn = wid & 1;
  const int lr = lane & 15, lk = lane >> 4;
  const int xsw = (lr & 7) << 4;

  f32x4 acc[4][8];
#pragma unroll
  for (int i = 0; i < 4; ++i)
#pragma unroll
    for (int n = 0; n < 8; ++n) acc[i][n] = (f32x4){0.f, 0.f, 0.f, 0.f};

#define PROJ_PREFETCH(KN_, AO_, BO_)                                                        \
  if ((KN_) < K) {                                                                          \
    float4 ar0[4], ar1[4];                                                                  \
    _Pragma("unroll") for (int s = 0; s < 4; ++s) {                                         \
      int slot = s * 256 + tid;                                                             \
      int row = slot >> 3, seg = slot & 7;                                                  \
      size_t arow = (size_t)(b0 + (row >> 5)) * 1024 + t0 + (row & 31);                     \
      const float* ga = Aptr + arow * K + (KN_) + seg * 8;                                  \
      ar0[s] = *(const float4*)ga;                                                          \
      ar1[s] = *(const float4*)(ga + 4);                                                    \
    }                                                                                       \
    __builtin_amdgcn_sched_barrier(0);                                                      \
    _Pragma("unroll") for (int i = 0; i < 8; ++i) {                                         \
      int g = (wid * 8 + i) * 64 + lane;                                                    \
      int brow = g >> 3, cg = g & 7;                                                        \
      const f16* bsrc = W16 + (size_t)(v * 256 + brow) * K + (KN_) + ((cg ^ (brow & 7)) << 3); \
      gload16(bsrc, smem + (BO_) + (wid * 8 + i) * 1024);                                   \
    }                                                                                       \
    __builtin_amdgcn_sched_barrier(0);                                                      \
    _Pragma("unroll") for (int s = 0; s < 4; ++s) {                                         \
      int slot = s * 256 + tid;                                                             \
      int row = slot >> 3, seg = slot & 7;                                                  \
      *(iv4*)(smem + (AO_) + row * 128 + ((seg ^ (row & 7)) << 4)) = cvt8(ar0[s], ar1[s]);  \
    }                                                                                       \
    __builtin_amdgcn_sched_barrier(0);                                                      \
  } else {                                                                                  \
    __builtin_amdgcn_sched_barrier(0);                                                      \
    asm volatile("s_waitcnt vmcnt(0)" ::: "memory");                                        \
    __builtin_amdgcn_sched_barrier(0);                                                      \
  }

#define PROJ_COMPUTE(AO_, BO_)                                                              \
  _Pragma("unroll") for (int kk = 0; kk < 2; ++kk) {                                        \
    f16x8 af[4], bf[8];                                                                     \
    _Pragma("unroll") for (int mi = 0; mi < 4; ++mi) {                                      \
      int ba = (wm * 64 + mi * 16 + lr) * 128 + kk * 64 + lk * 16;                          \
      af[mi] = *(const f16x8*)(smem + (AO_) + (ba ^ xsw));                                  \
    }                                                                                       \
    _Pragma("unroll") for (int ni = 0; ni < 8; ++ni) {                                      \
      int bb = (wn * 128 + ni * 16 + lr) * 128 + kk * 64 + lk * 16;                         \
      bf[ni] = *(const f16x8*)(smem + (BO_) + (bb ^ xsw));                                  \
    }                                                                                       \
    _Pragma("unroll") for (int mi = 0; mi < 4; ++mi)                                        \
      _Pragma("unroll") for (int ni = 0; ni < 8; ++ni)                                      \
        acc[mi][ni] = __builtin_amdgcn_mfma_f32_16x16x32_f16(af[mi], bf[ni], acc[mi][ni], 0, 0, 0); \
  }

  PROJ_PREFETCH(0, 0, 32768);
  for (int k0 = 0; k0 < K; k0 += 128) {
    PROJ_PREFETCH(k0 + 64, 16384, 65536);
    WG_BARRIER();
    PROJ_COMPUTE(0, 32768);
    WG_BARRIER();
    PROJ_PREFETCH(k0 + 128, 0, 32768);
    WG_BARRIER();
    PROJ_COMPUTE(16384, 65536);
    WG_BARRIER();
  }
#undef PROJ_PREFETCH
#undef PROJ_COMPUTE

  // epilogue: two passes, 32KB LDS each
  float biasv[8];
#pragma unroll
  for (int ni = 0; ni < 8; ++ni)
    biasv[ni] = bsum[unit * 1024 + v * 256 + wn * 128 + ni * 16 + lr];
  char* Pv = P4 + ((size_t)unit << 26) + ((size_t)v << 24);
#pragma unroll
  for (int pass = 0; pass < 2; ++pass) {
    __syncthreads();
#pragma unroll
    for (int mi2 = 0; mi2 < 2; ++mi2) {
      int mi = mi2 * 2 + pass;
#pragma unroll
      for (int ni = 0; ni < 8; ++ni) {
        int col = wn * 128 + ni * 16 + lr;
        int wc = col >> 5, jc = (col >> 4) & 1, lc = col & 15;
#pragma unroll
        for (int rr = 0; rr < 4; ++rr) {
          int row = wm * 64 + mi * 16 + lk * 4 + rr;
          int bsub = row >> 5, tl = row & 15;
          int unit2 = tl * 256 + wc * 32 + jc * 16 + lc;
          int off = (unit2 * 8 + bsub * 2) ^ ((tl & 7) << 4);
          *(f16*)(smem + off) = (f16)(acc[mi][ni][rr] + biasv[ni]);
        }
      }
    }
    __syncthreads();
#pragma unroll
    for (int k = 0; k < 16; ++k) {
      int uid = k * 256 + tid;
      int tl = uid >> 8, sub = uid & 255;
      int off = (uid * 8) ^ ((tl & 7) << 4);
      unsigned long long val = *(const unsigned long long*)(smem + off);
      int t_loc = pass * 16 + tl;
      int wq = sub >> 5, jq = (sub >> 4) & 1, lq = sub & 15;
      size_t didx =
          (((size_t)((t0 + t_loc) * 4 + c) * 512) + wq * 64 + jq * 32 + lkb * 16 + lq) << 3;
      *(unsigned long long*)(Pv + didx) = val;
    }
  }
}

// ---------------- LSTM recurrence (proven, unchanged) ----------------
__global__ __attribute__((amdgpu_flat_work_group_size(512, 512), amdgpu_waves_per_eu(2, 2)))
void lstm_rec5(const char* __restrict__ Wq4,
               const float* __restrict__ fsc4,
               const char* __restrict__ P4,
               const float* __restrict__ h0m,
               const float* __restrict__ c0m,
               const float* __restrict__ h0b,
               const float* __restrict__ c0b,
               f16* __restrict__ hid4) {
  const int wg = blockIdx.x;
  const int u = wg >> 4, c16 = wg & 15;
  const int dir = u & 1;
  const int tid = threadIdx.x;
  const int l = tid & 63, w = tid >> 6;
  const int lr = l & 15, lk = l >> 4;
  const int jj = lk >> 1, selb = lk & 1;
  const int r2 = lr & 1;
  const int swzA = r2 ? 80 : 0;
  const int swzW = selb ? 80 : 0;
  const int j = w * 32 + jj * 16 + lr;

  __shared__ __align__(16) char hbuf[2][512];

  iv4 Bf[4][8];
  const char* wb = Wq4 + ((size_t)u << 18);
#pragma unroll
  for (int nt = 0; nt < 8; ++nt) {
    int n = (nt >> 1) * 256 + w * 32 + ((nt & 1) << 4) + lr;
#pragma unroll
    for (int ks = 0; ks < 4; ++ks)
      Bf[ks][nt] = *(const iv4*)(wb + (size_t)n * 256 + ks * 64 + lk * 16);
  }
  float fv[4], fv4[4];
#pragma unroll
  for (int v = 0; v < 4; ++v) {
    fv[v] = fsc4[u * 1024 + v * 256 + j];
    fv4[v] = fv[v] * 4.f;
  }

  const int b = c16 * 2 + selb;
  const float* h0 = (u < 2 ? h0m : h0b) + (size_t)dir * BATCH * HID;
  const float* c0 = (u < 2 ? c0m : c0b) + (size_t)dir * BATCH * HID;
  float cst = c0[b * HID + j];
  {
    float hv = h0[b * HID + j] * 31.75f;
    int hq = (int)rintf(hv);
    hq = hq > 127 ? 127 : (hq < -127 ? -127 : hq);
    hbuf[0][selb * 256 + (j ^ swzW)] = (char)hq;
  }

  const char* Pc = P4 + ((size_t)u << 26);
  const size_t soff =
      (size_t)((w * 64 + jj * 32 + (((c16 >> 1) & 1) << 4) + lr) * 8 + (c16 & 1) * 4);
  const int cq = c16 >> 2;
  f16x2 Pa[4], Pb[4];
  {
    int t0 = dir ? (S_LEN - 1) : 0;
    size_t tb = ((size_t)((t0 << 2) + cq) << 12) + soff;
#pragma unroll
    for (int v = 0; v < 4; ++v) Pa[v] = *(const f16x2*)(Pc + ((size_t)v << 24) + tb);
  }
  WG_BARRIER();

#define LSTM_STEP(S_, SP_, PC_, PN_, FV_)                                                   \
  {                                                                                         \
    const int t = dir ? (S_LEN - 1 - (S_)) : (S_);                                          \
    {                                                                                       \
      int s2 = ((S_) + 1 < S_LEN) ? (S_) + 1 : (S_);                                        \
      int t2 = dir ? (S_LEN - 1 - s2) : s2;                                                 \
      size_t tb = ((size_t)((t2 << 2) + cq) << 12) + soff;                                  \
      _Pragma("unroll") for (int v = 0; v < 4; ++v)                                         \
          PN_[v] = *(const f16x2*)(Pc + ((size_t)v << 24) + tb);                            \
    }                                                                                       \
    iv4 ia[8];                                                                              \
    _Pragma("unroll") for (int nt = 0; nt < 8; ++nt) ia[nt] = (iv4){0, 0, 0, 0};            \
    const char* hb = hbuf[SP_];                                                             \
    _Pragma("unroll") for (int ks = 0; ks < 4; ++ks) {                                      \
      iv4 Af = *(const iv4*)(hb + r2 * 256 + ((ks * 64 + lk * 16) ^ swzA));                 \
      _Pragma("unroll") for (int nt = 0; nt < 8; ++nt)                                      \
          ia[nt] = __builtin_amdgcn_mfma_i32_16x16x64_i8(Af, Bf[ks][nt], ia[nt], 0, 0, 0);  \
    }                                                                                       \
    float z[4];                                                                             \
    _Pragma("unroll") for (int v = 0; v < 4; ++v) {                                         \
      int e0 = selb ? ia[v * 2][1] : ia[v * 2][0];                                          \
      int e1 = selb ? ia[v * 2 + 1][1] : ia[v * 2 + 1][0];                                  \
      int iz = jj ? e1 : e0;                                                                \
      float pv = selb ? (float)PC_[v][1] : (float)PC_[v][0];                                \
      z[v] = pv + FV_[v] * (float)iz;                                                       \
    }                                                                                       \
    float zi = z[0], zf = z[1], zg = z[2], zo = z[3];                                       \
    float ei = EXP2(-zi), ef = EXP2(-zf), eg = EXP2(-zg), eo = EXP2(-zo);                   \
    float di = 1.f + ei, df = 1.f + ef, dg = 1.f + eg, dof = 1.f + eo;                      \
    float r1 = RCP(di * df);                                                                \
    float si = r1 * df, sf = r1 * di;                                                       \
    float r2x = RCP(dg * dof);                                                              \
    float tg = 2.f * (r2x * dof) - 1.f, so = r2x * dg;                                      \
    float cc = sf * cst + si * tg;                                                          \
    cst = cc;                                                                               \
    float ec = EXP2(-L2E2 * cc);                                                            \
    float th = 2.f * RCP(1.f + ec) - 1.f;                                                   \
    float hh = so * th;                                                                     \
    int hq = (int)rintf(hh * 127.f);                                                        \
    hbuf[SP_ ^ 1][selb * 256 + (j ^ swzW)] = (char)hq;                                      \
    hid4[((size_t)b << 20) + ((size_t)t << 10) + (u << 8) + j] = (f16)hh;                   \
    WG_BARRIER();                                                                           \
  }

  LSTM_STEP(0, 0, Pa, Pb, fv4);
  for (int s = 1; s <= 1021; s += 2) {
    LSTM_STEP(s, 1, Pb, Pa, fv);
    LSTM_STEP(s + 1, 0, Pa, Pb, fv);
  }
  LSTM_STEP(1023, 1, Pb, Pa, fv);
#undef LSTM_STEP
}

// ---------------- emissions via MFMA ----------------
// block = 256 thr (4 waves x 16 rows), 512 blocks. wtag/wbin staged in LDS (XOR-swizzled);
// hid4 A-fragments direct from global (each element read once).
__global__ __launch_bounds__(256) void emis_mfma(const f16* __restrict__ hid4,
                                                 const f16* __restrict__ wtag,
                                                 const float* __restrict__ btag,
                                                 const f16* __restrict__ wbin,
                                                 const float* __restrict__ bbin,
                                                 float* __restrict__ emis,
                                                 float* __restrict__ emisb) {
  __shared__ __align__(16) f16 wt[16 * 1024];  // 32KB, [tag][k] swizzled
  __shared__ __align__(16) f16 wbp[16 * 512];  // 16KB, rows 5..15 zero, swizzled
  const int tid = threadIdx.x;
  // stage wtag: 2048 granules (f16x8)
#pragma unroll
  for (int i = 0; i < 8; ++i) {
    int idx = i * 256 + tid;
    int n = idx >> 7, cc = idx & 127;
    ((f16x8*)wt)[n * 128 + (cc ^ (n & 7))] = ((const f16x8*)wtag)[idx];
  }
  // stage wbin padded: 1024 granules
#pragma unroll
  for (int i = 0; i < 4; ++i) {
    int idx = i * 256 + tid;
    int n = idx >> 6, cc = idx & 63;
    f16x8 val = {};
    if (n < 5) val = ((const f16x8*)wbin)[n * 64 + cc];
    ((f16x8*)wbp)[n * 64 + (cc ^ (n & 7))] = val;
  }
  __syncthreads();

  const int wv = tid >> 6, lane = tid & 63;
  const int lr = lane & 15, lk = lane >> 4;
  const size_t row0 = (size_t)blockIdx.x * 64 + wv * 16;
  const f16* arow = hid4 + (row0 + lr) * 1024;
  const f16x8* wtp = (const f16x8*)wt;
  const f16x8* wbv = (const f16x8*)wbp;
  const int bsw = lr & 7;

  f32x4 accm = (f32x4){0.f, 0.f, 0.f, 0.f};
  f32x4 accb = (f32x4){0.f, 0.f, 0.f, 0.f};
#pragma unroll
  for (int ks = 0; ks < 32; ++ks) {
    f16x8 a = *(const f16x8*)(arow + ks * 32 + lk * 8);
    f16x8 b = wtp[lr * 128 + ((ks * 4 + lk) ^ bsw)];
    accm = __builtin_amdgcn_mfma_f32_16x16x32_f16(a, b, accm, 0, 0, 0);
  }
#pragma unroll
  for (int ks = 0; ks < 16; ++ks) {
    f16x8 a = *(const f16x8*)(arow + 512 + ks * 32 + lk * 8);
    f16x8 b = wbv[lr * 64 + ((ks * 4 + lk) ^ bsw)];
    accb = __builtin_amdgcn_mfma_f32_16x16x32_f16(a, b, accb, 0, 0, 0);
  }
  // C layout: col = lane&15 (tag), row = lk*4 + r
  float bt = btag[lr];
  float bb = (lr < 5) ? bbin[lr] : 0.f;
#pragma unroll
  for (int r = 0; r < 4; ++r) {
    size_t orow = row0 + lk * 4 + r;
    emis[orow * 16 + lr] = accm[r] + bt;
    if (lr < 5) emisb[orow * 5 + lr] = accb[r] + bb;
  }
}

// ---------------- fused CRF (round-14 proven) ----------------
__global__ __launch_bounds__(64) void crf_fused(const float* __restrict__ emis,
                                                const float* __restrict__ trans,
                                                const float* __restrict__ emisb,
                                                const float* __restrict__ transb,
                                                const float* __restrict__ mask,
                                                const int* __restrict__ tags,
                                                const int* __restrict__ tagsb,
                                                float* __restrict__ outLogZ,
                                                float* __restrict__ outScore) {
  const int lane = threadIdx.x;
  if (blockIdx.x < 64) {
    const int crf = blockIdx.x >> 5, b = blockIdx.x & 31;
    const int NTc = crf ? 5 : 16;
    const float* __restrict__ E = crf ? emisb : emis;
    const float* __restrict__ T = crf ? transb : trans;
    const int jn = lane >> 2, p = lane & 3;
    const bool jv = (jn < NTc);
    const int jc = jv ? jn : 0;
    float Tc[4];
#pragma unroll
    for (int ii = 0; ii < 4; ++ii) {
      int i = p * 4 + ii;
      Tc[ii] = (jv && i < NTc) ? T[i * NTc + jn] : -1e30f;
    }
    float alpha = jv ? (T[1 * NTc + jc] + E[(size_t)(b << 10) * NTc + jc]) : -1e30f;
    const size_t ebase = (size_t)(b << 10) * NTc + jc;
    const int mbase = b << 10;
#define LDE(tt) E[ebase + (size_t)(tt)*NTc]
#define LDM(tt) mask[mbase + (tt)]

    auto step = [&](float e_tj, float m_t) {
      float a0 = __shfl(alpha, ((p * 4 + 0) << 2) | p);
      float a1 = __shfl(alpha, ((p * 4 + 1) << 2) | p);
      float a2 = __shfl(alpha, ((p * 4 + 2) << 2) | p);
      float a3 = __shfl(alpha, ((p * 4 + 3) << 2) | p);
      float v0 = a0 + Tc[0], v1 = a1 + Tc[1], v2 = a2 + Tc[2], v3 = a3 + Tc[3];
      float mx = fmaxf(fmaxf(v0, v1), fmaxf(v2, v3));
      mx = fmaxf(mx, __shfl_xor(mx, 1, 4));
      mx = fmaxf(mx, __shfl_xor(mx, 2, 4));
      float ss = __expf(v0 - mx) + __expf(v1 - mx) + __expf(v2 - mx) + __expf(v3 - mx);
      ss += __shfl_xor(ss, 1, 4);
      ss += __shfl_xor(ss, 2, 4);
      float newv = e_tj + mx + __logf(ss);
      alpha = (m_t > 0.5f) ? newv : alpha;
    };

    float eb[4], mb[4];
#pragma unroll
    for (int k = 0; k < 4; ++k) { eb[k] = LDE(1 + k); mb[k] = LDM(1 + k); }
    for (int t = 1; t <= 1017; t += 4) {
      float en[4], mn[4];
#pragma unroll
      for (int k = 0; k < 4; ++k) {
        int ix = t + 4 + k;
        ix = ix > 1023 ? 1023 : ix;
        en[k] = LDE(ix);
        mn[k] = LDM(ix);
      }
      step(eb[0], mb[0]); step(eb[1], mb[1]); step(eb[2], mb[2]); step(eb[3], mb[3]);
#pragma unroll
      for (int k = 0; k < 4; ++k) { eb[k] = en[k]; mb[k] = mn[k]; }
    }
    step(eb[0], mb[0]); step(eb[1], mb[1]); step(eb[2], mb[2]);
#undef LDE
#undef LDM

    float fin = (jv && p == 0) ? (alpha + T[jn * NTc + 2]) : -1e30f;
    float mx = fin;
#pragma unroll
    for (int off = 1; off < 64; off <<= 1) mx = fmaxf(mx, __shfl_xor(mx, off));
    float ss = __expf(fin - mx);
#pragma unroll
    for (int off = 1; off < 64; off <<= 1) ss += __shfl_xor(ss, off);
    if (lane == 0) outLogZ[crf * 32 + b] = mx + __logf(ss);
  } else {
    const int bi = blockIdx.x - 64;
    const int crf = bi >> 5, b = bi & 31;
    const int NTc = crf ? 5 : 16;
    const float* __restrict__ E = crf ? emisb : emis;
    const float* __restrict__ T = crf ? transb : trans;
    const int* __restrict__ tg = (crf ? tagsb : tags) + (b << 10);
    const float* __restrict__ mk = mask + (b << 10);
    float s = 0.f, cnt = 0.f;
    for (int t = lane; t < S_LEN; t += 64) {
      float m = mk[t];
      cnt += m;
      if (t >= 1 && m > 0.5f)
        s += E[((size_t)(b << 10) + t) * NTc + tg[t]] + T[tg[t - 1] * NTc + tg[t]];
    }
#pragma unroll
    for (int off = 32; off >= 1; off >>= 1) {
      s += __shfl_down(s, off);
      cnt += __shfl_down(cnt, off);
    }
    if (lane == 0) {
      int L = (int)(cnt + 0.5f);
      int t0 = tg[0];
      float tot = T[1 * NTc + t0] + E[(size_t)(b << 10) * NTc + t0] + s + T[tg[L - 1] * NTc + 2];
      outScore[crf * 32 + b] = tot;
    }
  }
}

__global__ void finalk(const float* __restrict__ logZ, const float* __restrict__ score,
                       float* __restrict__ out) {
  int j = threadIdx.x;
  if (j < 2) {
    float a = 0.f;
    for (int b = 0; b < 32; ++b) a += logZ[j * 32 + b] - score[j * 32 + b];
    out[j] = a;
  }
}

extern "C" void kernel_launch(void* const* d_in, const int* in_sizes, int n_in,
                              void* d_out, int out_size, void* d_ws, size_t ws_size,
                              hipStream_t stream) {
  const float* x       = (const float*)d_in[0];
  const float* xbin    = (const float*)d_in[1];
  const float* mask    = (const float*)d_in[2];
  const int*   tags    = (const int*)d_in[3];
  const int*   tagsb   = (const int*)d_in[4];
  const float* trans   = (const float*)d_in[5];
  const float* transb  = (const float*)d_in[6];
  const float* w2f_ih  = (const float*)d_in[7];
  const float* w2f_hh  = (const float*)d_in[8];
  const float* b2f_ih  = (const float*)d_in[9];
  const float* b2f_hh  = (const float*)d_in[10];
  const float* w2b_ih  = (const float*)d_in[11];
  const float* w2b_hh  = (const float*)d_in[12];
  const float* b2b_ih  = (const float*)d_in[13];
  const float* b2b_hh  = (const float*)d_in[14];
  const float* w_bin   = (const float*)d_in[15];
  const float* bb_bin  = (const float*)d_in[16];
  const float* w1f_ih  = (const float*)d_in[17];
  const float* w1f_hh  = (const float*)d_in[18];
  const float* b1f_ih  = (const float*)d_in[19];
  const float* b1f_hh  = (const float*)d_in[20];
  const float* w1b_ih  = (const float*)d_in[21];
  const float* w1b_hh  = (const float*)d_in[22];
  const float* b1b_ih  = (const float*)d_in[23];
  const float* b1b_hh  = (const float*)d_in[24];
  const float* w_tag   = (const float*)d_in[25];
  const float* b_tag   = (const float*)d_in[26];
  const float* h0_bin  = (const float*)d_in[27];
  const float* c0_bin  = (const float*)d_in[28];
  const float* h0_main = (const float*)d_in[29];
  const float* c0_main = (const float*)d_in[30];

  char* ws = (char*)d_ws;
  char* P4    = ws;                                   // 256MiB
  f16* hid4   = (f16*)(ws + 268435456);               // 64MiB
  char* Wq4   = ws + 335544320;                       // 1MiB
  float* fsc4 = (float*)(ws + 336592896);             // 16KB
  f16* wtag   = (f16*)(ws + 336609280);
  f16* wbin   = (f16*)(ws + 336642048);
  float* emis  = (float*)(ws + 336647168);            // 2MiB
  float* emisb = (float*)(ws + 338744320);
  float* logZ  = (float*)(ws + 339399680);
  float* score = (float*)(ws + 339399936);
  float* bsum  = (float*)(ws + 339400704);            // 16KB
  f16* w16all  = (f16*)(ws + 340000768);              // 8MiB

  prep_all<<<3107, 256, 0, stream>>>(w1f_hh, w1b_hh, w2f_hh, w2b_hh, Wq4, fsc4,
                                     w_tag, wtag, w_bin, wbin,
                                     w1f_ih, w1b_ih, w2f_ih, w2b_ih, w16all,
                                     b1f_ih, b1f_hh, b1b_ih, b1b_hh,
                                     b2f_ih, b2f_hh, b2b_ih, b2b_hh, bsum);
  proj_gemm<<<4096, 256, 0, stream>>>(x, xbin, w16all, bsum, P4);
  lstm_rec5<<<64, 512, 0, stream>>>(Wq4, fsc4, P4, h0_main, c0_main, h0_bin, c0_bin, hid4);
  emis_mfma<<<512, 256, 0, stream>>>(hid4, wtag, b_tag, wbin, bb_bin, emis, emisb);
  crf_fused<<<128, 64, 0, stream>>>(emis, trans, emisb, transb, mask, tags, tagsb, logZ, score);
  finalk<<<1, 64, 0, stream>>>(logZ, score, (float*)d_out);
}